// Round 14
// baseline (6986.643 us; speedup 1.0000x reference)
//
#include <hip/hip_runtime.h>
#include <hip/hip_bf16.h>

#define BB 512
#define SS 512
#define EE 128
#define HH 256
#define VV 128
#define G4H 1024
#define TSL 64              // rec1 time-slice length
#define NSEG (SS / TSL)     // 8

using bf16 = __bf16;
typedef __attribute__((ext_vector_type(8))) __bf16 bf16x8;
typedef __attribute__((ext_vector_type(4))) float f32x4;

__device__ __forceinline__ float rcpf(float x) { return __builtin_amdgcn_rcpf(x); }
__device__ __forceinline__ float exp2f_(float x) { return __builtin_amdgcn_exp2f(x); }
__device__ __forceinline__ float sigf(float x) {
  return rcpf(1.0f + exp2f_(-1.442695041f * x));
}
__device__ __forceinline__ float tanh_(float x) {
  return 2.0f * rcpf(1.0f + exp2f_(-2.885390082f * x)) - 1.0f;
}
__device__ __forceinline__ bf16x8 cvt8(const float* __restrict__ s) {
  bf16x8 f;
  #pragma unroll
  for (int j = 0; j < 8; ++j) f[j] = (bf16)s[j];
  return f;
}
__device__ __forceinline__ float bf2f(unsigned short u) {
  return __uint_as_float(((unsigned)u) << 16);
}
__device__ __forceinline__ void nt_store_bf16(bf16* p, bf16 v) {
  __builtin_nontemporal_store(__builtin_bit_cast(short, v), (short*)p);
}

// ---------------------------------------------------------------------------
// x dtype sniffer (validated R4): odd 32-bit words all zero <=> int64.
// ---------------------------------------------------------------------------
__global__ void detect_kernel(const int* __restrict__ x, int* __restrict__ flag) {
  const int i = blockIdx.x * 256 + threadIdx.x;
  if (x[2 * i + 1] != 0) atomicOr(flag, 1);
}

// ---------------------------------------------------------------------------
// Gate-interleaved bf16 table: table[v][u*4+q] = emb[v,:].Wi0[q*256+u,:] + biases
// ---------------------------------------------------------------------------
__global__ __launch_bounds__(256)
void table_kernel(const float* __restrict__ emb, const float* __restrict__ Wi,
                  const float* __restrict__ bi, const float* __restrict__ bh,
                  unsigned short* __restrict__ table) {
  const int g = blockIdx.x * 256 + threadIdx.x;  // 0..1023
  const int v = blockIdx.y;                      // 0..127
  float s = bi[g] + bh[g];
  const float* er = emb + v * EE;
  const float* wr = Wi + (size_t)g * EE;
  #pragma unroll 4
  for (int e = 0; e < EE; ++e) s += er[e] * wr[e];
  const bf16 b = (bf16)s;
  table[v * G4H + (g & 255) * 4 + (g >> 8)] = *(const unsigned short*)&b;
}

// ---------------------------------------------------------------------------
// Weight prep: Wh (fp32 [1024][256]) -> bf16 MFMA-fragment granules.
// Flat granule index = w*4096 + s*512 + kc*64 + l  (16B each, 512KB/layer).
// Slot s -> (gate q = s>>1, col-half j = s&1); lane l=(lg,ln):
//   granule holds Wh[q*256 + w*32 + 16j + ln][kc*32 + lg*8 .. +8).
// ---------------------------------------------------------------------------
__global__ __launch_bounds__(256)
void wprep_kernel(const float* __restrict__ Wh0, const float* __restrict__ Wh1,
                  bf16x8* __restrict__ wb0, bf16x8* __restrict__ wb1) {
  const int idx = blockIdx.x * 256 + threadIdx.x;   // 0..32767
  const int l = idx & 63, kc = (idx >> 6) & 7, s = (idx >> 9) & 7, w = idx >> 12;
  const int lg = l >> 4, ln = l & 15;
  const int n = (s >> 1) * HH + w * 32 + 16 * (s & 1) + ln;
  const int k0 = kc * 32 + lg * 8;
  const float* src = (blockIdx.y ? Wh1 : Wh0) + (size_t)n * HH + k0;
  (blockIdx.y ? wb1 : wb0)[idx] = cvt8(src);
}

// ---------------------------------------------------------------------------
// MFMA recurrence layer 0. 64 WGs x 512 thr; WG owns 8 batch rows (top half
// of the 16-row M-tile; bottom half zeros). LDS = 80KB -> up to 2 WGs/CU.
// Per wave (32 hidden cols x 4 gates = 8 slots):
//   slot 0: VGPR-resident (32 regs)   slot 1: LDS (64KB total)
//   slots 2-7: streamed from L2 (bf16 wb, 48KB/wave/step)
// h1 stores are NONTEMPORAL so the 64MB write stream does not evict the
// L2-resident weights (R6's regression mechanism).
// ---------------------------------------------------------------------------
__global__ __launch_bounds__(512)
void rec0_kernel(const int* __restrict__ x, const int* __restrict__ flagp,
                 const bf16x8* __restrict__ wb,
                 const unsigned short* __restrict__ table,
                 bf16* __restrict__ h1) {
  __shared__ bf16 hbuf[2][4096];     // 16KB (rows 8-15 stay zero)
  __shared__ bf16x8 wlds[4096];      // 64KB (slot 1)
  const int tid = threadIdx.x, w = tid >> 6, l = tid & 63, lg = l >> 4, ln = l & 15;
  const int b0 = blockIdx.x * 8, hb = w * 32;
  const int is32 = *flagp;

  bf16x8 Wf[8];                      // slot 0
  #pragma unroll
  for (int kc = 0; kc < 8; ++kc) Wf[kc] = wb[w * 4096 + kc * 64 + l];
  #pragma unroll
  for (int kc = 0; kc < 8; ++kc)     // slot 1 -> LDS
    wlds[(w * 8 + kc) * 64 + l] = wb[w * 4096 + 512 + kc * 64 + l];
  const bf16x8* __restrict__ gs = wb + w * 4096 + 2 * 512 + l;  // slots 2..7

  { bf16x8 z = {}; ((bf16x8*)hbuf[0])[tid] = z; ((bf16x8*)hbuf[1])[tid] = z; }
  float c[2][4] = {};

  int hoff[4];
  #pragma unroll
  for (int r = 0; r < 4; ++r)
    hoff[r] = ((b0 + ((lg * 4 + r) & 7)) * SS) * HH + hb + ln;

  int idx[4] = {0, 0, 0, 0};
  if (lg < 2) {
    #pragma unroll
    for (int r = 0; r < 4; ++r) {
      const long xi = (long)(b0 + lg * 4 + r) * SS;
      idx[r] = x[is32 ? xi : 2 * xi] & 127;
    }
  }
  __syncthreads();

  #pragma unroll 1
  for (int t = 0; t < SS; ++t) {
    const int p = t & 1;
    // table gather for step t + x prefetch for t+1 (live rows only)
    ushort4 tj[4][2];
    if (lg < 2) {
      #pragma unroll
      for (int r = 0; r < 4; ++r) {
        const unsigned short* base = table + (size_t)idx[r] * G4H + (hb + ln) * 4;
        tj[r][0] = *(const ushort4*)base;
        tj[r][1] = *(const ushort4*)(base + 64);
      }
      if (t + 1 < SS) {
        #pragma unroll
        for (int r = 0; r < 4; ++r) {
          const long xi = (long)(b0 + lg * 4 + r) * SS + (t + 1);
          idx[r] = x[is32 ? xi : 2 * xi] & 127;
        }
      }
    }
    f32x4 acc[4][2] = {};
    #pragma unroll
    for (int kc = 0; kc < 8; ++kc) {
      bf16x8 a = ((const bf16x8*)hbuf[p])[kc * 64 + ln * 4 + lg];
      acc[0][0] = __builtin_amdgcn_mfma_f32_16x16x32_bf16(a, Wf[kc], acc[0][0], 0, 0, 0);
      {
        bf16x8 bw = wlds[(w * 8 + kc) * 64 + l];
        acc[0][1] = __builtin_amdgcn_mfma_f32_16x16x32_bf16(a, bw, acc[0][1], 0, 0, 0);
      }
      acc[1][0] = __builtin_amdgcn_mfma_f32_16x16x32_bf16(a, gs[0 * 512 + kc * 64], acc[1][0], 0, 0, 0);
      acc[1][1] = __builtin_amdgcn_mfma_f32_16x16x32_bf16(a, gs[1 * 512 + kc * 64], acc[1][1], 0, 0, 0);
      acc[2][0] = __builtin_amdgcn_mfma_f32_16x16x32_bf16(a, gs[2 * 512 + kc * 64], acc[2][0], 0, 0, 0);
      acc[2][1] = __builtin_amdgcn_mfma_f32_16x16x32_bf16(a, gs[3 * 512 + kc * 64], acc[2][1], 0, 0, 0);
      acc[3][0] = __builtin_amdgcn_mfma_f32_16x16x32_bf16(a, gs[4 * 512 + kc * 64], acc[3][0], 0, 0, 0);
      acc[3][1] = __builtin_amdgcn_mfma_f32_16x16x32_bf16(a, gs[5 * 512 + kc * 64], acc[3][1], 0, 0, 0);
    }
    // epilogue (live rows m<8 only)
    #pragma unroll
    for (int j = 0; j < 2; ++j)
      #pragma unroll
      for (int r = 0; r < 4; ++r) {
        const int m = lg * 4 + r;
        if (m < 8) {
          const float fg = sigf(acc[0][j][r] + bf2f(tj[r][j].x));
          const float ig = sigf(acc[1][j][r] + bf2f(tj[r][j].y));
          const float gg = tanh_(acc[2][j][r] + bf2f(tj[r][j].z));
          const float og = sigf(acc[3][j][r] + bf2f(tj[r][j].w));
          const float cc = fg * c[j][r] + ig * gg;
          c[j][r] = cc;
          const bf16 hv = (bf16)(og * tanh_(cc));
          hbuf[p ^ 1][(w * 64 + m * 4 + 2 * j + (ln >> 3)) * 8 + (ln & 7)] = hv;
          nt_store_bf16(&h1[hoff[r] + t * HH + 16 * j], hv);
        }
      }
    __syncthreads();
  }
}

// ---------------------------------------------------------------------------
// MFMA recurrence layer 1, one time-slice [t0,t0+TSL). Same structure;
// gate init gathered from gate-interleaved bf16 xg (includes bi1+bh1).
// ---------------------------------------------------------------------------
__global__ __launch_bounds__(512)
void rec1_kernel(const unsigned short* __restrict__ xg, const bf16x8* __restrict__ wb,
                 bf16* __restrict__ hreg, float* __restrict__ cws, int t0) {
  __shared__ bf16 hbuf[2][4096];
  __shared__ bf16x8 wlds[4096];
  const int tid = threadIdx.x, w = tid >> 6, l = tid & 63, lg = l >> 4, ln = l & 15;
  const int b0 = blockIdx.x * 8, hb = w * 32;

  bf16x8 Wf[8];
  #pragma unroll
  for (int kc = 0; kc < 8; ++kc) Wf[kc] = wb[w * 4096 + kc * 64 + l];
  #pragma unroll
  for (int kc = 0; kc < 8; ++kc)
    wlds[(w * 8 + kc) * 64 + l] = wb[w * 4096 + 512 + kc * 64 + l];
  const bf16x8* __restrict__ gs = wb + w * 4096 + 2 * 512 + l;

  int hoff[4];
  size_t xbase[4];
  #pragma unroll
  for (int r = 0; r < 4; ++r) {
    const int mc = (lg * 4 + r) & 7;
    hoff[r] = ((b0 + mc) * SS) * HH + hb + ln;
    xbase[r] = (size_t)(b0 + mc) * TSL * G4H + (hb + ln) * 4;
  }

  { bf16x8 z = {}; ((bf16x8*)hbuf[0])[tid] = z; ((bf16x8*)hbuf[1])[tid] = z; }
  float c[2][4] = {};
  if (t0 != 0) {
    #pragma unroll
    for (int j = 0; j < 2; ++j)
      #pragma unroll
      for (int r = 0; r < 4; ++r) {
        const int m = lg * 4 + r;
        if (m < 8) {
          const int col = hb + 16 * j + ln;
          c[j][r] = cws[(size_t)(b0 + m) * HH + col];
          const bf16 hv = hreg[((size_t)(b0 + m) * SS + (t0 - 1)) * HH + col];
          hbuf[0][(w * 64 + m * 4 + 2 * j + (ln >> 3)) * 8 + (ln & 7)] = hv;
        }
      }
  }
  __syncthreads();

  #pragma unroll 1
  for (int tt = 0; tt < TSL; ++tt) {
    const int t = t0 + tt, p = tt & 1;
    ushort4 tj[4][2];
    if (lg < 2) {
      #pragma unroll
      for (int r = 0; r < 4; ++r) {
        const unsigned short* base = xg + xbase[r] + (size_t)tt * G4H;
        tj[r][0] = *(const ushort4*)base;
        tj[r][1] = *(const ushort4*)(base + 64);
      }
    }
    f32x4 acc[4][2] = {};
    #pragma unroll
    for (int kc = 0; kc < 8; ++kc) {
      bf16x8 a = ((const bf16x8*)hbuf[p])[kc * 64 + ln * 4 + lg];
      acc[0][0] = __builtin_amdgcn_mfma_f32_16x16x32_bf16(a, Wf[kc], acc[0][0], 0, 0, 0);
      {
        bf16x8 bw = wlds[(w * 8 + kc) * 64 + l];
        acc[0][1] = __builtin_amdgcn_mfma_f32_16x16x32_bf16(a, bw, acc[0][1], 0, 0, 0);
      }
      acc[1][0] = __builtin_amdgcn_mfma_f32_16x16x32_bf16(a, gs[0 * 512 + kc * 64], acc[1][0], 0, 0, 0);
      acc[1][1] = __builtin_amdgcn_mfma_f32_16x16x32_bf16(a, gs[1 * 512 + kc * 64], acc[1][1], 0, 0, 0);
      acc[2][0] = __builtin_amdgcn_mfma_f32_16x16x32_bf16(a, gs[2 * 512 + kc * 64], acc[2][0], 0, 0, 0);
      acc[2][1] = __builtin_amdgcn_mfma_f32_16x16x32_bf16(a, gs[3 * 512 + kc * 64], acc[2][1], 0, 0, 0);
      acc[3][0] = __builtin_amdgcn_mfma_f32_16x16x32_bf16(a, gs[4 * 512 + kc * 64], acc[3][0], 0, 0, 0);
      acc[3][1] = __builtin_amdgcn_mfma_f32_16x16x32_bf16(a, gs[5 * 512 + kc * 64], acc[3][1], 0, 0, 0);
    }
    #pragma unroll
    for (int j = 0; j < 2; ++j)
      #pragma unroll
      for (int r = 0; r < 4; ++r) {
        const int m = lg * 4 + r;
        if (m < 8) {
          const float fg = sigf(acc[0][j][r] + bf2f(tj[r][j].x));
          const float ig = sigf(acc[1][j][r] + bf2f(tj[r][j].y));
          const float gg = tanh_(acc[2][j][r] + bf2f(tj[r][j].z));
          const float og = sigf(acc[3][j][r] + bf2f(tj[r][j].w));
          const float cc = fg * c[j][r] + ig * gg;
          c[j][r] = cc;
          const bf16 hv = (bf16)(og * tanh_(cc));
          hbuf[p ^ 1][(w * 64 + m * 4 + 2 * j + (ln >> 3)) * 8 + (ln & 7)] = hv;
          nt_store_bf16(&hreg[hoff[r] + t * HH + 16 * j], hv);
        }
      }
    __syncthreads();
  }
  #pragma unroll
  for (int j = 0; j < 2; ++j)
    #pragma unroll
    for (int r = 0; r < 4; ++r) {
      const int m = lg * 4 + r;
      if (m < 8)
        cws[(size_t)(b0 + m) * HH + hb + 16 * j + ln] = c[j][r];
    }
}

// ---------------------------------------------------------------------------
// Tiled GEMM 128x128, K=256, 8 waves, XOR-swizzled LDS.
// OUT_BF16==1: xg slice -> bf16 gate-interleaved layout [(n&255)*4 + n>>8].
// OUT_BF16==0: proj -> fp32 [row*VV + n].
// ---------------------------------------------------------------------------
template <int OUT_BF16>
__global__ __launch_bounds__(512)
void gemm_kernel(const bf16* __restrict__ A, const float* __restrict__ W,
                 const float* __restrict__ bias0, const float* __restrict__ bias1,
                 void* __restrict__ out, int t0, int NCOL) {
  __shared__ bf16x8 alds[4096];   // 128 rows x 32 granules(16B)
  __shared__ bf16x8 blds[4096];
  const int tid = threadIdx.x, w = tid >> 6, l = tid & 63, lg = l >> 4, ln = l & 15;
  const int wm = w & 1, wn = w >> 1;
  const int R0 = blockIdx.x * 128, N0 = blockIdx.y * 128;
  {
    const int row = tid >> 2, seg = tid & 3;   // 4 thr/row, 64 cols each
    const bf16* asrc;
    if (OUT_BF16) {
      const int R = R0 + row;
      asrc = A + ((size_t)(R >> 6) * SS + t0 + (R & 63)) * HH + seg * 64;
    } else {
      asrc = A + ((size_t)R0 + row) * HH + seg * 64;
    }
    #pragma unroll
    for (int k = 0; k < 8; ++k) {
      const int g = seg * 8 + k;
      alds[row * 32 + (g ^ (row & 7))] = *(const bf16x8*)(asrc + k * 8);
    }
    const float* bsrc = W + (size_t)(N0 + row) * HH + seg * 64;
    #pragma unroll
    for (int k = 0; k < 8; ++k) {
      const int g = seg * 8 + k;
      blds[row * 32 + (g ^ (row & 7))] = cvt8(bsrc + k * 8);
    }
  }
  __syncthreads();
  f32x4 acc[4][2] = {};
  #pragma unroll
  for (int kc = 0; kc < 8; ++kc) {
    bf16x8 bfr[2];
    #pragma unroll
    for (int nt = 0; nt < 2; ++nt) {
      const int row = wn * 32 + nt * 16 + ln;
      bfr[nt] = blds[row * 32 + ((kc * 4 + lg) ^ (row & 7))];
    }
    #pragma unroll
    for (int mt = 0; mt < 4; ++mt) {
      const int row = wm * 64 + mt * 16 + ln;
      bf16x8 a = alds[row * 32 + ((kc * 4 + lg) ^ (row & 7))];
      #pragma unroll
      for (int nt = 0; nt < 2; ++nt)
        acc[mt][nt] = __builtin_amdgcn_mfma_f32_16x16x32_bf16(a, bfr[nt], acc[mt][nt], 0, 0, 0);
    }
  }
  #pragma unroll
  for (int nt = 0; nt < 2; ++nt) {
    const int n = N0 + wn * 32 + nt * 16 + ln;
    const float bv = bias0[n] + (bias1 ? bias1[n] : 0.f);
    const int col = OUT_BF16 ? ((n & 255) * 4 + (n >> 8)) : n;
    #pragma unroll
    for (int mt = 0; mt < 4; ++mt)
      #pragma unroll
      for (int r = 0; r < 4; ++r) {
        const size_t row = (size_t)R0 + wm * 64 + mt * 16 + lg * 4 + r;
        if (OUT_BF16) ((bf16*)out)[row * NCOL + col] = (bf16)(acc[mt][nt][r] + bv);
        else          ((float*)out)[row * NCOL + col] = acc[mt][nt][r] + bv;
      }
  }
}

extern "C" void kernel_launch(void* const* d_in, const int* in_sizes, int n_in,
                              void* d_out, int out_size, void* d_ws, size_t ws_size,
                              hipStream_t stream) {
  const int*   x   = (const int*)d_in[0];
  const float* emb = (const float*)d_in[1];
  const float* Wi0 = (const float*)d_in[2];
  const float* bi0 = (const float*)d_in[3];
  const float* Wh0 = (const float*)d_in[4];
  const float* bh0 = (const float*)d_in[5];
  const float* Wi1 = (const float*)d_in[6];
  const float* bi1 = (const float*)d_in[7];
  const float* Wh1 = (const float*)d_in[8];
  const float* bh1 = (const float*)d_in[9];
  const float* Wg  = (const float*)d_in[10];
  const float* bg  = (const float*)d_in[11];

  // ws: [flag 256B][table bf16 256KB][wbuf0 512KB][wbuf1 512KB][hreg bf16 128MB]
  char* ws = (char*)d_ws;
  int* flag = (int*)ws;
  unsigned short* table = (unsigned short*)(ws + 256);
  bf16x8* wb0 = (bf16x8*)(ws + 256 + 262144);
  bf16x8* wb1 = (bf16x8*)(ws + 256 + 262144 + 524288);
  bf16* hreg = (bf16*)(ws + 256 + 262144 + 524288 + 524288);
  const size_t need = 256 + 262144 + 524288 + 524288
                    + (size_t)BB * SS * HH * sizeof(bf16);
  if (ws_size < need) return;

  // d_out as scratch until proj: [xg slice 67.1MB][cws 512KB]
  unsigned short* xg = (unsigned short*)d_out;
  float* cws = (float*)((char*)d_out + (size_t)BB * TSL * G4H * sizeof(bf16));

  (void)hipMemsetAsync(flag, 0, sizeof(int), stream);
  detect_kernel<<<dim3(8), dim3(256), 0, stream>>>(x, flag);
  table_kernel<<<dim3(4, 128), dim3(256), 0, stream>>>(emb, Wi0, bi0, bh0, table);
  wprep_kernel<<<dim3(128, 2), dim3(256), 0, stream>>>(Wh0, Wh1, wb0, wb1);
  rec0_kernel<<<dim3(BB / 8), dim3(512), 0, stream>>>(x, flag, wb0, table, hreg);
  for (int s = 0; s < NSEG; ++s) {
    const int t0 = s * TSL;
    gemm_kernel<1><<<dim3(BB * TSL / 128, G4H / 128), dim3(512), 0, stream>>>(
        hreg, Wi1, bi1, bh1, xg, t0, G4H);
    rec1_kernel<<<dim3(BB / 8), dim3(512), 0, stream>>>(xg, wb1, hreg, cws, t0);
  }
  gemm_kernel<0><<<dim3(BB * SS / 128, VV / 128), dim3(512), 0, stream>>>(
      hreg, Wg, bg, nullptr, d_out, 0, VV);
}

// Round 15
// 4934.808 us; speedup vs baseline: 1.4158x; 1.4158x over previous
//
#include <hip/hip_runtime.h>
#include <hip/hip_bf16.h>

#define BB 512
#define SS 512
#define EE 128
#define HH 256
#define VV 128
#define G4H 1024
#define TSL 64              // rec1 time-slice length
#define NSEG (SS / TSL)     // 8

using bf16 = __bf16;
typedef __attribute__((ext_vector_type(8))) __bf16 bf16x8;
typedef __attribute__((ext_vector_type(4))) float f32x4;

__device__ __forceinline__ float rcpf(float x) { return __builtin_amdgcn_rcpf(x); }
__device__ __forceinline__ float exp2f_(float x) { return __builtin_amdgcn_exp2f(x); }
__device__ __forceinline__ float sigf(float x) {
  return rcpf(1.0f + exp2f_(-1.442695041f * x));
}
__device__ __forceinline__ float tanh_(float x) {
  return 2.0f * rcpf(1.0f + exp2f_(-2.885390082f * x)) - 1.0f;
}
__device__ __forceinline__ bf16x8 cvt8(const float* __restrict__ s) {
  bf16x8 f;
  #pragma unroll
  for (int j = 0; j < 8; ++j) f[j] = (bf16)s[j];
  return f;
}
__device__ __forceinline__ float bf2f(unsigned short u) {
  return __uint_as_float(((unsigned)u) << 16);
}

// ---------------------------------------------------------------------------
// x dtype sniffer (validated R4): odd 32-bit words all zero <=> int64.
// ---------------------------------------------------------------------------
__global__ void detect_kernel(const int* __restrict__ x, int* __restrict__ flag) {
  const int i = blockIdx.x * 256 + threadIdx.x;
  if (x[2 * i + 1] != 0) atomicOr(flag, 1);
}

// ---------------------------------------------------------------------------
// Gate-interleaved bf16 table: table[v][u*4+q] = emb[v,:].Wi0[q*256+u,:] + biases
// ---------------------------------------------------------------------------
__global__ __launch_bounds__(256)
void table_kernel(const float* __restrict__ emb, const float* __restrict__ Wi,
                  const float* __restrict__ bi, const float* __restrict__ bh,
                  unsigned short* __restrict__ table) {
  const int g = blockIdx.x * 256 + threadIdx.x;  // 0..1023
  const int v = blockIdx.y;                      // 0..127
  float s = bi[g] + bh[g];
  const float* er = emb + v * EE;
  const float* wr = Wi + (size_t)g * EE;
  #pragma unroll 4
  for (int e = 0; e < EE; ++e) s += er[e] * wr[e];
  const bf16 b = (bf16)s;
  table[v * G4H + (g & 255) * 4 + (g >> 8)] = *(const unsigned short*)&b;
}

// ---------------------------------------------------------------------------
// Weight prep for the 16-wave scheme: Wh (fp32 [1024][256]) -> bf16 granules.
// Granule index = w16*2048 + q*512 + kc*64 + l  (16B each, 512KB/layer).
// Wave w16 owns hidden cols [16*w16, 16*w16+16); slot q = gate.
// Granule (w16,q,kc,l=(lg,ln)) holds Wh[q*256 + w16*16 + ln][kc*32+lg*8 ..+8).
// ---------------------------------------------------------------------------
__global__ __launch_bounds__(256)
void wprep_kernel(const float* __restrict__ Wh0, const float* __restrict__ Wh1,
                  bf16x8* __restrict__ wb0, bf16x8* __restrict__ wb1) {
  const int idx = blockIdx.x * 256 + threadIdx.x;   // 0..32767
  const int l = idx & 63, kc = (idx >> 6) & 7, q = (idx >> 9) & 3, w16 = idx >> 11;
  const int lg = l >> 4, ln = l & 15;
  const int n = q * HH + w16 * 16 + ln;
  const int k0 = kc * 32 + lg * 8;
  const float* src = (blockIdx.y ? Wh1 : Wh0) + (size_t)n * HH + k0;
  (blockIdx.y ? wb1 : wb0)[idx] = cvt8(src);
}

// ---------------------------------------------------------------------------
// MFMA recurrence layer 0. 32 WGs x 1024 thr (16 waves -> 4/SIMD = 2x TLP).
// Wave w owns 16 hidden cols x 4 gates:
//   q=3 (o): LDS-resident (128 KB total)
//   q=0,1,2 (f,i,g): streamed from L2 bf16 wb with DISTANCE-2 pipeline
//     (wA/wB rotation; loads for kc+2 issue before kc's MFMAs).
// Total register demand ~100 < 128 -> nothing demoted, loads stay hoisted.
// h state in LDS fragment-major (R5/R11 verified layout); 1 barrier/step.
// ---------------------------------------------------------------------------
__global__ __launch_bounds__(1024)
void rec0_kernel(const int* __restrict__ x, const int* __restrict__ flagp,
                 const bf16x8* __restrict__ wb,
                 const unsigned short* __restrict__ table,
                 bf16* __restrict__ h1) {
  __shared__ bf16 hbuf[2][4096];     // 16 KB
  __shared__ bf16x8 wlds[8192];      // 128 KB: o-gate, 16 waves x 512 granules
  const int tid = threadIdx.x, w = tid >> 6, l = tid & 63, lg = l >> 4, ln = l & 15;
  const int b0 = blockIdx.x * 16;
  const int col = w * 16 + ln;       // this lane's hidden column
  const int is32 = *flagp;

  #pragma unroll
  for (int kc = 0; kc < 8; ++kc)     // o-gate -> LDS
    wlds[(w * 8 + kc) * 64 + l] = wb[w * 2048 + 3 * 512 + kc * 64 + l];
  const bf16x8* __restrict__ g0 = wb + w * 2048 + 0 * 512 + l;
  const bf16x8* __restrict__ g1 = wb + w * 2048 + 1 * 512 + l;
  const bf16x8* __restrict__ g2 = wb + w * 2048 + 2 * 512 + l;

  if (tid < 512) { bf16x8 z = {}; ((bf16x8*)hbuf[0])[tid] = z; }
  float c[4] = {0.f, 0.f, 0.f, 0.f};

  int hoff[4];
  #pragma unroll
  for (int r = 0; r < 4; ++r)
    hoff[r] = ((b0 + lg * 4 + r) * SS) * HH + col;

  int idx[4];
  #pragma unroll
  for (int r = 0; r < 4; ++r) {
    const long xi = (long)(b0 + lg * 4 + r) * SS;
    idx[r] = x[is32 ? xi : 2 * xi] & 127;
  }
  __syncthreads();

  #pragma unroll 1
  for (int t = 0; t < SS; ++t) {
    const int p = t & 1;
    // table gather for step t (one ushort4 per row: 4 gates interleaved)
    ushort4 tj[4];
    #pragma unroll
    for (int r = 0; r < 4; ++r)
      tj[r] = *(const ushort4*)(table + (size_t)idx[r] * G4H + col * 4);
    // prefetch x indices for t+1
    if (t + 1 < SS) {
      #pragma unroll
      for (int r = 0; r < 4; ++r) {
        const long xi = (long)(b0 + lg * 4 + r) * SS + (t + 1);
        idx[r] = x[is32 ? xi : 2 * xi] & 127;
      }
    }
    // distance-2 stream pipeline over kc
    bf16x8 wA0 = g0[0], wA1 = g1[0], wA2 = g2[0];
    bf16x8 wB0 = g0[64], wB1 = g1[64], wB2 = g2[64];
    f32x4 acc[4] = {};
    #pragma unroll
    for (int kc = 0; kc < 8; ++kc) {
      bf16x8 a = ((const bf16x8*)hbuf[p])[kc * 64 + ln * 4 + lg];
      bf16x8 c0 = (kc & 1) ? wB0 : wA0;
      bf16x8 c1 = (kc & 1) ? wB1 : wA1;
      bf16x8 c2 = (kc & 1) ? wB2 : wA2;
      if (kc + 2 < 8) {
        if (kc & 1) { wB0 = g0[(kc + 2) * 64]; wB1 = g1[(kc + 2) * 64]; wB2 = g2[(kc + 2) * 64]; }
        else        { wA0 = g0[(kc + 2) * 64]; wA1 = g1[(kc + 2) * 64]; wA2 = g2[(kc + 2) * 64]; }
      }
      acc[0] = __builtin_amdgcn_mfma_f32_16x16x32_bf16(a, c0, acc[0], 0, 0, 0);
      acc[1] = __builtin_amdgcn_mfma_f32_16x16x32_bf16(a, c1, acc[1], 0, 0, 0);
      acc[2] = __builtin_amdgcn_mfma_f32_16x16x32_bf16(a, c2, acc[2], 0, 0, 0);
      bf16x8 ow = wlds[(w * 8 + kc) * 64 + l];
      acc[3] = __builtin_amdgcn_mfma_f32_16x16x32_bf16(a, ow, acc[3], 0, 0, 0);
    }
    // epilogue: 4 h-values per lane (rows lg*4+r, column `col`)
    #pragma unroll
    for (int r = 0; r < 4; ++r) {
      const float fg = sigf(acc[0][r] + bf2f(tj[r].x));
      const float ig = sigf(acc[1][r] + bf2f(tj[r].y));
      const float gg = tanh_(acc[2][r] + bf2f(tj[r].z));
      const float og = sigf(acc[3][r] + bf2f(tj[r].w));
      const float cc = fg * c[r] + ig * gg;
      c[r] = cc;
      const bf16 hv = (bf16)(og * tanh_(cc));
      const int m = lg * 4 + r;
      hbuf[p ^ 1][(((w >> 1) * 64) + m * 4 + (w & 1) * 2 + (ln >> 3)) * 8 + (ln & 7)] = hv;
      h1[hoff[r] + t * HH] = hv;
    }
    __syncthreads();
  }
}

// ---------------------------------------------------------------------------
// MFMA recurrence layer 1, one time-slice [t0,t0+TSL). Same geometry;
// gate init gathered from gate-interleaved bf16 xg (includes bi1+bh1).
// ---------------------------------------------------------------------------
__global__ __launch_bounds__(1024)
void rec1_kernel(const unsigned short* __restrict__ xg, const bf16x8* __restrict__ wb,
                 bf16* __restrict__ hreg, float* __restrict__ cws, int t0) {
  __shared__ bf16 hbuf[2][4096];
  __shared__ bf16x8 wlds[8192];
  const int tid = threadIdx.x, w = tid >> 6, l = tid & 63, lg = l >> 4, ln = l & 15;
  const int b0 = blockIdx.x * 16;
  const int col = w * 16 + ln;

  #pragma unroll
  for (int kc = 0; kc < 8; ++kc)
    wlds[(w * 8 + kc) * 64 + l] = wb[w * 2048 + 3 * 512 + kc * 64 + l];
  const bf16x8* __restrict__ g0 = wb + w * 2048 + 0 * 512 + l;
  const bf16x8* __restrict__ g1 = wb + w * 2048 + 1 * 512 + l;
  const bf16x8* __restrict__ g2 = wb + w * 2048 + 2 * 512 + l;

  int hoff[4];
  size_t xbase[4];
  #pragma unroll
  for (int r = 0; r < 4; ++r) {
    hoff[r] = ((b0 + lg * 4 + r) * SS) * HH + col;
    xbase[r] = (size_t)(b0 + lg * 4 + r) * TSL * G4H + col * 4;
  }

  float c[4];
  if (t0 == 0) {
    #pragma unroll
    for (int r = 0; r < 4; ++r) c[r] = 0.f;
    if (tid < 512) { bf16x8 z = {}; ((bf16x8*)hbuf[0])[tid] = z; }
  } else {
    #pragma unroll
    for (int r = 0; r < 4; ++r) {
      const int m = lg * 4 + r;
      c[r] = cws[(size_t)(b0 + m) * HH + col];
      const bf16 hv = hreg[((size_t)(b0 + m) * SS + (t0 - 1)) * HH + col];
      hbuf[0][(((w >> 1) * 64) + m * 4 + (w & 1) * 2 + (ln >> 3)) * 8 + (ln & 7)] = hv;
    }
  }
  __syncthreads();

  #pragma unroll 1
  for (int tt = 0; tt < TSL; ++tt) {
    const int t = t0 + tt, p = tt & 1;
    ushort4 tj[4];
    #pragma unroll
    for (int r = 0; r < 4; ++r)
      tj[r] = *(const ushort4*)(xg + xbase[r] + (size_t)tt * G4H);
    bf16x8 wA0 = g0[0], wA1 = g1[0], wA2 = g2[0];
    bf16x8 wB0 = g0[64], wB1 = g1[64], wB2 = g2[64];
    f32x4 acc[4] = {};
    #pragma unroll
    for (int kc = 0; kc < 8; ++kc) {
      bf16x8 a = ((const bf16x8*)hbuf[p])[kc * 64 + ln * 4 + lg];
      bf16x8 c0 = (kc & 1) ? wB0 : wA0;
      bf16x8 c1 = (kc & 1) ? wB1 : wA1;
      bf16x8 c2 = (kc & 1) ? wB2 : wA2;
      if (kc + 2 < 8) {
        if (kc & 1) { wB0 = g0[(kc + 2) * 64]; wB1 = g1[(kc + 2) * 64]; wB2 = g2[(kc + 2) * 64]; }
        else        { wA0 = g0[(kc + 2) * 64]; wA1 = g1[(kc + 2) * 64]; wA2 = g2[(kc + 2) * 64]; }
      }
      acc[0] = __builtin_amdgcn_mfma_f32_16x16x32_bf16(a, c0, acc[0], 0, 0, 0);
      acc[1] = __builtin_amdgcn_mfma_f32_16x16x32_bf16(a, c1, acc[1], 0, 0, 0);
      acc[2] = __builtin_amdgcn_mfma_f32_16x16x32_bf16(a, c2, acc[2], 0, 0, 0);
      bf16x8 ow = wlds[(w * 8 + kc) * 64 + l];
      acc[3] = __builtin_amdgcn_mfma_f32_16x16x32_bf16(a, ow, acc[3], 0, 0, 0);
    }
    #pragma unroll
    for (int r = 0; r < 4; ++r) {
      const float fg = sigf(acc[0][r] + bf2f(tj[r].x));
      const float ig = sigf(acc[1][r] + bf2f(tj[r].y));
      const float gg = tanh_(acc[2][r] + bf2f(tj[r].z));
      const float og = sigf(acc[3][r] + bf2f(tj[r].w));
      const float cc = fg * c[r] + ig * gg;
      c[r] = cc;
      const bf16 hv = (bf16)(og * tanh_(cc));
      const int m = lg * 4 + r;
      hbuf[p ^ 1][(((w >> 1) * 64) + m * 4 + (w & 1) * 2 + (ln >> 3)) * 8 + (ln & 7)] = hv;
      hreg[hoff[r] + t * HH] = hv;
    }
    __syncthreads();
  }
  #pragma unroll
  for (int r = 0; r < 4; ++r)
    cws[(size_t)(b0 + lg * 4 + r) * HH + col] = c[r];
}

// ---------------------------------------------------------------------------
// Tiled GEMM 128x128, K=256, 8 waves, XOR-swizzled LDS.
// OUT_BF16==1: xg slice -> bf16 gate-interleaved layout [(n&255)*4 + n>>8].
// OUT_BF16==0: proj -> fp32 [row*VV + n].
// ---------------------------------------------------------------------------
template <int OUT_BF16>
__global__ __launch_bounds__(512)
void gemm_kernel(const bf16* __restrict__ A, const float* __restrict__ W,
                 const float* __restrict__ bias0, const float* __restrict__ bias1,
                 void* __restrict__ out, int t0, int NCOL) {
  __shared__ bf16x8 alds[4096];   // 128 rows x 32 granules(16B)
  __shared__ bf16x8 blds[4096];
  const int tid = threadIdx.x, w = tid >> 6, l = tid & 63, lg = l >> 4, ln = l & 15;
  const int wm = w & 1, wn = w >> 1;
  const int R0 = blockIdx.x * 128, N0 = blockIdx.y * 128;
  {
    const int row = tid >> 2, seg = tid & 3;   // 4 thr/row, 64 cols each
    const bf16* asrc;
    if (OUT_BF16) {
      const int R = R0 + row;
      asrc = A + ((size_t)(R >> 6) * SS + t0 + (R & 63)) * HH + seg * 64;
    } else {
      asrc = A + ((size_t)R0 + row) * HH + seg * 64;
    }
    #pragma unroll
    for (int k = 0; k < 8; ++k) {
      const int g = seg * 8 + k;
      alds[row * 32 + (g ^ (row & 7))] = *(const bf16x8*)(asrc + k * 8);
    }
    const float* bsrc = W + (size_t)(N0 + row) * HH + seg * 64;
    #pragma unroll
    for (int k = 0; k < 8; ++k) {
      const int g = seg * 8 + k;
      blds[row * 32 + (g ^ (row & 7))] = cvt8(bsrc + k * 8);
    }
  }
  __syncthreads();
  f32x4 acc[4][2] = {};
  #pragma unroll
  for (int kc = 0; kc < 8; ++kc) {
    bf16x8 bfr[2];
    #pragma unroll
    for (int nt = 0; nt < 2; ++nt) {
      const int row = wn * 32 + nt * 16 + ln;
      bfr[nt] = blds[row * 32 + ((kc * 4 + lg) ^ (row & 7))];
    }
    #pragma unroll
    for (int mt = 0; mt < 4; ++mt) {
      const int row = wm * 64 + mt * 16 + ln;
      bf16x8 a = alds[row * 32 + ((kc * 4 + lg) ^ (row & 7))];
      #pragma unroll
      for (int nt = 0; nt < 2; ++nt)
        acc[mt][nt] = __builtin_amdgcn_mfma_f32_16x16x32_bf16(a, bfr[nt], acc[mt][nt], 0, 0, 0);
    }
  }
  #pragma unroll
  for (int nt = 0; nt < 2; ++nt) {
    const int n = N0 + wn * 32 + nt * 16 + ln;
    const float bv = bias0[n] + (bias1 ? bias1[n] : 0.f);
    const int col = OUT_BF16 ? ((n & 255) * 4 + (n >> 8)) : n;
    #pragma unroll
    for (int mt = 0; mt < 4; ++mt)
      #pragma unroll
      for (int r = 0; r < 4; ++r) {
        const size_t row = (size_t)R0 + wm * 64 + mt * 16 + lg * 4 + r;
        if (OUT_BF16) ((bf16*)out)[row * NCOL + col] = (bf16)(acc[mt][nt][r] + bv);
        else          ((float*)out)[row * NCOL + col] = acc[mt][nt][r] + bv;
      }
  }
}

extern "C" void kernel_launch(void* const* d_in, const int* in_sizes, int n_in,
                              void* d_out, int out_size, void* d_ws, size_t ws_size,
                              hipStream_t stream) {
  const int*   x   = (const int*)d_in[0];
  const float* emb = (const float*)d_in[1];
  const float* Wi0 = (const float*)d_in[2];
  const float* bi0 = (const float*)d_in[3];
  const float* Wh0 = (const float*)d_in[4];
  const float* bh0 = (const float*)d_in[5];
  const float* Wi1 = (const float*)d_in[6];
  const float* bi1 = (const float*)d_in[7];
  const float* Wh1 = (const float*)d_in[8];
  const float* bh1 = (const float*)d_in[9];
  const float* Wg  = (const float*)d_in[10];
  const float* bg  = (const float*)d_in[11];

  // ws: [flag 256B][table bf16 256KB][wbuf0 512KB][wbuf1 512KB][hreg bf16 128MB]
  char* ws = (char*)d_ws;
  int* flag = (int*)ws;
  unsigned short* table = (unsigned short*)(ws + 256);
  bf16x8* wb0 = (bf16x8*)(ws + 256 + 262144);
  bf16x8* wb1 = (bf16x8*)(ws + 256 + 262144 + 524288);
  bf16* hreg = (bf16*)(ws + 256 + 262144 + 524288 + 524288);
  const size_t need = 256 + 262144 + 524288 + 524288
                    + (size_t)BB * SS * HH * sizeof(bf16);
  if (ws_size < need) return;

  // d_out as scratch until proj: [xg slice 67.1MB][cws 512KB]
  unsigned short* xg = (unsigned short*)d_out;
  float* cws = (float*)((char*)d_out + (size_t)BB * TSL * G4H * sizeof(bf16));

  (void)hipMemsetAsync(flag, 0, sizeof(int), stream);
  detect_kernel<<<dim3(8), dim3(256), 0, stream>>>(x, flag);
  table_kernel<<<dim3(4, 128), dim3(256), 0, stream>>>(emb, Wi0, bi0, bh0, table);
  wprep_kernel<<<dim3(128, 2), dim3(256), 0, stream>>>(Wh0, Wh1, wb0, wb1);
  rec0_kernel<<<dim3(BB / 16), dim3(1024), 0, stream>>>(x, flag, wb0, table, hreg);
  for (int s = 0; s < NSEG; ++s) {
    const int t0 = s * TSL;
    gemm_kernel<1><<<dim3(BB * TSL / 128, G4H / 128), dim3(512), 0, stream>>>(
        hreg, Wi1, bi1, bh1, xg, t0, G4H);
    rec1_kernel<<<dim3(BB / 16), dim3(1024), 0, stream>>>(xg, wb1, hreg, cws, t0);
  }
  gemm_kernel<0><<<dim3(BB * SS / 128, VV / 128), dim3(512), 0, stream>>>(
      hreg, Wg, bg, nullptr, d_out, 0, VV);
}

// Round 16
// 4884.383 us; speedup vs baseline: 1.4304x; 1.0103x over previous
//
#include <hip/hip_runtime.h>
#include <hip/hip_bf16.h>

#define BB 512
#define SS 512
#define EE 128
#define HH 256
#define VV 128
#define G4H 1024
#define TSL 64              // rec1 time-slice length
#define NSEG (SS / TSL)     // 8

using bf16 = __bf16;
typedef __attribute__((ext_vector_type(8))) __bf16 bf16x8;
typedef __attribute__((ext_vector_type(4))) float f32x4;

__device__ __forceinline__ float rcpf(float x) { return __builtin_amdgcn_rcpf(x); }
__device__ __forceinline__ float exp2f_(float x) { return __builtin_amdgcn_exp2f(x); }
__device__ __forceinline__ float sigf(float x) {
  return rcpf(1.0f + exp2f_(-1.442695041f * x));
}
__device__ __forceinline__ float tanh_(float x) {
  return 2.0f * rcpf(1.0f + exp2f_(-2.885390082f * x)) - 1.0f;
}
__device__ __forceinline__ bf16x8 cvt8(const float* __restrict__ s) {
  bf16x8 f;
  #pragma unroll
  for (int j = 0; j < 8; ++j) f[j] = (bf16)s[j];
  return f;
}
__device__ __forceinline__ float bf2f(unsigned short u) {
  return __uint_as_float(((unsigned)u) << 16);
}

// ---------------------------------------------------------------------------
// x dtype sniffer (validated R4): odd 32-bit words all zero <=> int64.
// ---------------------------------------------------------------------------
__global__ void detect_kernel(const int* __restrict__ x, int* __restrict__ flag) {
  const int i = blockIdx.x * 256 + threadIdx.x;
  if (x[2 * i + 1] != 0) atomicOr(flag, 1);
}

// ---------------------------------------------------------------------------
// Gate-interleaved bf16 table: table[v][u*4+q] = emb[v,:].Wi0[q*256+u,:] + biases
// ---------------------------------------------------------------------------
__global__ __launch_bounds__(256)
void table_kernel(const float* __restrict__ emb, const float* __restrict__ Wi,
                  const float* __restrict__ bi, const float* __restrict__ bh,
                  unsigned short* __restrict__ table) {
  const int g = blockIdx.x * 256 + threadIdx.x;  // 0..1023
  const int v = blockIdx.y;                      // 0..127
  float s = bi[g] + bh[g];
  const float* er = emb + v * EE;
  const float* wr = Wi + (size_t)g * EE;
  #pragma unroll 4
  for (int e = 0; e < EE; ++e) s += er[e] * wr[e];
  const bf16 b = (bf16)s;
  table[v * G4H + (g & 255) * 4 + (g >> 8)] = *(const unsigned short*)&b;
}

// ---------------------------------------------------------------------------
// Weight prep for the 16-wave scheme: Wh (fp32 [1024][256]) -> bf16 granules.
// Granule index = w16*2048 + q*512 + kc*64 + l  (16B each, 512KB/layer).
// Wave w16 owns hidden cols [16*w16, 16*w16+16); slot q = gate.
// Granule (w16,q,kc,l=(lg,ln)) holds Wh[q*256 + w16*16 + ln][kc*32+lg*8 ..+8).
// ---------------------------------------------------------------------------
__global__ __launch_bounds__(256)
void wprep_kernel(const float* __restrict__ Wh0, const float* __restrict__ Wh1,
                  bf16x8* __restrict__ wb0, bf16x8* __restrict__ wb1) {
  const int idx = blockIdx.x * 256 + threadIdx.x;   // 0..32767
  const int l = idx & 63, kc = (idx >> 6) & 7, q = (idx >> 9) & 3, w16 = idx >> 11;
  const int lg = l >> 4, ln = l & 15;
  const int n = q * HH + w16 * 16 + ln;
  const int k0 = kc * 32 + lg * 8;
  const float* src = (blockIdx.y ? Wh1 : Wh0) + (size_t)n * HH + k0;
  (blockIdx.y ? wb1 : wb0)[idx] = cvt8(src);
}

// ---------------------------------------------------------------------------
// MFMA recurrence layer 0. 32 WGs x 1024 thr (16 waves, 4/SIMD).
// Wave w owns 16 hidden cols x 4 gates:
//   q=0 (f): VGPR-RESIDENT Wres[8] (32 regs; 64 base + 32 = 96 <= 128 cap,
//            so the allocator has no pressure to demote -- the key experiment)
//   q=3 (o): LDS-resident (128 KB total)
//   q=1,2 (i,g): streamed from L2 bf16 wb with distance-2 pipeline.
// Port traffic: 2 slots x 8KB x 16 waves = 256KB/WG/step (was 384KB).
// ---------------------------------------------------------------------------
__global__ __launch_bounds__(1024)
void rec0_kernel(const int* __restrict__ x, const int* __restrict__ flagp,
                 const bf16x8* __restrict__ wb,
                 const unsigned short* __restrict__ table,
                 bf16* __restrict__ h1) {
  __shared__ bf16 hbuf[2][4096];     // 16 KB
  __shared__ bf16x8 wlds[8192];      // 128 KB: o-gate, 16 waves x 512 granules
  const int tid = threadIdx.x, w = tid >> 6, l = tid & 63, lg = l >> 4, ln = l & 15;
  const int b0 = blockIdx.x * 16;
  const int col = w * 16 + ln;       // this lane's hidden column
  const int is32 = *flagp;

  // f-gate: VGPR-resident (32 regs)
  bf16x8 Wres[8];
  #pragma unroll
  for (int kc = 0; kc < 8; ++kc) Wres[kc] = wb[w * 2048 + 0 * 512 + kc * 64 + l];
  #pragma unroll
  for (int kc = 0; kc < 8; ++kc)     // o-gate -> LDS
    wlds[(w * 8 + kc) * 64 + l] = wb[w * 2048 + 3 * 512 + kc * 64 + l];
  const bf16x8* __restrict__ g1 = wb + w * 2048 + 1 * 512 + l;   // i
  const bf16x8* __restrict__ g2 = wb + w * 2048 + 2 * 512 + l;   // g

  if (tid < 512) { bf16x8 z = {}; ((bf16x8*)hbuf[0])[tid] = z; }
  float c[4] = {0.f, 0.f, 0.f, 0.f};

  int hoff[4];
  #pragma unroll
  for (int r = 0; r < 4; ++r)
    hoff[r] = ((b0 + lg * 4 + r) * SS) * HH + col;

  int idx[4];
  #pragma unroll
  for (int r = 0; r < 4; ++r) {
    const long xi = (long)(b0 + lg * 4 + r) * SS;
    idx[r] = x[is32 ? xi : 2 * xi] & 127;
  }
  __syncthreads();

  #pragma unroll 1
  for (int t = 0; t < SS; ++t) {
    const int p = t & 1;
    // table gather for step t (one ushort4 per row: 4 gates interleaved)
    ushort4 tj[4];
    #pragma unroll
    for (int r = 0; r < 4; ++r)
      tj[r] = *(const ushort4*)(table + (size_t)idx[r] * G4H + col * 4);
    // prefetch x indices for t+1
    if (t + 1 < SS) {
      #pragma unroll
      for (int r = 0; r < 4; ++r) {
        const long xi = (long)(b0 + lg * 4 + r) * SS + (t + 1);
        idx[r] = x[is32 ? xi : 2 * xi] & 127;
      }
    }
    // distance-2 stream pipeline over kc for i,g gates
    bf16x8 wA1 = g1[0], wA2 = g2[0];
    bf16x8 wB1 = g1[64], wB2 = g2[64];
    f32x4 acc[4] = {};
    #pragma unroll
    for (int kc = 0; kc < 8; ++kc) {
      bf16x8 a = ((const bf16x8*)hbuf[p])[kc * 64 + ln * 4 + lg];
      bf16x8 c1 = (kc & 1) ? wB1 : wA1;
      bf16x8 c2 = (kc & 1) ? wB2 : wA2;
      if (kc + 2 < 8) {
        if (kc & 1) { wB1 = g1[(kc + 2) * 64]; wB2 = g2[(kc + 2) * 64]; }
        else        { wA1 = g1[(kc + 2) * 64]; wA2 = g2[(kc + 2) * 64]; }
      }
      acc[0] = __builtin_amdgcn_mfma_f32_16x16x32_bf16(a, Wres[kc], acc[0], 0, 0, 0);
      acc[1] = __builtin_amdgcn_mfma_f32_16x16x32_bf16(a, c1, acc[1], 0, 0, 0);
      acc[2] = __builtin_amdgcn_mfma_f32_16x16x32_bf16(a, c2, acc[2], 0, 0, 0);
      bf16x8 ow = wlds[(w * 8 + kc) * 64 + l];
      acc[3] = __builtin_amdgcn_mfma_f32_16x16x32_bf16(a, ow, acc[3], 0, 0, 0);
    }
    // epilogue: 4 h-values per lane (rows lg*4+r, column `col`)
    #pragma unroll
    for (int r = 0; r < 4; ++r) {
      const float fg = sigf(acc[0][r] + bf2f(tj[r].x));
      const float ig = sigf(acc[1][r] + bf2f(tj[r].y));
      const float gg = tanh_(acc[2][r] + bf2f(tj[r].z));
      const float og = sigf(acc[3][r] + bf2f(tj[r].w));
      const float cc = fg * c[r] + ig * gg;
      c[r] = cc;
      const bf16 hv = (bf16)(og * tanh_(cc));
      const int m = lg * 4 + r;
      hbuf[p ^ 1][(((w >> 1) * 64) + m * 4 + (w & 1) * 2 + (ln >> 3)) * 8 + (ln & 7)] = hv;
      h1[hoff[r] + t * HH] = hv;
    }
    __syncthreads();
  }
}

// ---------------------------------------------------------------------------
// MFMA recurrence layer 1, one time-slice [t0,t0+TSL). Same geometry;
// gate init gathered from gate-interleaved bf16 xg (includes bi1+bh1).
// ---------------------------------------------------------------------------
__global__ __launch_bounds__(1024)
void rec1_kernel(const unsigned short* __restrict__ xg, const bf16x8* __restrict__ wb,
                 bf16* __restrict__ hreg, float* __restrict__ cws, int t0) {
  __shared__ bf16 hbuf[2][4096];
  __shared__ bf16x8 wlds[8192];
  const int tid = threadIdx.x, w = tid >> 6, l = tid & 63, lg = l >> 4, ln = l & 15;
  const int b0 = blockIdx.x * 16;
  const int col = w * 16 + ln;

  bf16x8 Wres[8];
  #pragma unroll
  for (int kc = 0; kc < 8; ++kc) Wres[kc] = wb[w * 2048 + 0 * 512 + kc * 64 + l];
  #pragma unroll
  for (int kc = 0; kc < 8; ++kc)
    wlds[(w * 8 + kc) * 64 + l] = wb[w * 2048 + 3 * 512 + kc * 64 + l];
  const bf16x8* __restrict__ g1 = wb + w * 2048 + 1 * 512 + l;
  const bf16x8* __restrict__ g2 = wb + w * 2048 + 2 * 512 + l;

  int hoff[4];
  size_t xbase[4];
  #pragma unroll
  for (int r = 0; r < 4; ++r) {
    hoff[r] = ((b0 + lg * 4 + r) * SS) * HH + col;
    xbase[r] = (size_t)(b0 + lg * 4 + r) * TSL * G4H + col * 4;
  }

  float c[4];
  if (t0 == 0) {
    #pragma unroll
    for (int r = 0; r < 4; ++r) c[r] = 0.f;
    if (tid < 512) { bf16x8 z = {}; ((bf16x8*)hbuf[0])[tid] = z; }
  } else {
    #pragma unroll
    for (int r = 0; r < 4; ++r) {
      const int m = lg * 4 + r;
      c[r] = cws[(size_t)(b0 + m) * HH + col];
      const bf16 hv = hreg[((size_t)(b0 + m) * SS + (t0 - 1)) * HH + col];
      hbuf[0][(((w >> 1) * 64) + m * 4 + (w & 1) * 2 + (ln >> 3)) * 8 + (ln & 7)] = hv;
    }
  }
  __syncthreads();

  #pragma unroll 1
  for (int tt = 0; tt < TSL; ++tt) {
    const int t = t0 + tt, p = tt & 1;
    ushort4 tj[4];
    #pragma unroll
    for (int r = 0; r < 4; ++r)
      tj[r] = *(const ushort4*)(xg + xbase[r] + (size_t)tt * G4H);
    bf16x8 wA1 = g1[0], wA2 = g2[0];
    bf16x8 wB1 = g1[64], wB2 = g2[64];
    f32x4 acc[4] = {};
    #pragma unroll
    for (int kc = 0; kc < 8; ++kc) {
      bf16x8 a = ((const bf16x8*)hbuf[p])[kc * 64 + ln * 4 + lg];
      bf16x8 c1 = (kc & 1) ? wB1 : wA1;
      bf16x8 c2 = (kc & 1) ? wB2 : wA2;
      if (kc + 2 < 8) {
        if (kc & 1) { wB1 = g1[(kc + 2) * 64]; wB2 = g2[(kc + 2) * 64]; }
        else        { wA1 = g1[(kc + 2) * 64]; wA2 = g2[(kc + 2) * 64]; }
      }
      acc[0] = __builtin_amdgcn_mfma_f32_16x16x32_bf16(a, Wres[kc], acc[0], 0, 0, 0);
      acc[1] = __builtin_amdgcn_mfma_f32_16x16x32_bf16(a, c1, acc[1], 0, 0, 0);
      acc[2] = __builtin_amdgcn_mfma_f32_16x16x32_bf16(a, c2, acc[2], 0, 0, 0);
      bf16x8 ow = wlds[(w * 8 + kc) * 64 + l];
      acc[3] = __builtin_amdgcn_mfma_f32_16x16x32_bf16(a, ow, acc[3], 0, 0, 0);
    }
    #pragma unroll
    for (int r = 0; r < 4; ++r) {
      const float fg = sigf(acc[0][r] + bf2f(tj[r].x));
      const float ig = sigf(acc[1][r] + bf2f(tj[r].y));
      const float gg = tanh_(acc[2][r] + bf2f(tj[r].z));
      const float og = sigf(acc[3][r] + bf2f(tj[r].w));
      const float cc = fg * c[r] + ig * gg;
      c[r] = cc;
      const bf16 hv = (bf16)(og * tanh_(cc));
      const int m = lg * 4 + r;
      hbuf[p ^ 1][(((w >> 1) * 64) + m * 4 + (w & 1) * 2 + (ln >> 3)) * 8 + (ln & 7)] = hv;
      hreg[hoff[r] + t * HH] = hv;
    }
    __syncthreads();
  }
  #pragma unroll
  for (int r = 0; r < 4; ++r)
    cws[(size_t)(b0 + lg * 4 + r) * HH + col] = c[r];
}

// ---------------------------------------------------------------------------
// Tiled GEMM 128x128, K=256, 8 waves, XOR-swizzled LDS.
// OUT_BF16==1: xg slice -> bf16 gate-interleaved layout [(n&255)*4 + n>>8].
// OUT_BF16==0: proj -> fp32 [row*VV + n].
// ---------------------------------------------------------------------------
template <int OUT_BF16>
__global__ __launch_bounds__(512)
void gemm_kernel(const bf16* __restrict__ A, const float* __restrict__ W,
                 const float* __restrict__ bias0, const float* __restrict__ bias1,
                 void* __restrict__ out, int t0, int NCOL) {
  __shared__ bf16x8 alds[4096];   // 128 rows x 32 granules(16B)
  __shared__ bf16x8 blds[4096];
  const int tid = threadIdx.x, w = tid >> 6, l = tid & 63, lg = l >> 4, ln = l & 15;
  const int wm = w & 1, wn = w >> 1;
  const int R0 = blockIdx.x * 128, N0 = blockIdx.y * 128;
  {
    const int row = tid >> 2, seg = tid & 3;   // 4 thr/row, 64 cols each
    const bf16* asrc;
    if (OUT_BF16) {
      const int R = R0 + row;
      asrc = A + ((size_t)(R >> 6) * SS + t0 + (R & 63)) * HH + seg * 64;
    } else {
      asrc = A + ((size_t)R0 + row) * HH + seg * 64;
    }
    #pragma unroll
    for (int k = 0; k < 8; ++k) {
      const int g = seg * 8 + k;
      alds[row * 32 + (g ^ (row & 7))] = *(const bf16x8*)(asrc + k * 8);
    }
    const float* bsrc = W + (size_t)(N0 + row) * HH + seg * 64;
    #pragma unroll
    for (int k = 0; k < 8; ++k) {
      const int g = seg * 8 + k;
      blds[row * 32 + (g ^ (row & 7))] = cvt8(bsrc + k * 8);
    }
  }
  __syncthreads();
  f32x4 acc[4][2] = {};
  #pragma unroll
  for (int kc = 0; kc < 8; ++kc) {
    bf16x8 bfr[2];
    #pragma unroll
    for (int nt = 0; nt < 2; ++nt) {
      const int row = wn * 32 + nt * 16 + ln;
      bfr[nt] = blds[row * 32 + ((kc * 4 + lg) ^ (row & 7))];
    }
    #pragma unroll
    for (int mt = 0; mt < 4; ++mt) {
      const int row = wm * 64 + mt * 16 + ln;
      bf16x8 a = alds[row * 32 + ((kc * 4 + lg) ^ (row & 7))];
      #pragma unroll
      for (int nt = 0; nt < 2; ++nt)
        acc[mt][nt] = __builtin_amdgcn_mfma_f32_16x16x32_bf16(a, bfr[nt], acc[mt][nt], 0, 0, 0);
    }
  }
  #pragma unroll
  for (int nt = 0; nt < 2; ++nt) {
    const int n = N0 + wn * 32 + nt * 16 + ln;
    const float bv = bias0[n] + (bias1 ? bias1[n] : 0.f);
    const int col = OUT_BF16 ? ((n & 255) * 4 + (n >> 8)) : n;
    #pragma unroll
    for (int mt = 0; mt < 4; ++mt)
      #pragma unroll
      for (int r = 0; r < 4; ++r) {
        const size_t row = (size_t)R0 + wm * 64 + mt * 16 + lg * 4 + r;
        if (OUT_BF16) ((bf16*)out)[row * NCOL + col] = (bf16)(acc[mt][nt][r] + bv);
        else          ((float*)out)[row * NCOL + col] = acc[mt][nt][r] + bv;
      }
  }
}

extern "C" void kernel_launch(void* const* d_in, const int* in_sizes, int n_in,
                              void* d_out, int out_size, void* d_ws, size_t ws_size,
                              hipStream_t stream) {
  const int*   x   = (const int*)d_in[0];
  const float* emb = (const float*)d_in[1];
  const float* Wi0 = (const float*)d_in[2];
  const float* bi0 = (const float*)d_in[3];
  const float* Wh0 = (const float*)d_in[4];
  const float* bh0 = (const float*)d_in[5];
  const float* Wi1 = (const float*)d_in[6];
  const float* bi1 = (const float*)d_in[7];
  const float* Wh1 = (const float*)d_in[8];
  const float* bh1 = (const float*)d_in[9];
  const float* Wg  = (const float*)d_in[10];
  const float* bg  = (const float*)d_in[11];

  // ws: [flag 256B][table bf16 256KB][wbuf0 512KB][wbuf1 512KB][hreg bf16 128MB]
  char* ws = (char*)d_ws;
  int* flag = (int*)ws;
  unsigned short* table = (unsigned short*)(ws + 256);
  bf16x8* wb0 = (bf16x8*)(ws + 256 + 262144);
  bf16x8* wb1 = (bf16x8*)(ws + 256 + 262144 + 524288);
  bf16* hreg = (bf16*)(ws + 256 + 262144 + 524288 + 524288);
  const size_t need = 256 + 262144 + 524288 + 524288
                    + (size_t)BB * SS * HH * sizeof(bf16);
  if (ws_size < need) return;

  // d_out as scratch until proj: [xg slice 67.1MB][cws 512KB]
  unsigned short* xg = (unsigned short*)d_out;
  float* cws = (float*)((char*)d_out + (size_t)BB * TSL * G4H * sizeof(bf16));

  (void)hipMemsetAsync(flag, 0, sizeof(int), stream);
  detect_kernel<<<dim3(8), dim3(256), 0, stream>>>(x, flag);
  table_kernel<<<dim3(4, 128), dim3(256), 0, stream>>>(emb, Wi0, bi0, bh0, table);
  wprep_kernel<<<dim3(128, 2), dim3(256), 0, stream>>>(Wh0, Wh1, wb0, wb1);
  rec0_kernel<<<dim3(BB / 16), dim3(1024), 0, stream>>>(x, flag, wb0, table, hreg);
  for (int s = 0; s < NSEG; ++s) {
    const int t0 = s * TSL;
    gemm_kernel<1><<<dim3(BB * TSL / 128, G4H / 128), dim3(512), 0, stream>>>(
        hreg, Wi1, bi1, bh1, xg, t0, G4H);
    rec1_kernel<<<dim3(BB / 16), dim3(1024), 0, stream>>>(xg, wb1, hreg, cws, t0);
  }
  gemm_kernel<0><<<dim3(BB * SS / 128, VV / 128), dim3(512), 0, stream>>>(
      hreg, Wg, bg, nullptr, d_out, 0, VV);
}

// Round 18
// 3917.261 us; speedup vs baseline: 1.7836x; 1.2469x over previous
//
#include <hip/hip_runtime.h>
#include <hip/hip_bf16.h>

#define BB 512
#define SS 512
#define EE 128
#define HH 256
#define VV 128
#define G4H 1024
#define TSL 64              // rec1 time-slice length
#define NSEG (SS / TSL)     // 8

using bf16 = __bf16;
typedef __attribute__((ext_vector_type(8))) __bf16 bf16x8;
typedef __attribute__((ext_vector_type(4))) float f32x4;

__device__ __forceinline__ float rcpf(float x) { return __builtin_amdgcn_rcpf(x); }
__device__ __forceinline__ float exp2f_(float x) { return __builtin_amdgcn_exp2f(x); }
__device__ __forceinline__ float sigf(float x) {
  return rcpf(1.0f + exp2f_(-1.442695041f * x));
}
__device__ __forceinline__ float tanh_(float x) {
  return 2.0f * rcpf(1.0f + exp2f_(-2.885390082f * x)) - 1.0f;
}
__device__ __forceinline__ bf16x8 cvt8(const float* __restrict__ s) {
  bf16x8 f;
  #pragma unroll
  for (int j = 0; j < 8; ++j) f[j] = (bf16)s[j];
  return f;
}
__device__ __forceinline__ float bf2f(unsigned short u) {
  return __uint_as_float(((unsigned)u) << 16);
}

// ---------------------------------------------------------------------------
// x dtype sniffer (validated R4): odd 32-bit words all zero <=> int64.
// ---------------------------------------------------------------------------
__global__ void detect_kernel(const int* __restrict__ x, int* __restrict__ flag) {
  const int i = blockIdx.x * 256 + threadIdx.x;
  if (x[2 * i + 1] != 0) atomicOr(flag, 1);
}

// ---------------------------------------------------------------------------
// Gate-interleaved bf16 table: table[v][u*4+q] = emb[v,:].Wi0[q*256+u,:] + biases
// ---------------------------------------------------------------------------
__global__ __launch_bounds__(256)
void table_kernel(const float* __restrict__ emb, const float* __restrict__ Wi,
                  const float* __restrict__ bi, const float* __restrict__ bh,
                  unsigned short* __restrict__ table) {
  const int g = blockIdx.x * 256 + threadIdx.x;  // 0..1023
  const int v = blockIdx.y;                      // 0..127
  float s = bi[g] + bh[g];
  const float* er = emb + v * EE;
  const float* wr = Wi + (size_t)g * EE;
  #pragma unroll 4
  for (int e = 0; e < EE; ++e) s += er[e] * wr[e];
  const bf16 b = (bf16)s;
  table[v * G4H + (g & 255) * 4 + (g >> 8)] = *(const unsigned short*)&b;
}

// ---------------------------------------------------------------------------
// Weight prep (R11-verified): Wh (fp32 [1024][256]) -> bf16 MFMA granules.
// Granule index = w*4096 + s*512 + kc*64 + l (16B each, 512KB/layer).
// Slot s -> (gate q = s>>1, col-half j = s&1); lane l=(lg,ln):
//   granule holds Wh[q*256 + w*32 + 16j + ln][kc*32 + lg*8 .. +8).
// ---------------------------------------------------------------------------
__global__ __launch_bounds__(256)
void wprep_kernel(const float* __restrict__ Wh0, const float* __restrict__ Wh1,
                  bf16x8* __restrict__ wb0, bf16x8* __restrict__ wb1) {
  const int idx = blockIdx.x * 256 + threadIdx.x;   // 0..32767
  const int l = idx & 63, kc = (idx >> 6) & 7, s = (idx >> 9) & 7, w = idx >> 12;
  const int lg = l >> 4, ln = l & 15;
  const int n = (s >> 1) * HH + w * 32 + 16 * (s & 1) + ln;
  const int k0 = kc * 32 + lg * 8;
  const float* src = (blockIdx.y ? Wh1 : Wh0) + (size_t)n * HH + k0;
  (blockIdx.y ? wb1 : wb0)[idx] = cvt8(src);
}

// ---------------------------------------------------------------------------
// MFMA recurrence layer 0 (R11 verbatim, 4450us-proven). 32 WGs x 512 thr.
//   slots 0-3 (f,i): compiler-managed (streams from L2 as it chooses)
//   slots 4,5 (g): streamed   slots 6,7 (o): LDS-resident
// ---------------------------------------------------------------------------
__global__ __launch_bounds__(512) __attribute__((amdgpu_waves_per_eu(2)))
void rec0_kernel(const int* __restrict__ x, const int* __restrict__ flagp,
                 const bf16x8* __restrict__ wb,
                 const unsigned short* __restrict__ table,
                 bf16* __restrict__ h1) {
  __shared__ bf16 hbuf[2][4096];
  __shared__ bf16x8 wlds[8192];      // 128KB o-gate weights
  const int tid = threadIdx.x, w = tid >> 6, l = tid & 63, lg = l >> 4, ln = l & 15;
  const int b0 = blockIdx.x * 16, hb = w * 32;
  const int is32 = *flagp;

  bf16x8 Wf[4][8];
  #pragma unroll
  for (int s = 0; s < 4; ++s)
    #pragma unroll
    for (int kc = 0; kc < 8; ++kc)
      Wf[s][kc] = wb[w * 4096 + s * 512 + kc * 64 + l];
  #pragma unroll
  for (int j = 0; j < 2; ++j)
    #pragma unroll
    for (int kc = 0; kc < 8; ++kc)
      wlds[((w * 2 + j) * 8 + kc) * 64 + l] = wb[w * 4096 + (6 + j) * 512 + kc * 64 + l];
  const bf16x8* __restrict__ gsrc0 = wb + w * 4096 + 4 * 512 + l;
  const bf16x8* __restrict__ gsrc1 = wb + w * 4096 + 5 * 512 + l;

  { bf16x8 z = {}; ((bf16x8*)hbuf[0])[tid] = z; }
  float c[2][4] = {};

  int hoff[4];
  #pragma unroll
  for (int r = 0; r < 4; ++r)
    hoff[r] = ((b0 + lg * 4 + r) * SS) * HH + hb + ln;

  int idx[4];
  #pragma unroll
  for (int r = 0; r < 4; ++r) {
    const long xi = (long)(b0 + lg * 4 + r) * SS;
    idx[r] = x[is32 ? xi : 2 * xi] & 127;
  }
  __syncthreads();

  #pragma unroll 1
  for (int t = 0; t < SS; ++t) {
    const int p = t & 1;
    ushort4 tj[4][2];
    #pragma unroll
    for (int r = 0; r < 4; ++r) {
      const unsigned short* base = table + (size_t)idx[r] * G4H + (hb + ln) * 4;
      tj[r][0] = *(const ushort4*)base;
      tj[r][1] = *(const ushort4*)(base + 64);
    }
    if (t + 1 < SS) {
      #pragma unroll
      for (int r = 0; r < 4; ++r) {
        const long xi = (long)(b0 + lg * 4 + r) * SS + (t + 1);
        idx[r] = x[is32 ? xi : 2 * xi] & 127;
      }
    }
    f32x4 acc[4][2] = {};
    #pragma unroll
    for (int kc = 0; kc < 8; ++kc) {
      bf16x8 a = ((const bf16x8*)hbuf[p])[kc * 64 + ln * 4 + lg];
      acc[0][0] = __builtin_amdgcn_mfma_f32_16x16x32_bf16(a, Wf[0][kc], acc[0][0], 0, 0, 0);
      acc[0][1] = __builtin_amdgcn_mfma_f32_16x16x32_bf16(a, Wf[1][kc], acc[0][1], 0, 0, 0);
      acc[1][0] = __builtin_amdgcn_mfma_f32_16x16x32_bf16(a, Wf[2][kc], acc[1][0], 0, 0, 0);
      acc[1][1] = __builtin_amdgcn_mfma_f32_16x16x32_bf16(a, Wf[3][kc], acc[1][1], 0, 0, 0);
      acc[2][0] = __builtin_amdgcn_mfma_f32_16x16x32_bf16(a, gsrc0[kc * 64], acc[2][0], 0, 0, 0);
      acc[2][1] = __builtin_amdgcn_mfma_f32_16x16x32_bf16(a, gsrc1[kc * 64], acc[2][1], 0, 0, 0);
      #pragma unroll
      for (int j = 0; j < 2; ++j) {
        bf16x8 bw = wlds[((w * 2 + j) * 8 + kc) * 64 + l];
        acc[3][j] = __builtin_amdgcn_mfma_f32_16x16x32_bf16(a, bw, acc[3][j], 0, 0, 0);
      }
    }
    #pragma unroll
    for (int j = 0; j < 2; ++j)
      #pragma unroll
      for (int r = 0; r < 4; ++r) {
        const float fg = sigf(acc[0][j][r] + bf2f(tj[r][j].x));
        const float ig = sigf(acc[1][j][r] + bf2f(tj[r][j].y));
        const float gg = tanh_(acc[2][j][r] + bf2f(tj[r][j].z));
        const float og = sigf(acc[3][j][r] + bf2f(tj[r][j].w));
        const float cc = fg * c[j][r] + ig * gg;
        c[j][r] = cc;
        const bf16 hv = (bf16)(og * tanh_(cc));
        const int m = lg * 4 + r;
        hbuf[p ^ 1][(w * 64 + m * 4 + 2 * j + (ln >> 3)) * 8 + (ln & 7)] = hv;
        h1[hoff[r] + t * HH + 16 * j] = hv;
      }
    __syncthreads();
  }
}

// ---------------------------------------------------------------------------
// rec1 body (R11 verbatim, parameterized by block id and smem arena).
// ---------------------------------------------------------------------------
__device__ __forceinline__
void rec1_body(char* smem, const unsigned short* __restrict__ xg,
               const bf16x8* __restrict__ wb, bf16* __restrict__ hreg,
               float* __restrict__ cws, int t0, int bid) {
  bf16 (*hbuf)[4096] = (bf16(*)[4096])smem;           // 16 KB
  bf16x8* wlds = (bf16x8*)(smem + 16384);             // 128 KB
  const int tid = threadIdx.x, w = tid >> 6, l = tid & 63, lg = l >> 4, ln = l & 15;
  const int b0 = bid * 16, hb = w * 32;

  bf16x8 Wf[4][8];
  #pragma unroll
  for (int s = 0; s < 4; ++s)
    #pragma unroll
    for (int kc = 0; kc < 8; ++kc)
      Wf[s][kc] = wb[w * 4096 + s * 512 + kc * 64 + l];
  #pragma unroll
  for (int j = 0; j < 2; ++j)
    #pragma unroll
    for (int kc = 0; kc < 8; ++kc)
      wlds[((w * 2 + j) * 8 + kc) * 64 + l] = wb[w * 4096 + (6 + j) * 512 + kc * 64 + l];
  const bf16x8* __restrict__ gsrc0 = wb + w * 4096 + 4 * 512 + l;
  const bf16x8* __restrict__ gsrc1 = wb + w * 4096 + 5 * 512 + l;

  int hoff[4];
  size_t xbase[4];
  #pragma unroll
  for (int r = 0; r < 4; ++r) {
    hoff[r] = ((b0 + lg * 4 + r) * SS) * HH + hb + ln;
    xbase[r] = (size_t)(b0 + lg * 4 + r) * TSL * G4H + (hb + ln) * 4;
  }

  float c[2][4];
  if (t0 == 0) {
    #pragma unroll
    for (int j = 0; j < 2; ++j)
      #pragma unroll
      for (int r = 0; r < 4; ++r) c[j][r] = 0.f;
    bf16x8 z = {};
    ((bf16x8*)&hbuf[0][0])[tid] = z;
  } else {
    #pragma unroll
    for (int j = 0; j < 2; ++j)
      #pragma unroll
      for (int r = 0; r < 4; ++r) {
        const int m = lg * 4 + r, col = hb + 16 * j + ln;
        c[j][r] = cws[(size_t)(b0 + m) * HH + col];
        const bf16 hv = hreg[((size_t)(b0 + m) * SS + (t0 - 1)) * HH + col];
        hbuf[0][(w * 64 + m * 4 + 2 * j + (ln >> 3)) * 8 + (ln & 7)] = hv;
      }
  }
  __syncthreads();

  #pragma unroll 1
  for (int tt = 0; tt < TSL; ++tt) {
    const int t = t0 + tt, p = tt & 1;
    ushort4 tj[4][2];
    #pragma unroll
    for (int r = 0; r < 4; ++r) {
      const unsigned short* base = xg + xbase[r] + (size_t)tt * G4H;
      tj[r][0] = *(const ushort4*)base;
      tj[r][1] = *(const ushort4*)(base + 64);
    }
    f32x4 acc[4][2] = {};
    #pragma unroll
    for (int kc = 0; kc < 8; ++kc) {
      bf16x8 a = ((const bf16x8*)&hbuf[p][0])[kc * 64 + ln * 4 + lg];
      acc[0][0] = __builtin_amdgcn_mfma_f32_16x16x32_bf16(a, Wf[0][kc], acc[0][0], 0, 0, 0);
      acc[0][1] = __builtin_amdgcn_mfma_f32_16x16x32_bf16(a, Wf[1][kc], acc[0][1], 0, 0, 0);
      acc[1][0] = __builtin_amdgcn_mfma_f32_16x16x32_bf16(a, Wf[2][kc], acc[1][0], 0, 0, 0);
      acc[1][1] = __builtin_amdgcn_mfma_f32_16x16x32_bf16(a, Wf[3][kc], acc[1][1], 0, 0, 0);
      acc[2][0] = __builtin_amdgcn_mfma_f32_16x16x32_bf16(a, gsrc0[kc * 64], acc[2][0], 0, 0, 0);
      acc[2][1] = __builtin_amdgcn_mfma_f32_16x16x32_bf16(a, gsrc1[kc * 64], acc[2][1], 0, 0, 0);
      #pragma unroll
      for (int j = 0; j < 2; ++j) {
        bf16x8 bw = wlds[((w * 2 + j) * 8 + kc) * 64 + l];
        acc[3][j] = __builtin_amdgcn_mfma_f32_16x16x32_bf16(a, bw, acc[3][j], 0, 0, 0);
      }
    }
    #pragma unroll
    for (int j = 0; j < 2; ++j)
      #pragma unroll
      for (int r = 0; r < 4; ++r) {
        const float fg = sigf(acc[0][j][r] + bf2f(tj[r][j].x));
        const float ig = sigf(acc[1][j][r] + bf2f(tj[r][j].y));
        const float gg = tanh_(acc[2][j][r] + bf2f(tj[r][j].z));
        const float og = sigf(acc[3][j][r] + bf2f(tj[r][j].w));
        const float cc = fg * c[j][r] + ig * gg;
        c[j][r] = cc;
        const bf16 hv = (bf16)(og * tanh_(cc));
        const int m = lg * 4 + r;
        hbuf[p ^ 1][(w * 64 + m * 4 + 2 * j + (ln >> 3)) * 8 + (ln & 7)] = hv;
        hreg[hoff[r] + t * HH + 16 * j] = hv;
      }
    __syncthreads();
  }
  #pragma unroll
  for (int j = 0; j < 2; ++j)
    #pragma unroll
    for (int r = 0; r < 4; ++r)
      cws[(size_t)(b0 + lg * 4 + r) * HH + hb + 16 * j + ln] = c[j][r];
}

// ---------------------------------------------------------------------------
// xg GEMM body (gemm<1> verbatim): 128x128 K=256 tile, XOR-swizzled LDS;
// writes bf16 gate-interleaved xg for slice starting at t0.
// ---------------------------------------------------------------------------
__device__ __forceinline__
void xg_body(char* smem, const bf16* __restrict__ A, const float* __restrict__ W,
             const float* __restrict__ bias0, const float* __restrict__ bias1,
             bf16* __restrict__ out, int t0, int flat) {
  bf16x8* alds = (bf16x8*)smem;                       // 64 KB
  bf16x8* blds = (bf16x8*)(smem + 65536);             // 64 KB
  const int tid = threadIdx.x, w = tid >> 6, l = tid & 63, lg = l >> 4, ln = l & 15;
  const int wm = w & 1, wn = w >> 1;
  const int R0 = (flat & 255) * 128, N0 = (flat >> 8) * 128;
  {
    const int row = tid >> 2, seg = tid & 3;
    const int R = R0 + row;
    const bf16* asrc = A + ((size_t)(R >> 6) * SS + t0 + (R & 63)) * HH + seg * 64;
    #pragma unroll
    for (int k = 0; k < 8; ++k) {
      const int g = seg * 8 + k;
      alds[row * 32 + (g ^ (row & 7))] = *(const bf16x8*)(asrc + k * 8);
    }
    const float* bsrc = W + (size_t)(N0 + row) * HH + seg * 64;
    #pragma unroll
    for (int k = 0; k < 8; ++k) {
      const int g = seg * 8 + k;
      blds[row * 32 + (g ^ (row & 7))] = cvt8(bsrc + k * 8);
    }
  }
  __syncthreads();
  f32x4 acc[4][2] = {};
  #pragma unroll
  for (int kc = 0; kc < 8; ++kc) {
    bf16x8 bfr[2];
    #pragma unroll
    for (int nt = 0; nt < 2; ++nt) {
      const int row = wn * 32 + nt * 16 + ln;
      bfr[nt] = blds[row * 32 + ((kc * 4 + lg) ^ (row & 7))];
    }
    #pragma unroll
    for (int mt = 0; mt < 4; ++mt) {
      const int row = wm * 64 + mt * 16 + ln;
      bf16x8 a = alds[row * 32 + ((kc * 4 + lg) ^ (row & 7))];
      #pragma unroll
      for (int nt = 0; nt < 2; ++nt)
        acc[mt][nt] = __builtin_amdgcn_mfma_f32_16x16x32_bf16(a, bfr[nt], acc[mt][nt], 0, 0, 0);
    }
  }
  #pragma unroll
  for (int nt = 0; nt < 2; ++nt) {
    const int n = N0 + wn * 32 + nt * 16 + ln;
    const float bv = bias0[n] + bias1[n];
    const int col = (n & 255) * 4 + (n >> 8);
    #pragma unroll
    for (int mt = 0; mt < 4; ++mt)
      #pragma unroll
      for (int r = 0; r < 4; ++r) {
        const size_t row = (size_t)R0 + wm * 64 + mt * 16 + lg * 4 + r;
        out[row * G4H + col] = (bf16)(acc[mt][nt][r] + bv);
      }
  }
}

// ---------------------------------------------------------------------------
// Combined slice kernel: blocks 0..31 run rec1(slice t0) on 32 CUs;
// blocks 32.. run xg GEMM for slice t0+TSL on the remaining CUs (concurrent:
// xg(s+1) reads h1 rows of slice s+1, disjoint from rec1(s)'s h2 writes).
// ---------------------------------------------------------------------------
__global__ __launch_bounds__(512)
void combo_kernel(const unsigned short* __restrict__ xg_in,
                  const bf16x8* __restrict__ wb, bf16* __restrict__ hreg,
                  float* __restrict__ cws, int t0,
                  const float* __restrict__ Wi, const float* __restrict__ bi,
                  const float* __restrict__ bh, bf16* __restrict__ xg_out) {
  __shared__ __align__(16) char smem[147456];
  if (blockIdx.x < 32)
    rec1_body(smem, xg_in, wb, hreg, cws, t0, blockIdx.x);
  else
    xg_body(smem, hreg, Wi, bi, bh, xg_out, t0 + TSL, blockIdx.x - 32);
}

// ---------------------------------------------------------------------------
// Standalone tiled GEMM (R11 verbatim): OUT_BF16==1 -> xg slice;
// OUT_BF16==0 -> proj fp32 [row*VV + n].
// ---------------------------------------------------------------------------
template <int OUT_BF16>
__global__ __launch_bounds__(512)
void gemm_kernel(const bf16* __restrict__ A, const float* __restrict__ W,
                 const float* __restrict__ bias0, const float* __restrict__ bias1,
                 void* __restrict__ out, int t0, int NCOL) {
  __shared__ bf16x8 alds[4096];
  __shared__ bf16x8 blds[4096];
  const int tid = threadIdx.x, w = tid >> 6, l = tid & 63, lg = l >> 4, ln = l & 15;
  const int wm = w & 1, wn = w >> 1;
  const int R0 = blockIdx.x * 128, N0 = blockIdx.y * 128;
  {
    const int row = tid >> 2, seg = tid & 3;
    const bf16* asrc;
    if (OUT_BF16) {
      const int R = R0 + row;
      asrc = A + ((size_t)(R >> 6) * SS + t0 + (R & 63)) * HH + seg * 64;
    } else {
      asrc = A + ((size_t)R0 + row) * HH + seg * 64;
    }
    #pragma unroll
    for (int k = 0; k < 8; ++k) {
      const int g = seg * 8 + k;
      alds[row * 32 + (g ^ (row & 7))] = *(const bf16x8*)(asrc + k * 8);
    }
    const float* bsrc = W + (size_t)(N0 + row) * HH + seg * 64;
    #pragma unroll
    for (int k = 0; k < 8; ++k) {
      const int g = seg * 8 + k;
      blds[row * 32 + (g ^ (row & 7))] = cvt8(bsrc + k * 8);
    }
  }
  __syncthreads();
  f32x4 acc[4][2] = {};
  #pragma unroll
  for (int kc = 0; kc < 8; ++kc) {
    bf16x8 bfr[2];
    #pragma unroll
    for (int nt = 0; nt < 2; ++nt) {
      const int row = wn * 32 + nt * 16 + ln;
      bfr[nt] = blds[row * 32 + ((kc * 4 + lg) ^ (row & 7))];
    }
    #pragma unroll
    for (int mt = 0; mt < 4; ++mt) {
      const int row = wm * 64 + mt * 16 + ln;
      bf16x8 a = alds[row * 32 + ((kc * 4 + lg) ^ (row & 7))];
      #pragma unroll
      for (int nt = 0; nt < 2; ++nt)
        acc[mt][nt] = __builtin_amdgcn_mfma_f32_16x16x32_bf16(a, bfr[nt], acc[mt][nt], 0, 0, 0);
    }
  }
  #pragma unroll
  for (int nt = 0; nt < 2; ++nt) {
    const int n = N0 + wn * 32 + nt * 16 + ln;
    const float bv = bias0[n] + (bias1 ? bias1[n] : 0.f);
    const int col = OUT_BF16 ? ((n & 255) * 4 + (n >> 8)) : n;
    #pragma unroll
    for (int mt = 0; mt < 4; ++mt)
      #pragma unroll
      for (int r = 0; r < 4; ++r) {
        const size_t row = (size_t)R0 + wm * 64 + mt * 16 + lg * 4 + r;
        if (OUT_BF16) ((bf16*)out)[row * NCOL + col] = (bf16)(acc[mt][nt][r] + bv);
        else          ((float*)out)[row * NCOL + col] = acc[mt][nt][r] + bv;
      }
  }
}

extern "C" void kernel_launch(void* const* d_in, const int* in_sizes, int n_in,
                              void* d_out, int out_size, void* d_ws, size_t ws_size,
                              hipStream_t stream) {
  const int*   x   = (const int*)d_in[0];
  const float* emb = (const float*)d_in[1];
  const float* Wi0 = (const float*)d_in[2];
  const float* bi0 = (const float*)d_in[3];
  const float* Wh0 = (const float*)d_in[4];
  const float* bh0 = (const float*)d_in[5];
  const float* Wi1 = (const float*)d_in[6];
  const float* bi1 = (const float*)d_in[7];
  const float* Wh1 = (const float*)d_in[8];
  const float* bh1 = (const float*)d_in[9];
  const float* Wg  = (const float*)d_in[10];
  const float* bg  = (const float*)d_in[11];

  // ws: [flag 256B][table bf16 256KB][wbuf0 512KB][wbuf1 512KB][hreg bf16 128MB]
  // cws (512KB) OVERLAYS wbuf0: wb0 is consumed only by rec0, which completes
  // before any rec1/cws use. Total need == R11-proven 135.53MB.
  char* ws = (char*)d_ws;
  int* flag = (int*)ws;
  unsigned short* table = (unsigned short*)(ws + 256);
  bf16x8* wb0 = (bf16x8*)(ws + 256 + 262144);
  bf16x8* wb1 = (bf16x8*)(ws + 256 + 262144 + 524288);
  bf16* hreg = (bf16*)(ws + 256 + 262144 + 524288 + 524288);
  float* cws = (float*)wb0;
  const size_t need = 256 + 262144 + 524288 + 524288
                    + (size_t)BB * SS * HH * sizeof(bf16);
  if (ws_size < need) return;

  // d_out as scratch until proj: double-buffered xg slices (2 x 67.1MB = d_out)
  bf16* xgbuf0 = (bf16*)d_out;
  bf16* xgbuf1 = (bf16*)((char*)d_out + (size_t)BB * TSL * G4H * sizeof(bf16));

  (void)hipMemsetAsync(flag, 0, sizeof(int), stream);
  detect_kernel<<<dim3(8), dim3(256), 0, stream>>>(x, flag);
  table_kernel<<<dim3(4, 128), dim3(256), 0, stream>>>(emb, Wi0, bi0, bh0, table);
  wprep_kernel<<<dim3(128, 2), dim3(256), 0, stream>>>(Wh0, Wh1, wb0, wb1);
  rec0_kernel<<<dim3(BB / 16), dim3(512), 0, stream>>>(x, flag, wb0, table, hreg);
  // xg slice 0 (standalone)
  gemm_kernel<1><<<dim3(256, 8), dim3(512), 0, stream>>>(
      hreg, Wi1, bi1, bh1, xgbuf0, 0, G4H);
  for (int s = 0; s < NSEG; ++s) {
    const int t0 = s * TSL;
    bf16* xin  = (s & 1) ? xgbuf1 : xgbuf0;
    bf16* xout = (s & 1) ? xgbuf0 : xgbuf1;
    const int nblk = 32 + ((s + 1 < NSEG) ? 2048 : 0);
    combo_kernel<<<dim3(nblk), dim3(512), 0, stream>>>(
        (const unsigned short*)xin, wb1, hreg, cws, t0, Wi1, bi1, bh1, xout);
  }
  gemm_kernel<0><<<dim3(BB * SS / 128, VV / 128), dim3(512), 0, stream>>>(
      hreg, Wg, bg, nullptr, d_out, 0, VV);
}

// Round 19
// 2882.484 us; speedup vs baseline: 2.4238x; 1.3590x over previous
//
#include <hip/hip_runtime.h>
#include <hip/hip_bf16.h>

#define BB 512
#define SS 512
#define EE 128
#define HH 256
#define VV 128
#define G4H 1024
#define TSL 64              // slice length
#define NSEG (SS / TSL)     // 8

using bf16 = __bf16;
typedef __attribute__((ext_vector_type(8))) __bf16 bf16x8;
typedef __attribute__((ext_vector_type(4))) float f32x4;

__device__ __forceinline__ float rcpf(float x) { return __builtin_amdgcn_rcpf(x); }
__device__ __forceinline__ float exp2f_(float x) { return __builtin_amdgcn_exp2f(x); }
__device__ __forceinline__ float sigf(float x) {
  return rcpf(1.0f + exp2f_(-1.442695041f * x));
}
__device__ __forceinline__ float tanh_(float x) {
  return 2.0f * rcpf(1.0f + exp2f_(-2.885390082f * x)) - 1.0f;
}
__device__ __forceinline__ bf16x8 cvt8(const float* __restrict__ s) {
  bf16x8 f;
  #pragma unroll
  for (int j = 0; j < 8; ++j) f[j] = (bf16)s[j];
  return f;
}
__device__ __forceinline__ float bf2f(unsigned short u) {
  return __uint_as_float(((unsigned)u) << 16);
}

__global__ void detect_kernel(const int* __restrict__ x, int* __restrict__ flag) {
  const int i = blockIdx.x * 256 + threadIdx.x;
  if (x[2 * i + 1] != 0) atomicOr(flag, 1);
}

__global__ __launch_bounds__(256)
void table_kernel(const float* __restrict__ emb, const float* __restrict__ Wi,
                  const float* __restrict__ bi, const float* __restrict__ bh,
                  unsigned short* __restrict__ table) {
  const int g = blockIdx.x * 256 + threadIdx.x;
  const int v = blockIdx.y;
  float s = bi[g] + bh[g];
  const float* er = emb + v * EE;
  const float* wr = Wi + (size_t)g * EE;
  #pragma unroll 4
  for (int e = 0; e < EE; ++e) s += er[e] * wr[e];
  const bf16 b = (bf16)s;
  table[v * G4H + (g & 255) * 4 + (g >> 8)] = *(const unsigned short*)&b;
}

__global__ __launch_bounds__(256)
void wprep_kernel(const float* __restrict__ Wh0, const float* __restrict__ Wh1,
                  bf16x8* __restrict__ wb0, bf16x8* __restrict__ wb1) {
  const int idx = blockIdx.x * 256 + threadIdx.x;
  const int l = idx & 63, kc = (idx >> 6) & 7, s = (idx >> 9) & 7, w = idx >> 12;
  const int lg = l >> 4, ln = l & 15;
  const int n = (s >> 1) * HH + w * 32 + 16 * (s & 1) + ln;
  const int k0 = kc * 32 + lg * 8;
  const float* src = (blockIdx.y ? Wh1 : Wh0) + (size_t)n * HH + k0;
  (blockIdx.y ? wb1 : wb0)[idx] = cvt8(src);
}

// ---------------------------------------------------------------------------
// rec0 slice body. CARRY==1: c-state in registers (cin/cout), no cws traffic.
// CARRY==0: c via cws0. h reload from h1 region at t0-1 (bf16, bit-identical
// to LDS carry). R11-proven inner loop.
// ---------------------------------------------------------------------------
__device__ __forceinline__
void rec0_body(char* smem, const int* __restrict__ x, int is32,
               const bf16x8* __restrict__ wb,
               const unsigned short* __restrict__ table,
               bf16* __restrict__ h1, float (*cst)[4],
               int t0, int bid, bool load_h) {
  bf16 (*hbuf)[4096] = (bf16(*)[4096])smem;
  bf16x8* wlds = (bf16x8*)(smem + 16384);
  const int tid = threadIdx.x, w = tid >> 6, l = tid & 63, lg = l >> 4, ln = l & 15;
  const int b0 = bid * 16, hb = w * 32;

  bf16x8 Wf[4][8];
  #pragma unroll
  for (int s = 0; s < 4; ++s)
    #pragma unroll
    for (int kc = 0; kc < 8; ++kc)
      Wf[s][kc] = wb[w * 4096 + s * 512 + kc * 64 + l];
  #pragma unroll
  for (int j = 0; j < 2; ++j)
    #pragma unroll
    for (int kc = 0; kc < 8; ++kc)
      wlds[((w * 2 + j) * 8 + kc) * 64 + l] = wb[w * 4096 + (6 + j) * 512 + kc * 64 + l];
  const bf16x8* __restrict__ gsrc0 = wb + w * 4096 + 4 * 512 + l;
  const bf16x8* __restrict__ gsrc1 = wb + w * 4096 + 5 * 512 + l;

  int hoff[4];
  #pragma unroll
  for (int r = 0; r < 4; ++r)
    hoff[r] = ((b0 + lg * 4 + r) * SS) * HH + hb + ln;

  if (t0 == 0) {
    bf16x8 z = {};
    ((bf16x8*)&hbuf[0][0])[tid] = z;
  } else if (load_h) {
    #pragma unroll
    for (int j = 0; j < 2; ++j)
      #pragma unroll
      for (int r = 0; r < 4; ++r) {
        const int m = lg * 4 + r, col = hb + 16 * j + ln;
        const bf16 hv = h1[((size_t)(b0 + m) * SS + (t0 - 1)) * HH + col];
        hbuf[0][(w * 64 + m * 4 + 2 * j + (ln >> 3)) * 8 + (ln & 7)] = hv;
      }
  }
  int idx[4];
  #pragma unroll
  for (int r = 0; r < 4; ++r) {
    const long xi = (long)(b0 + lg * 4 + r) * SS + t0;
    idx[r] = x[is32 ? xi : 2 * xi] & 127;
  }
  __syncthreads();

  #pragma unroll 1
  for (int tt = 0; tt < TSL; ++tt) {
    const int t = t0 + tt, p = tt & 1;
    ushort4 tj[4][2];
    #pragma unroll
    for (int r = 0; r < 4; ++r) {
      const unsigned short* base = table + (size_t)idx[r] * G4H + (hb + ln) * 4;
      tj[r][0] = *(const ushort4*)base;
      tj[r][1] = *(const ushort4*)(base + 64);
    }
    if (tt + 1 < TSL) {
      #pragma unroll
      for (int r = 0; r < 4; ++r) {
        const long xi = (long)(b0 + lg * 4 + r) * SS + (t + 1);
        idx[r] = x[is32 ? xi : 2 * xi] & 127;
      }
    }
    f32x4 acc[4][2] = {};
    #pragma unroll
    for (int kc = 0; kc < 8; ++kc) {
      bf16x8 a = ((const bf16x8*)&hbuf[p][0])[kc * 64 + ln * 4 + lg];
      acc[0][0] = __builtin_amdgcn_mfma_f32_16x16x32_bf16(a, Wf[0][kc], acc[0][0], 0, 0, 0);
      acc[0][1] = __builtin_amdgcn_mfma_f32_16x16x32_bf16(a, Wf[1][kc], acc[0][1], 0, 0, 0);
      acc[1][0] = __builtin_amdgcn_mfma_f32_16x16x32_bf16(a, Wf[2][kc], acc[1][0], 0, 0, 0);
      acc[1][1] = __builtin_amdgcn_mfma_f32_16x16x32_bf16(a, Wf[3][kc], acc[1][1], 0, 0, 0);
      acc[2][0] = __builtin_amdgcn_mfma_f32_16x16x32_bf16(a, gsrc0[kc * 64], acc[2][0], 0, 0, 0);
      acc[2][1] = __builtin_amdgcn_mfma_f32_16x16x32_bf16(a, gsrc1[kc * 64], acc[2][1], 0, 0, 0);
      #pragma unroll
      for (int j = 0; j < 2; ++j) {
        bf16x8 bw = wlds[((w * 2 + j) * 8 + kc) * 64 + l];
        acc[3][j] = __builtin_amdgcn_mfma_f32_16x16x32_bf16(a, bw, acc[3][j], 0, 0, 0);
      }
    }
    #pragma unroll
    for (int j = 0; j < 2; ++j)
      #pragma unroll
      for (int r = 0; r < 4; ++r) {
        const float fg = sigf(acc[0][j][r] + bf2f(tj[r][j].x));
        const float ig = sigf(acc[1][j][r] + bf2f(tj[r][j].y));
        const float gg = tanh_(acc[2][j][r] + bf2f(tj[r][j].z));
        const float og = sigf(acc[3][j][r] + bf2f(tj[r][j].w));
        const float cc = fg * cst[j][r] + ig * gg;
        cst[j][r] = cc;
        const bf16 hv = (bf16)(og * tanh_(cc));
        const int m = lg * 4 + r;
        hbuf[p ^ 1][(w * 64 + m * 4 + 2 * j + (ln >> 3)) * 8 + (ln & 7)] = hv;
        h1[hoff[r] + t * HH + 16 * j] = hv;
      }
    __syncthreads();
  }
}

// ---------------------------------------------------------------------------
// rec1 slice body (R18 verbatim).
// ---------------------------------------------------------------------------
__device__ __forceinline__
void rec1_body(char* smem, const unsigned short* __restrict__ xg,
               const bf16x8* __restrict__ wb, bf16* __restrict__ hreg,
               float* __restrict__ cws, int t0, int bid) {
  bf16 (*hbuf)[4096] = (bf16(*)[4096])smem;
  bf16x8* wlds = (bf16x8*)(smem + 16384);
  const int tid = threadIdx.x, w = tid >> 6, l = tid & 63, lg = l >> 4, ln = l & 15;
  const int b0 = bid * 16, hb = w * 32;

  bf16x8 Wf[4][8];
  #pragma unroll
  for (int s = 0; s < 4; ++s)
    #pragma unroll
    for (int kc = 0; kc < 8; ++kc)
      Wf[s][kc] = wb[w * 4096 + s * 512 + kc * 64 + l];
  #pragma unroll
  for (int j = 0; j < 2; ++j)
    #pragma unroll
    for (int kc = 0; kc < 8; ++kc)
      wlds[((w * 2 + j) * 8 + kc) * 64 + l] = wb[w * 4096 + (6 + j) * 512 + kc * 64 + l];
  const bf16x8* __restrict__ gsrc0 = wb + w * 4096 + 4 * 512 + l;
  const bf16x8* __restrict__ gsrc1 = wb + w * 4096 + 5 * 512 + l;

  int hoff[4];
  size_t xbase[4];
  #pragma unroll
  for (int r = 0; r < 4; ++r) {
    hoff[r] = ((b0 + lg * 4 + r) * SS) * HH + hb + ln;
    xbase[r] = (size_t)(b0 + lg * 4 + r) * TSL * G4H + (hb + ln) * 4;
  }

  float c[2][4];
  if (t0 == 0) {
    #pragma unroll
    for (int j = 0; j < 2; ++j)
      #pragma unroll
      for (int r = 0; r < 4; ++r) c[j][r] = 0.f;
    bf16x8 z = {};
    ((bf16x8*)&hbuf[0][0])[tid] = z;
  } else {
    #pragma unroll
    for (int j = 0; j < 2; ++j)
      #pragma unroll
      for (int r = 0; r < 4; ++r) {
        const int m = lg * 4 + r, col = hb + 16 * j + ln;
        c[j][r] = cws[(size_t)(b0 + m) * HH + col];
        const bf16 hv = hreg[((size_t)(b0 + m) * SS + (t0 - 1)) * HH + col];
        hbuf[0][(w * 64 + m * 4 + 2 * j + (ln >> 3)) * 8 + (ln & 7)] = hv;
      }
  }
  __syncthreads();

  #pragma unroll 1
  for (int tt = 0; tt < TSL; ++tt) {
    const int t = t0 + tt, p = tt & 1;
    ushort4 tj[4][2];
    #pragma unroll
    for (int r = 0; r < 4; ++r) {
      const unsigned short* base = xg + xbase[r] + (size_t)tt * G4H;
      tj[r][0] = *(const ushort4*)base;
      tj[r][1] = *(const ushort4*)(base + 64);
    }
    f32x4 acc[4][2] = {};
    #pragma unroll
    for (int kc = 0; kc < 8; ++kc) {
      bf16x8 a = ((const bf16x8*)&hbuf[p][0])[kc * 64 + ln * 4 + lg];
      acc[0][0] = __builtin_amdgcn_mfma_f32_16x16x32_bf16(a, Wf[0][kc], acc[0][0], 0, 0, 0);
      acc[0][1] = __builtin_amdgcn_mfma_f32_16x16x32_bf16(a, Wf[1][kc], acc[0][1], 0, 0, 0);
      acc[1][0] = __builtin_amdgcn_mfma_f32_16x16x32_bf16(a, Wf[2][kc], acc[1][0], 0, 0, 0);
      acc[1][1] = __builtin_amdgcn_mfma_f32_16x16x32_bf16(a, Wf[3][kc], acc[1][1], 0, 0, 0);
      acc[2][0] = __builtin_amdgcn_mfma_f32_16x16x32_bf16(a, gsrc0[kc * 64], acc[2][0], 0, 0, 0);
      acc[2][1] = __builtin_amdgcn_mfma_f32_16x16x32_bf16(a, gsrc1[kc * 64], acc[2][1], 0, 0, 0);
      #pragma unroll
      for (int j = 0; j < 2; ++j) {
        bf16x8 bw = wlds[((w * 2 + j) * 8 + kc) * 64 + l];
        acc[3][j] = __builtin_amdgcn_mfma_f32_16x16x32_bf16(a, bw, acc[3][j], 0, 0, 0);
      }
    }
    #pragma unroll
    for (int j = 0; j < 2; ++j)
      #pragma unroll
      for (int r = 0; r < 4; ++r) {
        const float fg = sigf(acc[0][j][r] + bf2f(tj[r][j].x));
        const float ig = sigf(acc[1][j][r] + bf2f(tj[r][j].y));
        const float gg = tanh_(acc[2][j][r] + bf2f(tj[r][j].z));
        const float og = sigf(acc[3][j][r] + bf2f(tj[r][j].w));
        const float cc = fg * c[j][r] + ig * gg;
        c[j][r] = cc;
        const bf16 hv = (bf16)(og * tanh_(cc));
        const int m = lg * 4 + r;
        hbuf[p ^ 1][(w * 64 + m * 4 + 2 * j + (ln >> 3)) * 8 + (ln & 7)] = hv;
        hreg[hoff[r] + t * HH + 16 * j] = hv;
      }
    __syncthreads();
  }
  #pragma unroll
  for (int j = 0; j < 2; ++j)
    #pragma unroll
    for (int r = 0; r < 4; ++r)
      cws[(size_t)(b0 + lg * 4 + r) * HH + hb + 16 * j + ln] = c[j][r];
}

// ---------------------------------------------------------------------------
// xg GEMM body (R18 verbatim).
// ---------------------------------------------------------------------------
__device__ __forceinline__
void xg_body(char* smem, const bf16* __restrict__ A, const float* __restrict__ W,
             const float* __restrict__ bias0, const float* __restrict__ bias1,
             bf16* __restrict__ out, int t0, int flat) {
  bf16x8* alds = (bf16x8*)smem;
  bf16x8* blds = (bf16x8*)(smem + 65536);
  const int tid = threadIdx.x, w = tid >> 6, l = tid & 63, lg = l >> 4, ln = l & 15;
  const int wm = w & 1, wn = w >> 1;
  const int R0 = (flat & 255) * 128, N0 = (flat >> 8) * 128;
  {
    const int row = tid >> 2, seg = tid & 3;
    const int R = R0 + row;
    const bf16* asrc = A + ((size_t)(R >> 6) * SS + t0 + (R & 63)) * HH + seg * 64;
    #pragma unroll
    for (int k = 0; k < 8; ++k) {
      const int g = seg * 8 + k;
      alds[row * 32 + (g ^ (row & 7))] = *(const bf16x8*)(asrc + k * 8);
    }
    const float* bsrc = W + (size_t)(N0 + row) * HH + seg * 64;
    #pragma unroll
    for (int k = 0; k < 8; ++k) {
      const int g = seg * 8 + k;
      blds[row * 32 + (g ^ (row & 7))] = cvt8(bsrc + k * 8);
    }
  }
  __syncthreads();
  f32x4 acc[4][2] = {};
  #pragma unroll
  for (int kc = 0; kc < 8; ++kc) {
    bf16x8 bfr[2];
    #pragma unroll
    for (int nt = 0; nt < 2; ++nt) {
      const int row = wn * 32 + nt * 16 + ln;
      bfr[nt] = blds[row * 32 + ((kc * 4 + lg) ^ (row & 7))];
    }
    #pragma unroll
    for (int mt = 0; mt < 4; ++mt) {
      const int row = wm * 64 + mt * 16 + ln;
      bf16x8 a = alds[row * 32 + ((kc * 4 + lg) ^ (row & 7))];
      #pragma unroll
      for (int nt = 0; nt < 2; ++nt)
        acc[mt][nt] = __builtin_amdgcn_mfma_f32_16x16x32_bf16(a, bfr[nt], acc[mt][nt], 0, 0, 0);
    }
  }
  #pragma unroll
  for (int nt = 0; nt < 2; ++nt) {
    const int n = N0 + wn * 32 + nt * 16 + ln;
    const float bv = bias0[n] + bias1[n];
    const int col = (n & 255) * 4 + (n >> 8);
    #pragma unroll
    for (int mt = 0; mt < 4; ++mt)
      #pragma unroll
      for (int r = 0; r < 4; ++r) {
        const size_t row = (size_t)R0 + wm * 64 + mt * 16 + lg * 4 + r;
        out[row * G4H + col] = (bf16)(acc[mt][nt][r] + bv);
      }
  }
}

// ---------------------------------------------------------------------------
// Pipelined rec0 slice kernel role: c-state via cws0 (fp32).
// ---------------------------------------------------------------------------
__device__ __forceinline__
void rec0_slice(char* smem, const int* x, int is32, const bf16x8* wb0,
                const unsigned short* table, bf16* hreg, float* cws0,
                int t0, int bid) {
  const int tid = threadIdx.x, w = tid >> 6, l = tid & 63, lg = l >> 4, ln = l & 15;
  const int b0 = bid * 16, hb = w * 32;
  float c[2][4];
  if (t0 == 0) {
    #pragma unroll
    for (int j = 0; j < 2; ++j)
      #pragma unroll
      for (int r = 0; r < 4; ++r) c[j][r] = 0.f;
  } else {
    #pragma unroll
    for (int j = 0; j < 2; ++j)
      #pragma unroll
      for (int r = 0; r < 4; ++r)
        c[j][r] = cws0[(size_t)(b0 + lg * 4 + r) * HH + hb + 16 * j + ln];
  }
  rec0_body(smem, x, is32, wb0, table, hreg, c, t0, bid, t0 != 0);
  #pragma unroll
  for (int j = 0; j < 2; ++j)
    #pragma unroll
    for (int r = 0; r < 4; ++r)
      cws0[(size_t)(b0 + lg * 4 + r) * HH + hb + 16 * j + ln] = c[j][r];
}

// ---------------------------------------------------------------------------
// 3-stage pipeline launch k: blocks 0-31 rec0(k); 32-63 rec1(k-2); 64+ xg(k-1).
// ---------------------------------------------------------------------------
__global__ __launch_bounds__(512)
void pipe_kernel(const int* __restrict__ x, const int* __restrict__ flagp,
                 const bf16x8* __restrict__ wb0,
                 const unsigned short* __restrict__ table,
                 const unsigned short* __restrict__ xg_in,
                 const bf16x8* __restrict__ wb1,
                 bf16* __restrict__ hreg, float* __restrict__ cws0,
                 float* __restrict__ cws1, int k,
                 const float* __restrict__ Wi, const float* __restrict__ bi,
                 const float* __restrict__ bh, bf16* __restrict__ xg_out) {
  __shared__ __align__(16) char smem[147456];
  const int bx = blockIdx.x;
  if (bx < 32) {
    if (k < NSEG) rec0_slice(smem, x, *flagp, wb0, table, hreg, cws0, k * TSL, bx);
  } else if (bx < 64) {
    if (k >= 2) rec1_body(smem, xg_in, wb1, hreg, cws1, (k - 2) * TSL, bx - 32);
  } else {
    if (k >= 1 && k <= NSEG)
      xg_body(smem, hreg, Wi, bi, bh, xg_out, (k - 1) * TSL, bx - 64);
  }
}

// ---------------------------------------------------------------------------
// Fallback: monolithic rec0 (c carried in registers across internal slices),
// then R18's rec1||xg combo chain.
// ---------------------------------------------------------------------------
__global__ __launch_bounds__(512)
void rec0_full_kernel(const int* __restrict__ x, const int* __restrict__ flagp,
                      const bf16x8* __restrict__ wb,
                      const unsigned short* __restrict__ table,
                      bf16* __restrict__ h1) {
  __shared__ __align__(16) char smem[147456];
  const int is32 = *flagp;
  float c[2][4] = {};
  #pragma unroll 1
  for (int s = 0; s < NSEG; ++s) {
    rec0_body(smem, x, is32, wb, table, h1, c, s * TSL, blockIdx.x, false);
    __syncthreads();
  }
}

__global__ __launch_bounds__(512)
void combo_kernel(const unsigned short* __restrict__ xg_in,
                  const bf16x8* __restrict__ wb, bf16* __restrict__ hreg,
                  float* __restrict__ cws, int t0,
                  const float* __restrict__ Wi, const float* __restrict__ bi,
                  const float* __restrict__ bh, bf16* __restrict__ xg_out) {
  __shared__ __align__(16) char smem[147456];
  if (blockIdx.x < 32)
    rec1_body(smem, xg_in, wb, hreg, cws, t0, blockIdx.x);
  else
    xg_body(smem, hreg, Wi, bi, bh, xg_out, t0 + TSL, blockIdx.x - 32);
}

template <int OUT_BF16>
__global__ __launch_bounds__(512)
void gemm_kernel(const bf16* __restrict__ A, const float* __restrict__ W,
                 const float* __restrict__ bias0, const float* __restrict__ bias1,
                 void* __restrict__ out, int t0, int NCOL) {
  __shared__ bf16x8 alds[4096];
  __shared__ bf16x8 blds[4096];
  const int tid = threadIdx.x, w = tid >> 6, l = tid & 63, lg = l >> 4, ln = l & 15;
  const int wm = w & 1, wn = w >> 1;
  const int R0 = blockIdx.x * 128, N0 = blockIdx.y * 128;
  {
    const int row = tid >> 2, seg = tid & 3;
    const bf16* asrc;
    if (OUT_BF16) {
      const int R = R0 + row;
      asrc = A + ((size_t)(R >> 6) * SS + t0 + (R & 63)) * HH + seg * 64;
    } else {
      asrc = A + ((size_t)R0 + row) * HH + seg * 64;
    }
    #pragma unroll
    for (int k = 0; k < 8; ++k) {
      const int g = seg * 8 + k;
      alds[row * 32 + (g ^ (row & 7))] = *(const bf16x8*)(asrc + k * 8);
    }
    const float* bsrc = W + (size_t)(N0 + row) * HH + seg * 64;
    #pragma unroll
    for (int k = 0; k < 8; ++k) {
      const int g = seg * 8 + k;
      blds[row * 32 + (g ^ (row & 7))] = cvt8(bsrc + k * 8);
    }
  }
  __syncthreads();
  f32x4 acc[4][2] = {};
  #pragma unroll
  for (int kc = 0; kc < 8; ++kc) {
    bf16x8 bfr[2];
    #pragma unroll
    for (int nt = 0; nt < 2; ++nt) {
      const int row = wn * 32 + nt * 16 + ln;
      bfr[nt] = blds[row * 32 + ((kc * 4 + lg) ^ (row & 7))];
    }
    #pragma unroll
    for (int mt = 0; mt < 4; ++mt) {
      const int row = wm * 64 + mt * 16 + ln;
      bf16x8 a = alds[row * 32 + ((kc * 4 + lg) ^ (row & 7))];
      #pragma unroll
      for (int nt = 0; nt < 2; ++nt)
        acc[mt][nt] = __builtin_amdgcn_mfma_f32_16x16x32_bf16(a, bfr[nt], acc[mt][nt], 0, 0, 0);
    }
  }
  #pragma unroll
  for (int nt = 0; nt < 2; ++nt) {
    const int n = N0 + wn * 32 + nt * 16 + ln;
    const float bv = bias0[n] + (bias1 ? bias1[n] : 0.f);
    const int col = OUT_BF16 ? ((n & 255) * 4 + (n >> 8)) : n;
    #pragma unroll
    for (int mt = 0; mt < 4; ++mt)
      #pragma unroll
      for (int r = 0; r < 4; ++r) {
        const size_t row = (size_t)R0 + wm * 64 + mt * 16 + lg * 4 + r;
        if (OUT_BF16) ((bf16*)out)[row * NCOL + col] = (bf16)(acc[mt][nt][r] + bv);
        else          ((float*)out)[row * NCOL + col] = acc[mt][nt][r] + bv;
      }
  }
}

extern "C" void kernel_launch(void* const* d_in, const int* in_sizes, int n_in,
                              void* d_out, int out_size, void* d_ws, size_t ws_size,
                              hipStream_t stream) {
  const int*   x   = (const int*)d_in[0];
  const float* emb = (const float*)d_in[1];
  const float* Wi0 = (const float*)d_in[2];
  const float* bi0 = (const float*)d_in[3];
  const float* Wh0 = (const float*)d_in[4];
  const float* bh0 = (const float*)d_in[5];
  const float* Wi1 = (const float*)d_in[6];
  const float* bi1 = (const float*)d_in[7];
  const float* Wh1 = (const float*)d_in[8];
  const float* bh1 = (const float*)d_in[9];
  const float* Wg  = (const float*)d_in[10];
  const float* bg  = (const float*)d_in[11];

  char* ws = (char*)d_ws;
  int* flag = (int*)ws;
  unsigned short* table = (unsigned short*)(ws + 256);
  bf16x8* wb0 = (bf16x8*)(ws + 256 + 262144);
  bf16x8* wb1 = (bf16x8*)(ws + 256 + 262144 + 524288);
  bf16* hreg = (bf16*)(ws + 256 + 262144 + 524288 + 524288);
  const size_t need_base = 256 + 262144 + 524288 + 524288
                         + (size_t)BB * SS * HH * sizeof(bf16);
  float* cws0 = (float*)(ws + need_base);
  float* cws1 = (float*)(ws + need_base + 524288);
  const size_t need_full = need_base + 2 * 524288;
  if (ws_size < need_base) return;

  bf16* xgbuf0 = (bf16*)d_out;
  bf16* xgbuf1 = (bf16*)((char*)d_out + (size_t)BB * TSL * G4H * sizeof(bf16));

  (void)hipMemsetAsync(flag, 0, sizeof(int), stream);
  detect_kernel<<<dim3(8), dim3(256), 0, stream>>>(x, flag);
  table_kernel<<<dim3(4, 128), dim3(256), 0, stream>>>(emb, Wi0, bi0, bh0, table);
  wprep_kernel<<<dim3(128, 2), dim3(256), 0, stream>>>(Wh0, Wh1, wb0, wb1);

  if (ws_size >= need_full) {
    for (int k = 0; k <= NSEG + 1; ++k) {
      bf16* xin  = (k & 1) ? xgbuf1 : xgbuf0;   // slice k-2 buffer
      bf16* xout = (k & 1) ? xgbuf0 : xgbuf1;   // slice k-1 buffer
      const bool xgv = (k >= 1 && k <= NSEG);
      const int nblk = 64 + (xgv ? 2048 : 0);
      pipe_kernel<<<dim3(nblk), dim3(512), 0, stream>>>(
          x, flag, wb0, table, (const unsigned short*)xin, wb1,
          hreg, cws0, cws1, k, Wi1, bi1, bh1, xout);
    }
  } else {
    float* cwsA = (float*)wb0;  // wb0 dead after rec0_full completes
    rec0_full_kernel<<<dim3(32), dim3(512), 0, stream>>>(x, flag, wb0, table, hreg);
    gemm_kernel<1><<<dim3(256, 8), dim3(512), 0, stream>>>(
        hreg, Wi1, bi1, bh1, xgbuf0, 0, G4H);
    for (int s = 0; s < NSEG; ++s) {
      const int t0 = s * TSL;
      bf16* xin  = (s & 1) ? xgbuf1 : xgbuf0;
      bf16* xout = (s & 1) ? xgbuf0 : xgbuf1;
      const int nblk = 32 + ((s + 1 < NSEG) ? 2048 : 0);
      combo_kernel<<<dim3(nblk), dim3(512), 0, stream>>>(
          (const unsigned short*)xin, wb1, hreg, cwsA, t0, Wi1, bi1, bh1, xout);
    }
  }
  gemm_kernel<0><<<dim3(BB * SS / 128, VV / 128), dim3(512), 0, stream>>>(
      hreg, Wg, bg, nullptr, d_out, 0, VV);
}

// Round 20
// 2713.283 us; speedup vs baseline: 2.5750x; 1.0624x over previous
//
#include <hip/hip_runtime.h>
#include <hip/hip_bf16.h>

#define BB 512
#define SS 512
#define EE 128
#define HH 256
#define VV 128
#define G4H 1024
#define TSL 64              // slice length
#define NSEG (SS / TSL)     // 8

using bf16 = __bf16;
typedef __attribute__((ext_vector_type(8))) __bf16 bf16x8;
typedef __attribute__((ext_vector_type(4))) float f32x4;

__device__ __forceinline__ float rcpf(float x) { return __builtin_amdgcn_rcpf(x); }
__device__ __forceinline__ float exp2f_(float x) { return __builtin_amdgcn_exp2f(x); }
__device__ __forceinline__ float sigf(float x) {
  return rcpf(1.0f + exp2f_(-1.442695041f * x));
}
__device__ __forceinline__ float tanh_(float x) {
  return 2.0f * rcpf(1.0f + exp2f_(-2.885390082f * x)) - 1.0f;
}
__device__ __forceinline__ bf16x8 cvt8(const float* __restrict__ s) {
  bf16x8 f;
  #pragma unroll
  for (int j = 0; j < 8; ++j) f[j] = (bf16)s[j];
  return f;
}
__device__ __forceinline__ float bf2f(unsigned short u) {
  return __uint_as_float(((unsigned)u) << 16);
}

__global__ void detect_kernel(const int* __restrict__ x, int* __restrict__ flag) {
  const int i = blockIdx.x * 256 + threadIdx.x;
  if (x[2 * i + 1] != 0) atomicOr(flag, 1);
}

__global__ __launch_bounds__(256)
void table_kernel(const float* __restrict__ emb, const float* __restrict__ Wi,
                  const float* __restrict__ bi, const float* __restrict__ bh,
                  unsigned short* __restrict__ table) {
  const int g = blockIdx.x * 256 + threadIdx.x;
  const int v = blockIdx.y;
  float s = bi[g] + bh[g];
  const float* er = emb + v * EE;
  const float* wr = Wi + (size_t)g * EE;
  #pragma unroll 4
  for (int e = 0; e < EE; ++e) s += er[e] * wr[e];
  const bf16 b = (bf16)s;
  table[v * G4H + (g & 255) * 4 + (g >> 8)] = *(const unsigned short*)&b;
}

__global__ __launch_bounds__(256)
void wprep_kernel(const float* __restrict__ Wh0, const float* __restrict__ Wh1,
                  bf16x8* __restrict__ wb0, bf16x8* __restrict__ wb1) {
  const int idx = blockIdx.x * 256 + threadIdx.x;
  const int l = idx & 63, kc = (idx >> 6) & 7, s = (idx >> 9) & 7, w = idx >> 12;
  const int lg = l >> 4, ln = l & 15;
  const int n = (s >> 1) * HH + w * 32 + 16 * (s & 1) + ln;
  const int k0 = kc * 32 + lg * 8;
  const float* src = (blockIdx.y ? Wh1 : Wh0) + (size_t)n * HH + k0;
  (blockIdx.y ? wb1 : wb0)[idx] = cvt8(src);
}

// ---------------------------------------------------------------------------
// rec0 slice body (R19 verbatim).
// ---------------------------------------------------------------------------
__device__ __forceinline__
void rec0_body(char* smem, const int* __restrict__ x, int is32,
               const bf16x8* __restrict__ wb,
               const unsigned short* __restrict__ table,
               bf16* __restrict__ h1, float (*cst)[4],
               int t0, int bid, bool load_h) {
  bf16 (*hbuf)[4096] = (bf16(*)[4096])smem;
  bf16x8* wlds = (bf16x8*)(smem + 16384);
  const int tid = threadIdx.x, w = tid >> 6, l = tid & 63, lg = l >> 4, ln = l & 15;
  const int b0 = bid * 16, hb = w * 32;

  bf16x8 Wf[4][8];
  #pragma unroll
  for (int s = 0; s < 4; ++s)
    #pragma unroll
    for (int kc = 0; kc < 8; ++kc)
      Wf[s][kc] = wb[w * 4096 + s * 512 + kc * 64 + l];
  #pragma unroll
  for (int j = 0; j < 2; ++j)
    #pragma unroll
    for (int kc = 0; kc < 8; ++kc)
      wlds[((w * 2 + j) * 8 + kc) * 64 + l] = wb[w * 4096 + (6 + j) * 512 + kc * 64 + l];
  const bf16x8* __restrict__ gsrc0 = wb + w * 4096 + 4 * 512 + l;
  const bf16x8* __restrict__ gsrc1 = wb + w * 4096 + 5 * 512 + l;

  int hoff[4];
  #pragma unroll
  for (int r = 0; r < 4; ++r)
    hoff[r] = ((b0 + lg * 4 + r) * SS) * HH + hb + ln;

  if (t0 == 0) {
    bf16x8 z = {};
    ((bf16x8*)&hbuf[0][0])[tid] = z;
  } else if (load_h) {
    #pragma unroll
    for (int j = 0; j < 2; ++j)
      #pragma unroll
      for (int r = 0; r < 4; ++r) {
        const int m = lg * 4 + r, col = hb + 16 * j + ln;
        const bf16 hv = h1[((size_t)(b0 + m) * SS + (t0 - 1)) * HH + col];
        hbuf[0][(w * 64 + m * 4 + 2 * j + (ln >> 3)) * 8 + (ln & 7)] = hv;
      }
  }
  int idx[4];
  #pragma unroll
  for (int r = 0; r < 4; ++r) {
    const long xi = (long)(b0 + lg * 4 + r) * SS + t0;
    idx[r] = x[is32 ? xi : 2 * xi] & 127;
  }
  __syncthreads();

  #pragma unroll 1
  for (int tt = 0; tt < TSL; ++tt) {
    const int t = t0 + tt, p = tt & 1;
    ushort4 tj[4][2];
    #pragma unroll
    for (int r = 0; r < 4; ++r) {
      const unsigned short* base = table + (size_t)idx[r] * G4H + (hb + ln) * 4;
      tj[r][0] = *(const ushort4*)base;
      tj[r][1] = *(const ushort4*)(base + 64);
    }
    if (tt + 1 < TSL) {
      #pragma unroll
      for (int r = 0; r < 4; ++r) {
        const long xi = (long)(b0 + lg * 4 + r) * SS + (t + 1);
        idx[r] = x[is32 ? xi : 2 * xi] & 127;
      }
    }
    f32x4 acc[4][2] = {};
    #pragma unroll
    for (int kc = 0; kc < 8; ++kc) {
      bf16x8 a = ((const bf16x8*)&hbuf[p][0])[kc * 64 + ln * 4 + lg];
      acc[0][0] = __builtin_amdgcn_mfma_f32_16x16x32_bf16(a, Wf[0][kc], acc[0][0], 0, 0, 0);
      acc[0][1] = __builtin_amdgcn_mfma_f32_16x16x32_bf16(a, Wf[1][kc], acc[0][1], 0, 0, 0);
      acc[1][0] = __builtin_amdgcn_mfma_f32_16x16x32_bf16(a, Wf[2][kc], acc[1][0], 0, 0, 0);
      acc[1][1] = __builtin_amdgcn_mfma_f32_16x16x32_bf16(a, Wf[3][kc], acc[1][1], 0, 0, 0);
      acc[2][0] = __builtin_amdgcn_mfma_f32_16x16x32_bf16(a, gsrc0[kc * 64], acc[2][0], 0, 0, 0);
      acc[2][1] = __builtin_amdgcn_mfma_f32_16x16x32_bf16(a, gsrc1[kc * 64], acc[2][1], 0, 0, 0);
      #pragma unroll
      for (int j = 0; j < 2; ++j) {
        bf16x8 bw = wlds[((w * 2 + j) * 8 + kc) * 64 + l];
        acc[3][j] = __builtin_amdgcn_mfma_f32_16x16x32_bf16(a, bw, acc[3][j], 0, 0, 0);
      }
    }
    #pragma unroll
    for (int j = 0; j < 2; ++j)
      #pragma unroll
      for (int r = 0; r < 4; ++r) {
        const float fg = sigf(acc[0][j][r] + bf2f(tj[r][j].x));
        const float ig = sigf(acc[1][j][r] + bf2f(tj[r][j].y));
        const float gg = tanh_(acc[2][j][r] + bf2f(tj[r][j].z));
        const float og = sigf(acc[3][j][r] + bf2f(tj[r][j].w));
        const float cc = fg * cst[j][r] + ig * gg;
        cst[j][r] = cc;
        const bf16 hv = (bf16)(og * tanh_(cc));
        const int m = lg * 4 + r;
        hbuf[p ^ 1][(w * 64 + m * 4 + 2 * j + (ln >> 3)) * 8 + (ln & 7)] = hv;
        h1[hoff[r] + t * HH + 16 * j] = hv;
      }
    __syncthreads();
  }
}

// ---------------------------------------------------------------------------
// rec1 slice body (R19 verbatim).
// ---------------------------------------------------------------------------
__device__ __forceinline__
void rec1_body(char* smem, const unsigned short* __restrict__ xg,
               const bf16x8* __restrict__ wb, bf16* __restrict__ hreg,
               float* __restrict__ cws, int t0, int bid) {
  bf16 (*hbuf)[4096] = (bf16(*)[4096])smem;
  bf16x8* wlds = (bf16x8*)(smem + 16384);
  const int tid = threadIdx.x, w = tid >> 6, l = tid & 63, lg = l >> 4, ln = l & 15;
  const int b0 = bid * 16, hb = w * 32;

  bf16x8 Wf[4][8];
  #pragma unroll
  for (int s = 0; s < 4; ++s)
    #pragma unroll
    for (int kc = 0; kc < 8; ++kc)
      Wf[s][kc] = wb[w * 4096 + s * 512 + kc * 64 + l];
  #pragma unroll
  for (int j = 0; j < 2; ++j)
    #pragma unroll
    for (int kc = 0; kc < 8; ++kc)
      wlds[((w * 2 + j) * 8 + kc) * 64 + l] = wb[w * 4096 + (6 + j) * 512 + kc * 64 + l];
  const bf16x8* __restrict__ gsrc0 = wb + w * 4096 + 4 * 512 + l;
  const bf16x8* __restrict__ gsrc1 = wb + w * 4096 + 5 * 512 + l;

  int hoff[4];
  size_t xbase[4];
  #pragma unroll
  for (int r = 0; r < 4; ++r) {
    hoff[r] = ((b0 + lg * 4 + r) * SS) * HH + hb + ln;
    xbase[r] = (size_t)(b0 + lg * 4 + r) * TSL * G4H + (hb + ln) * 4;
  }

  float c[2][4];
  if (t0 == 0) {
    #pragma unroll
    for (int j = 0; j < 2; ++j)
      #pragma unroll
      for (int r = 0; r < 4; ++r) c[j][r] = 0.f;
    bf16x8 z = {};
    ((bf16x8*)&hbuf[0][0])[tid] = z;
  } else {
    #pragma unroll
    for (int j = 0; j < 2; ++j)
      #pragma unroll
      for (int r = 0; r < 4; ++r) {
        const int m = lg * 4 + r, col = hb + 16 * j + ln;
        c[j][r] = cws[(size_t)(b0 + m) * HH + col];
        const bf16 hv = hreg[((size_t)(b0 + m) * SS + (t0 - 1)) * HH + col];
        hbuf[0][(w * 64 + m * 4 + 2 * j + (ln >> 3)) * 8 + (ln & 7)] = hv;
      }
  }
  __syncthreads();

  #pragma unroll 1
  for (int tt = 0; tt < TSL; ++tt) {
    const int t = t0 + tt, p = tt & 1;
    ushort4 tj[4][2];
    #pragma unroll
    for (int r = 0; r < 4; ++r) {
      const unsigned short* base = xg + xbase[r] + (size_t)tt * G4H;
      tj[r][0] = *(const ushort4*)base;
      tj[r][1] = *(const ushort4*)(base + 64);
    }
    f32x4 acc[4][2] = {};
    #pragma unroll
    for (int kc = 0; kc < 8; ++kc) {
      bf16x8 a = ((const bf16x8*)&hbuf[p][0])[kc * 64 + ln * 4 + lg];
      acc[0][0] = __builtin_amdgcn_mfma_f32_16x16x32_bf16(a, Wf[0][kc], acc[0][0], 0, 0, 0);
      acc[0][1] = __builtin_amdgcn_mfma_f32_16x16x32_bf16(a, Wf[1][kc], acc[0][1], 0, 0, 0);
      acc[1][0] = __builtin_amdgcn_mfma_f32_16x16x32_bf16(a, Wf[2][kc], acc[1][0], 0, 0, 0);
      acc[1][1] = __builtin_amdgcn_mfma_f32_16x16x32_bf16(a, Wf[3][kc], acc[1][1], 0, 0, 0);
      acc[2][0] = __builtin_amdgcn_mfma_f32_16x16x32_bf16(a, gsrc0[kc * 64], acc[2][0], 0, 0, 0);
      acc[2][1] = __builtin_amdgcn_mfma_f32_16x16x32_bf16(a, gsrc1[kc * 64], acc[2][1], 0, 0, 0);
      #pragma unroll
      for (int j = 0; j < 2; ++j) {
        bf16x8 bw = wlds[((w * 2 + j) * 8 + kc) * 64 + l];
        acc[3][j] = __builtin_amdgcn_mfma_f32_16x16x32_bf16(a, bw, acc[3][j], 0, 0, 0);
      }
    }
    #pragma unroll
    for (int j = 0; j < 2; ++j)
      #pragma unroll
      for (int r = 0; r < 4; ++r) {
        const float fg = sigf(acc[0][j][r] + bf2f(tj[r][j].x));
        const float ig = sigf(acc[1][j][r] + bf2f(tj[r][j].y));
        const float gg = tanh_(acc[2][j][r] + bf2f(tj[r][j].z));
        const float og = sigf(acc[3][j][r] + bf2f(tj[r][j].w));
        const float cc = fg * c[j][r] + ig * gg;
        c[j][r] = cc;
        const bf16 hv = (bf16)(og * tanh_(cc));
        const int m = lg * 4 + r;
        hbuf[p ^ 1][(w * 64 + m * 4 + 2 * j + (ln >> 3)) * 8 + (ln & 7)] = hv;
        hreg[hoff[r] + t * HH + 16 * j] = hv;
      }
    __syncthreads();
  }
  #pragma unroll
  for (int j = 0; j < 2; ++j)
    #pragma unroll
    for (int r = 0; r < 4; ++r)
      cws[(size_t)(b0 + lg * 4 + r) * HH + hb + 16 * j + ln] = c[j][r];
}

// ---------------------------------------------------------------------------
// NEW xg GEMM body: tile = 64 rows x 256 gate-cols (one u-panel, ALL 4 gates).
// B-LDS staged in gate-interleaved row order so output columns are contiguous
// -> dense coalesced stores (fixes the 3x write amplification of R19).
// flat: rb = flat & 511 (batch; 64 rows = batch rb's full slice), up = flat>>9.
// LDS: A 32KB + B 128KB = 160KB.
// ---------------------------------------------------------------------------
__device__ __forceinline__
void xg_body(char* smem, const bf16* __restrict__ A, const float* __restrict__ W,
             const float* __restrict__ bias0, const float* __restrict__ bias1,
             bf16* __restrict__ out, int t0, int flat) {
  bf16x8* alds = (bf16x8*)smem;                       // 64 rows x 32 granules
  bf16x8* blds = (bf16x8*)(smem + 32768);             // 256 rows x 32 granules
  const int tid = threadIdx.x, w = tid >> 6, l = tid & 63, lg = l >> 4, ln = l & 15;
  const int wm = w & 1, wn = w >> 1;                  // 2 M-halves x 4 N-quarters
  const int rb = flat & 511, up = flat >> 9;          // batch, u-panel
  const int R0 = rb * 64;                             // xg row base
  {
    // A: 64 rows x 256k bf16; 8 thr/row x 32k
    const int row = tid >> 3, seg = tid & 7;
    const bf16* asrc = A + ((size_t)rb * SS + t0 + row) * HH + seg * 32;
    #pragma unroll
    for (int k = 0; k < 4; ++k) {
      const int g = seg * 4 + k;
      alds[row * 32 + (g ^ (row & 7))] = *(const bf16x8*)(asrc + k * 8);
    }
    // B: 256 gate-cols x 256k; col c -> Wi1 row n = (c&3)*256 + up*64 + (c>>2)
    const int col = tid >> 1, half = tid & 1;
    const int n = (col & 3) * HH + up * 64 + (col >> 2);
    const float* bsrc = W + (size_t)n * HH + half * 128;
    #pragma unroll
    for (int k = 0; k < 16; ++k) {
      const int g = half * 16 + k;
      blds[col * 32 + (g ^ (col & 7))] = cvt8(bsrc + k * 8);
    }
  }
  __syncthreads();
  f32x4 acc[2][4] = {};
  #pragma unroll
  for (int kc = 0; kc < 8; ++kc) {
    bf16x8 bfr[4];
    #pragma unroll
    for (int nt = 0; nt < 4; ++nt) {
      const int row = wn * 64 + nt * 16 + ln;
      bfr[nt] = blds[row * 32 + ((kc * 4 + lg) ^ (row & 7))];
    }
    #pragma unroll
    for (int mt = 0; mt < 2; ++mt) {
      const int row = wm * 32 + mt * 16 + ln;
      bf16x8 a = alds[row * 32 + ((kc * 4 + lg) ^ (row & 7))];
      #pragma unroll
      for (int nt = 0; nt < 4; ++nt)
        acc[mt][nt] = __builtin_amdgcn_mfma_f32_16x16x32_bf16(a, bfr[nt], acc[mt][nt], 0, 0, 0);
    }
  }
  #pragma unroll
  for (int nt = 0; nt < 4; ++nt) {
    const int local = wn * 64 + nt * 16 + ln;          // 0..255
    const int n = (local & 3) * HH + up * 64 + (local >> 2);
    const float bv = bias0[n] + bias1[n];
    const int gcol = up * 256 + local;                 // contiguous per lane
    #pragma unroll
    for (int mt = 0; mt < 2; ++mt)
      #pragma unroll
      for (int r = 0; r < 4; ++r) {
        const size_t row = (size_t)R0 + wm * 32 + mt * 16 + lg * 4 + r;
        out[row * G4H + gcol] = (bf16)(acc[mt][nt][r] + bv);
      }
  }
}

__device__ __forceinline__
void rec0_slice(char* smem, const int* x, int is32, const bf16x8* wb0,
                const unsigned short* table, bf16* hreg, float* cws0,
                int t0, int bid) {
  const int tid = threadIdx.x, w = tid >> 6, l = tid & 63, lg = l >> 4, ln = l & 15;
  const int b0 = bid * 16, hb = w * 32;
  float c[2][4];
  if (t0 == 0) {
    #pragma unroll
    for (int j = 0; j < 2; ++j)
      #pragma unroll
      for (int r = 0; r < 4; ++r) c[j][r] = 0.f;
  } else {
    #pragma unroll
    for (int j = 0; j < 2; ++j)
      #pragma unroll
      for (int r = 0; r < 4; ++r)
        c[j][r] = cws0[(size_t)(b0 + lg * 4 + r) * HH + hb + 16 * j + ln];
  }
  rec0_body(smem, x, is32, wb0, table, hreg, c, t0, bid, t0 != 0);
  #pragma unroll
  for (int j = 0; j < 2; ++j)
    #pragma unroll
    for (int r = 0; r < 4; ++r)
      cws0[(size_t)(b0 + lg * 4 + r) * HH + hb + 16 * j + ln] = c[j][r];
}

// ---------------------------------------------------------------------------
// 3-stage pipeline launch k: blocks 0-31 rec0(k); 32-63 rec1(k-2); 64+ xg(k-1).
// ---------------------------------------------------------------------------
__global__ __launch_bounds__(512)
void pipe_kernel(const int* __restrict__ x, const int* __restrict__ flagp,
                 const bf16x8* __restrict__ wb0,
                 const unsigned short* __restrict__ table,
                 const unsigned short* __restrict__ xg_in,
                 const bf16x8* __restrict__ wb1,
                 bf16* __restrict__ hreg, float* __restrict__ cws0,
                 float* __restrict__ cws1, int k,
                 const float* __restrict__ Wi, const float* __restrict__ bi,
                 const float* __restrict__ bh, bf16* __restrict__ xg_out) {
  __shared__ __align__(16) char smem[163840];
  const int bx = blockIdx.x;
  if (bx < 32) {
    if (k < NSEG) rec0_slice(smem, x, *flagp, wb0, table, hreg, cws0, k * TSL, bx);
  } else if (bx < 64) {
    if (k >= 2) rec1_body(smem, xg_in, wb1, hreg, cws1, (k - 2) * TSL, bx - 32);
  } else {
    if (k >= 1 && k <= NSEG)
      xg_body(smem, hreg, Wi, bi, bh, xg_out, (k - 1) * TSL, bx - 64);
  }
}

// ---------------------------------------------------------------------------
// Fallback path kernels.
// ---------------------------------------------------------------------------
__global__ __launch_bounds__(512)
void rec0_full_kernel(const int* __restrict__ x, const int* __restrict__ flagp,
                      const bf16x8* __restrict__ wb,
                      const unsigned short* __restrict__ table,
                      bf16* __restrict__ h1) {
  __shared__ __align__(16) char smem[147456];
  const int is32 = *flagp;
  float c[2][4] = {};
  #pragma unroll 1
  for (int s = 0; s < NSEG; ++s) {
    rec0_body(smem, x, is32, wb, table, h1, c, s * TSL, blockIdx.x, false);
    __syncthreads();
  }
}

__global__ __launch_bounds__(512)
void combo_kernel(const unsigned short* __restrict__ xg_in,
                  const bf16x8* __restrict__ wb, bf16* __restrict__ hreg,
                  float* __restrict__ cws, int t0,
                  const float* __restrict__ Wi, const float* __restrict__ bi,
                  const float* __restrict__ bh, bf16* __restrict__ xg_out) {
  __shared__ __align__(16) char smem[163840];
  if (blockIdx.x < 32)
    rec1_body(smem, xg_in, wb, hreg, cws, t0, blockIdx.x);
  else
    xg_body(smem, hreg, Wi, bi, bh, xg_out, t0 + TSL, blockIdx.x - 32);
}

__global__ __launch_bounds__(512)
void xg_kernel(const bf16* __restrict__ A, const float* __restrict__ W,
               const float* __restrict__ bi, const float* __restrict__ bh,
               bf16* __restrict__ out, int t0) {
  __shared__ __align__(16) char smem[163840];
  xg_body(smem, A, W, bi, bh, out, t0, blockIdx.x);
}

// ---------------------------------------------------------------------------
// proj GEMM (fp32 out, dense row-major — already coalesced).
// ---------------------------------------------------------------------------
__global__ __launch_bounds__(512)
void proj_kernel(const bf16* __restrict__ A, const float* __restrict__ W,
                 const float* __restrict__ bias0, float* __restrict__ out) {
  __shared__ bf16x8 alds[4096];
  __shared__ bf16x8 blds[4096];
  const int tid = threadIdx.x, w = tid >> 6, l = tid & 63, lg = l >> 4, ln = l & 15;
  const int wm = w & 1, wn = w >> 1;
  const int R0 = blockIdx.x * 128, N0 = blockIdx.y * 128;
  {
    const int row = tid >> 2, seg = tid & 3;
    const bf16* asrc = A + ((size_t)R0 + row) * HH + seg * 64;
    #pragma unroll
    for (int k = 0; k < 8; ++k) {
      const int g = seg * 8 + k;
      alds[row * 32 + (g ^ (row & 7))] = *(const bf16x8*)(asrc + k * 8);
    }
    const float* bsrc = W + (size_t)(N0 + row) * HH + seg * 64;
    #pragma unroll
    for (int k = 0; k < 8; ++k) {
      const int g = seg * 8 + k;
      blds[row * 32 + (g ^ (row & 7))] = cvt8(bsrc + k * 8);
    }
  }
  __syncthreads();
  f32x4 acc[4][2] = {};
  #pragma unroll
  for (int kc = 0; kc < 8; ++kc) {
    bf16x8 bfr[2];
    #pragma unroll
    for (int nt = 0; nt < 2; ++nt) {
      const int row = wn * 32 + nt * 16 + ln;
      bfr[nt] = blds[row * 32 + ((kc * 4 + lg) ^ (row & 7))];
    }
    #pragma unroll
    for (int mt = 0; mt < 4; ++mt) {
      const int row = wm * 64 + mt * 16 + ln;
      bf16x8 a = alds[row * 32 + ((kc * 4 + lg) ^ (row & 7))];
      #pragma unroll
      for (int nt = 0; nt < 2; ++nt)
        acc[mt][nt] = __builtin_amdgcn_mfma_f32_16x16x32_bf16(a, bfr[nt], acc[mt][nt], 0, 0, 0);
    }
  }
  #pragma unroll
  for (int nt = 0; nt < 2; ++nt) {
    const int n = N0 + wn * 32 + nt * 16 + ln;
    const float bv = bias0[n];
    #pragma unroll
    for (int mt = 0; mt < 4; ++mt)
      #pragma unroll
      for (int r = 0; r < 4; ++r) {
        const size_t row = (size_t)R0 + wm * 64 + mt * 16 + lg * 4 + r;
        out[row * VV + n] = acc[mt][nt][r] + bv;
      }
  }
}

extern "C" void kernel_launch(void* const* d_in, const int* in_sizes, int n_in,
                              void* d_out, int out_size, void* d_ws, size_t ws_size,
                              hipStream_t stream) {
  const int*   x   = (const int*)d_in[0];
  const float* emb = (const float*)d_in[1];
  const float* Wi0 = (const float*)d_in[2];
  const float* bi0 = (const float*)d_in[3];
  const float* Wh0 = (const float*)d_in[4];
  const float* bh0 = (const float*)d_in[5];
  const float* Wi1 = (const float*)d_in[6];
  const float* bi1 = (const float*)d_in[7];
  const float* Wh1 = (const float*)d_in[8];
  const float* bh1 = (const float*)d_in[9];
  const float* Wg  = (const float*)d_in[10];
  const float* bg  = (const float*)d_in[11];

  char* ws = (char*)d_ws;
  int* flag = (int*)ws;
  unsigned short* table = (unsigned short*)(ws + 256);
  bf16x8* wb0 = (bf16x8*)(ws + 256 + 262144);
  bf16x8* wb1 = (bf16x8*)(ws + 256 + 262144 + 524288);
  bf16* hreg = (bf16*)(ws + 256 + 262144 + 524288 + 524288);
  const size_t need_base = 256 + 262144 + 524288 + 524288
                         + (size_t)BB * SS * HH * sizeof(bf16);
  float* cws0 = (float*)(ws + need_base);
  float* cws1 = (float*)(ws + need_base + 524288);
  const size_t need_full = need_base + 2 * 524288;
  if (ws_size < need_base) return;

  bf16* xgbuf0 = (bf16*)d_out;
  bf16* xgbuf1 = (bf16*)((char*)d_out + (size_t)BB * TSL * G4H * sizeof(bf16));

  (void)hipMemsetAsync(flag, 0, sizeof(int), stream);
  detect_kernel<<<dim3(8), dim3(256), 0, stream>>>(x, flag);
  table_kernel<<<dim3(4, 128), dim3(256), 0, stream>>>(emb, Wi0, bi0, bh0, table);
  wprep_kernel<<<dim3(128, 2), dim3(256), 0, stream>>>(Wh0, Wh1, wb0, wb1);

  if (ws_size >= need_full) {
    for (int k = 0; k <= NSEG + 1; ++k) {
      bf16* xin  = (k & 1) ? xgbuf1 : xgbuf0;   // slice k-2 buffer
      bf16* xout = (k & 1) ? xgbuf0 : xgbuf1;   // slice k-1 buffer
      const bool xgv = (k >= 1 && k <= NSEG);
      const int nblk = 64 + (xgv ? 2048 : 0);
      pipe_kernel<<<dim3(nblk), dim3(512), 0, stream>>>(
          x, flag, wb0, table, (const unsigned short*)xin, wb1,
          hreg, cws0, cws1, k, Wi1, bi1, bh1, xout);
    }
  } else {
    float* cwsA = (float*)wb0;  // wb0 dead after rec0_full completes
    rec0_full_kernel<<<dim3(32), dim3(512), 0, stream>>>(x, flag, wb0, table, hreg);
    xg_kernel<<<dim3(2048), dim3(512), 0, stream>>>(hreg, Wi1, bi1, bh1, xgbuf0, 0);
    for (int s = 0; s < NSEG; ++s) {
      const int t0 = s * TSL;
      bf16* xin  = (s & 1) ? xgbuf1 : xgbuf0;
      bf16* xout = (s & 1) ? xgbuf0 : xgbuf1;
      const int nblk = 32 + ((s + 1 < NSEG) ? 2048 : 0);
      combo_kernel<<<dim3(nblk), dim3(512), 0, stream>>>(
          (const unsigned short*)xin, wb1, hreg, cwsA, t0, Wi1, bi1, bh1, xout);
    }
  }
  proj_kernel<<<dim3(BB * SS / 128, VV / 128), dim3(512), 0, stream>>>(
      hreg, Wg, bg, (float*)d_out);
}

// Round 21
// 2700.279 us; speedup vs baseline: 2.5874x; 1.0048x over previous
//
#include <hip/hip_runtime.h>
#include <hip/hip_bf16.h>

#define BB 512
#define SS 512
#define EE 128
#define HH 256
#define VV 128
#define G4H 1024
#define TSL 64              // slice length
#define NSEG (SS / TSL)     // 8

using bf16 = __bf16;
typedef __attribute__((ext_vector_type(8))) __bf16 bf16x8;
typedef __attribute__((ext_vector_type(4))) float f32x4;

__device__ __forceinline__ float rcpf(float x) { return __builtin_amdgcn_rcpf(x); }
__device__ __forceinline__ float exp2f_(float x) { return __builtin_amdgcn_exp2f(x); }
__device__ __forceinline__ float sigf(float x) {
  return rcpf(1.0f + exp2f_(-1.442695041f * x));
}
__device__ __forceinline__ float tanh_(float x) {
  return 2.0f * rcpf(1.0f + exp2f_(-2.885390082f * x)) - 1.0f;
}
__device__ __forceinline__ bf16x8 cvt8(const float* __restrict__ s) {
  bf16x8 f;
  #pragma unroll
  for (int j = 0; j < 8; ++j) f[j] = (bf16)s[j];
  return f;
}
__device__ __forceinline__ float bf2f(unsigned short u) {
  return __uint_as_float(((unsigned)u) << 16);
}

__global__ void detect_kernel(const int* __restrict__ x, int* __restrict__ flag) {
  const int i = blockIdx.x * 256 + threadIdx.x;
  if (x[2 * i + 1] != 0) atomicOr(flag, 1);
}

__global__ __launch_bounds__(256)
void table_kernel(const float* __restrict__ emb, const float* __restrict__ Wi,
                  const float* __restrict__ bi, const float* __restrict__ bh,
                  unsigned short* __restrict__ table) {
  const int g = blockIdx.x * 256 + threadIdx.x;
  const int v = blockIdx.y;
  float s = bi[g] + bh[g];
  const float* er = emb + v * EE;
  const float* wr = Wi + (size_t)g * EE;
  #pragma unroll 4
  for (int e = 0; e < EE; ++e) s += er[e] * wr[e];
  const bf16 b = (bf16)s;
  table[v * G4H + (g & 255) * 4 + (g >> 8)] = *(const unsigned short*)&b;
}

__global__ __launch_bounds__(256)
void wprep_kernel(const float* __restrict__ Wh0, const float* __restrict__ Wh1,
                  bf16x8* __restrict__ wb0, bf16x8* __restrict__ wb1) {
  const int idx = blockIdx.x * 256 + threadIdx.x;
  const int l = idx & 63, kc = (idx >> 6) & 7, s = (idx >> 9) & 7, w = idx >> 12;
  const int lg = l >> 4, ln = l & 15;
  const int n = (s >> 1) * HH + w * 32 + 16 * (s & 1) + ln;
  const int k0 = kc * 32 + lg * 8;
  const float* src = (blockIdx.y ? Wh1 : Wh0) + (size_t)n * HH + k0;
  (blockIdx.y ? wb1 : wb0)[idx] = cvt8(src);
}

// Wi1 (fp32 [1024][256]) -> bf16 granules in xg B-stage layout:
// granule idx = up*8192 + col*32 + g holds Wi1[n][g*8..g*8+8),
// n = (col&3)*256 + up*64 + (col>>2). Identical rounding to stage-time cvt.
__global__ __launch_bounds__(256)
void wiprep_kernel(const float* __restrict__ Wi1, bf16x8* __restrict__ wbi) {
  const int idx = blockIdx.x * 256 + threadIdx.x;   // 0..32767
  const int g = idx & 31, col = (idx >> 5) & 255, up = idx >> 13;
  const int n = (col & 3) * HH + up * 64 + (col >> 2);
  wbi[idx] = cvt8(Wi1 + (size_t)n * HH + g * 8);
}

// ---------------------------------------------------------------------------
// rec0 slice body (R20 verbatim).
// ---------------------------------------------------------------------------
__device__ __forceinline__
void rec0_body(char* smem, const int* __restrict__ x, int is32,
               const bf16x8* __restrict__ wb,
               const unsigned short* __restrict__ table,
               bf16* __restrict__ h1, float (*cst)[4],
               int t0, int bid, bool load_h) {
  bf16 (*hbuf)[4096] = (bf16(*)[4096])smem;
  bf16x8* wlds = (bf16x8*)(smem + 16384);
  const int tid = threadIdx.x, w = tid >> 6, l = tid & 63, lg = l >> 4, ln = l & 15;
  const int b0 = bid * 16, hb = w * 32;

  bf16x8 Wf[4][8];
  #pragma unroll
  for (int s = 0; s < 4; ++s)
    #pragma unroll
    for (int kc = 0; kc < 8; ++kc)
      Wf[s][kc] = wb[w * 4096 + s * 512 + kc * 64 + l];
  #pragma unroll
  for (int j = 0; j < 2; ++j)
    #pragma unroll
    for (int kc = 0; kc < 8; ++kc)
      wlds[((w * 2 + j) * 8 + kc) * 64 + l] = wb[w * 4096 + (6 + j) * 512 + kc * 64 + l];
  const bf16x8* __restrict__ gsrc0 = wb + w * 4096 + 4 * 512 + l;
  const bf16x8* __restrict__ gsrc1 = wb + w * 4096 + 5 * 512 + l;

  int hoff[4];
  #pragma unroll
  for (int r = 0; r < 4; ++r)
    hoff[r] = ((b0 + lg * 4 + r) * SS) * HH + hb + ln;

  if (t0 == 0) {
    bf16x8 z = {};
    ((bf16x8*)&hbuf[0][0])[tid] = z;
  } else if (load_h) {
    #pragma unroll
    for (int j = 0; j < 2; ++j)
      #pragma unroll
      for (int r = 0; r < 4; ++r) {
        const int m = lg * 4 + r, col = hb + 16 * j + ln;
        const bf16 hv = h1[((size_t)(b0 + m) * SS + (t0 - 1)) * HH + col];
        hbuf[0][(w * 64 + m * 4 + 2 * j + (ln >> 3)) * 8 + (ln & 7)] = hv;
      }
  }
  int idx[4];
  #pragma unroll
  for (int r = 0; r < 4; ++r) {
    const long xi = (long)(b0 + lg * 4 + r) * SS + t0;
    idx[r] = x[is32 ? xi : 2 * xi] & 127;
  }
  __syncthreads();

  #pragma unroll 1
  for (int tt = 0; tt < TSL; ++tt) {
    const int t = t0 + tt, p = tt & 1;
    ushort4 tj[4][2];
    #pragma unroll
    for (int r = 0; r < 4; ++r) {
      const unsigned short* base = table + (size_t)idx[r] * G4H + (hb + ln) * 4;
      tj[r][0] = *(const ushort4*)base;
      tj[r][1] = *(const ushort4*)(base + 64);
    }
    if (tt + 1 < TSL) {
      #pragma unroll
      for (int r = 0; r < 4; ++r) {
        const long xi = (long)(b0 + lg * 4 + r) * SS + (t + 1);
        idx[r] = x[is32 ? xi : 2 * xi] & 127;
      }
    }
    f32x4 acc[4][2] = {};
    #pragma unroll
    for (int kc = 0; kc < 8; ++kc) {
      bf16x8 a = ((const bf16x8*)&hbuf[p][0])[kc * 64 + ln * 4 + lg];
      acc[0][0] = __builtin_amdgcn_mfma_f32_16x16x32_bf16(a, Wf[0][kc], acc[0][0], 0, 0, 0);
      acc[0][1] = __builtin_amdgcn_mfma_f32_16x16x32_bf16(a, Wf[1][kc], acc[0][1], 0, 0, 0);
      acc[1][0] = __builtin_amdgcn_mfma_f32_16x16x32_bf16(a, Wf[2][kc], acc[1][0], 0, 0, 0);
      acc[1][1] = __builtin_amdgcn_mfma_f32_16x16x32_bf16(a, Wf[3][kc], acc[1][1], 0, 0, 0);
      acc[2][0] = __builtin_amdgcn_mfma_f32_16x16x32_bf16(a, gsrc0[kc * 64], acc[2][0], 0, 0, 0);
      acc[2][1] = __builtin_amdgcn_mfma_f32_16x16x32_bf16(a, gsrc1[kc * 64], acc[2][1], 0, 0, 0);
      #pragma unroll
      for (int j = 0; j < 2; ++j) {
        bf16x8 bw = wlds[((w * 2 + j) * 8 + kc) * 64 + l];
        acc[3][j] = __builtin_amdgcn_mfma_f32_16x16x32_bf16(a, bw, acc[3][j], 0, 0, 0);
      }
    }
    #pragma unroll
    for (int j = 0; j < 2; ++j)
      #pragma unroll
      for (int r = 0; r < 4; ++r) {
        const float fg = sigf(acc[0][j][r] + bf2f(tj[r][j].x));
        const float ig = sigf(acc[1][j][r] + bf2f(tj[r][j].y));
        const float gg = tanh_(acc[2][j][r] + bf2f(tj[r][j].z));
        const float og = sigf(acc[3][j][r] + bf2f(tj[r][j].w));
        const float cc = fg * cst[j][r] + ig * gg;
        cst[j][r] = cc;
        const bf16 hv = (bf16)(og * tanh_(cc));
        const int m = lg * 4 + r;
        hbuf[p ^ 1][(w * 64 + m * 4 + 2 * j + (ln >> 3)) * 8 + (ln & 7)] = hv;
        h1[hoff[r] + t * HH + 16 * j] = hv;
      }
    __syncthreads();
  }
}

// ---------------------------------------------------------------------------
// rec1 slice body (R20 verbatim).
// ---------------------------------------------------------------------------
__device__ __forceinline__
void rec1_body(char* smem, const unsigned short* __restrict__ xg,
               const bf16x8* __restrict__ wb, bf16* __restrict__ hreg,
               float* __restrict__ cws, int t0, int bid) {
  bf16 (*hbuf)[4096] = (bf16(*)[4096])smem;
  bf16x8* wlds = (bf16x8*)(smem + 16384);
  const int tid = threadIdx.x, w = tid >> 6, l = tid & 63, lg = l >> 4, ln = l & 15;
  const int b0 = bid * 16, hb = w * 32;

  bf16x8 Wf[4][8];
  #pragma unroll
  for (int s = 0; s < 4; ++s)
    #pragma unroll
    for (int kc = 0; kc < 8; ++kc)
      Wf[s][kc] = wb[w * 4096 + s * 512 + kc * 64 + l];
  #pragma unroll
  for (int j = 0; j < 2; ++j)
    #pragma unroll
    for (int kc = 0; kc < 8; ++kc)
      wlds[((w * 2 + j) * 8 + kc) * 64 + l] = wb[w * 4096 + (6 + j) * 512 + kc * 64 + l];
  const bf16x8* __restrict__ gsrc0 = wb + w * 4096 + 4 * 512 + l;
  const bf16x8* __restrict__ gsrc1 = wb + w * 4096 + 5 * 512 + l;

  int hoff[4];
  size_t xbase[4];
  #pragma unroll
  for (int r = 0; r < 4; ++r) {
    hoff[r] = ((b0 + lg * 4 + r) * SS) * HH + hb + ln;
    xbase[r] = (size_t)(b0 + lg * 4 + r) * TSL * G4H + (hb + ln) * 4;
  }

  float c[2][4];
  if (t0 == 0) {
    #pragma unroll
    for (int j = 0; j < 2; ++j)
      #pragma unroll
      for (int r = 0; r < 4; ++r) c[j][r] = 0.f;
    bf16x8 z = {};
    ((bf16x8*)&hbuf[0][0])[tid] = z;
  } else {
    #pragma unroll
    for (int j = 0; j < 2; ++j)
      #pragma unroll
      for (int r = 0; r < 4; ++r) {
        const int m = lg * 4 + r, col = hb + 16 * j + ln;
        c[j][r] = cws[(size_t)(b0 + m) * HH + col];
        const bf16 hv = hreg[((size_t)(b0 + m) * SS + (t0 - 1)) * HH + col];
        hbuf[0][(w * 64 + m * 4 + 2 * j + (ln >> 3)) * 8 + (ln & 7)] = hv;
      }
  }
  __syncthreads();

  #pragma unroll 1
  for (int tt = 0; tt < TSL; ++tt) {
    const int t = t0 + tt, p = tt & 1;
    ushort4 tj[4][2];
    #pragma unroll
    for (int r = 0; r < 4; ++r) {
      const unsigned short* base = xg + xbase[r] + (size_t)tt * G4H;
      tj[r][0] = *(const ushort4*)base;
      tj[r][1] = *(const ushort4*)(base + 64);
    }
    f32x4 acc[4][2] = {};
    #pragma unroll
    for (int kc = 0; kc < 8; ++kc) {
      bf16x8 a = ((const bf16x8*)&hbuf[p][0])[kc * 64 + ln * 4 + lg];
      acc[0][0] = __builtin_amdgcn_mfma_f32_16x16x32_bf16(a, Wf[0][kc], acc[0][0], 0, 0, 0);
      acc[0][1] = __builtin_amdgcn_mfma_f32_16x16x32_bf16(a, Wf[1][kc], acc[0][1], 0, 0, 0);
      acc[1][0] = __builtin_amdgcn_mfma_f32_16x16x32_bf16(a, Wf[2][kc], acc[1][0], 0, 0, 0);
      acc[1][1] = __builtin_amdgcn_mfma_f32_16x16x32_bf16(a, Wf[3][kc], acc[1][1], 0, 0, 0);
      acc[2][0] = __builtin_amdgcn_mfma_f32_16x16x32_bf16(a, gsrc0[kc * 64], acc[2][0], 0, 0, 0);
      acc[2][1] = __builtin_amdgcn_mfma_f32_16x16x32_bf16(a, gsrc1[kc * 64], acc[2][1], 0, 0, 0);
      #pragma unroll
      for (int j = 0; j < 2; ++j) {
        bf16x8 bw = wlds[((w * 2 + j) * 8 + kc) * 64 + l];
        acc[3][j] = __builtin_amdgcn_mfma_f32_16x16x32_bf16(a, bw, acc[3][j], 0, 0, 0);
      }
    }
    #pragma unroll
    for (int j = 0; j < 2; ++j)
      #pragma unroll
      for (int r = 0; r < 4; ++r) {
        const float fg = sigf(acc[0][j][r] + bf2f(tj[r][j].x));
        const float ig = sigf(acc[1][j][r] + bf2f(tj[r][j].y));
        const float gg = tanh_(acc[2][j][r] + bf2f(tj[r][j].z));
        const float og = sigf(acc[3][j][r] + bf2f(tj[r][j].w));
        const float cc = fg * c[j][r] + ig * gg;
        c[j][r] = cc;
        const bf16 hv = (bf16)(og * tanh_(cc));
        const int m = lg * 4 + r;
        hbuf[p ^ 1][(w * 64 + m * 4 + 2 * j + (ln >> 3)) * 8 + (ln & 7)] = hv;
        hreg[hoff[r] + t * HH + 16 * j] = hv;
      }
    __syncthreads();
  }
  #pragma unroll
  for (int j = 0; j < 2; ++j)
    #pragma unroll
    for (int r = 0; r < 4; ++r)
      cws[(size_t)(b0 + lg * 4 + r) * HH + hb + 16 * j + ln] = c[j][r];
}

// ---------------------------------------------------------------------------
// xg GEMM body: 64 rows x 256 gate-cols. WB16==1: B from pre-converted bf16
// wbi (halved L2 reads, no cvt); WB16==0: B from fp32 Wi1 (fallback).
// ---------------------------------------------------------------------------
template <int WB16>
__device__ __forceinline__
void xg_body(char* smem, const bf16* __restrict__ A, const void* __restrict__ Wb,
             const float* __restrict__ bias0, const float* __restrict__ bias1,
             bf16* __restrict__ out, int t0, int flat) {
  bf16x8* alds = (bf16x8*)smem;                       // 32 KB
  bf16x8* blds = (bf16x8*)(smem + 32768);             // 128 KB
  const int tid = threadIdx.x, w = tid >> 6, l = tid & 63, lg = l >> 4, ln = l & 15;
  const int wm = w & 1, wn = w >> 1;
  const int rb = flat & 511, up = flat >> 9;
  const int R0 = rb * 64;
  {
    const int row = tid >> 3, seg = tid & 7;
    const bf16* asrc = A + ((size_t)rb * SS + t0 + row) * HH + seg * 32;
    #pragma unroll
    for (int k = 0; k < 4; ++k) {
      const int g = seg * 4 + k;
      alds[row * 32 + (g ^ (row & 7))] = *(const bf16x8*)(asrc + k * 8);
    }
    const int col = tid >> 1, half = tid & 1;
    if (WB16) {
      const bf16x8* bsrc = (const bf16x8*)Wb + up * 8192 + col * 32 + half * 16;
      #pragma unroll
      for (int k = 0; k < 16; ++k) {
        const int g = half * 16 + k;
        blds[col * 32 + (g ^ (col & 7))] = bsrc[k];
      }
    } else {
      const int n = (col & 3) * HH + up * 64 + (col >> 2);
      const float* bsrc = (const float*)Wb + (size_t)n * HH + half * 128;
      #pragma unroll
      for (int k = 0; k < 16; ++k) {
        const int g = half * 16 + k;
        blds[col * 32 + (g ^ (col & 7))] = cvt8(bsrc + k * 8);
      }
    }
  }
  __syncthreads();
  f32x4 acc[2][4] = {};
  #pragma unroll
  for (int kc = 0; kc < 8; ++kc) {
    bf16x8 bfr[4];
    #pragma unroll
    for (int nt = 0; nt < 4; ++nt) {
      const int row = wn * 64 + nt * 16 + ln;
      bfr[nt] = blds[row * 32 + ((kc * 4 + lg) ^ (row & 7))];
    }
    #pragma unroll
    for (int mt = 0; mt < 2; ++mt) {
      const int row = wm * 32 + mt * 16 + ln;
      bf16x8 a = alds[row * 32 + ((kc * 4 + lg) ^ (row & 7))];
      #pragma unroll
      for (int nt = 0; nt < 4; ++nt)
        acc[mt][nt] = __builtin_amdgcn_mfma_f32_16x16x32_bf16(a, bfr[nt], acc[mt][nt], 0, 0, 0);
    }
  }
  #pragma unroll
  for (int nt = 0; nt < 4; ++nt) {
    const int local = wn * 64 + nt * 16 + ln;
    const int n = (local & 3) * HH + up * 64 + (local >> 2);
    const float bv = bias0[n] + bias1[n];
    const int gcol = up * 256 + local;
    #pragma unroll
    for (int mt = 0; mt < 2; ++mt)
      #pragma unroll
      for (int r = 0; r < 4; ++r) {
        const size_t row = (size_t)R0 + wm * 32 + mt * 16 + lg * 4 + r;
        out[row * G4H + gcol] = (bf16)(acc[mt][nt][r] + bv);
      }
  }
}

__device__ __forceinline__
void rec0_slice(char* smem, const int* x, int is32, const bf16x8* wb0,
                const unsigned short* table, bf16* hreg, float* cws0,
                int t0, int bid) {
  const int tid = threadIdx.x, w = tid >> 6, l = tid & 63, lg = l >> 4, ln = l & 15;
  const int b0 = bid * 16, hb = w * 32;
  float c[2][4];
  if (t0 == 0) {
    #pragma unroll
    for (int j = 0; j < 2; ++j)
      #pragma unroll
      for (int r = 0; r < 4; ++r) c[j][r] = 0.f;
  } else {
    #pragma unroll
    for (int j = 0; j < 2; ++j)
      #pragma unroll
      for (int r = 0; r < 4; ++r)
        c[j][r] = cws0[(size_t)(b0 + lg * 4 + r) * HH + hb + 16 * j + ln];
  }
  rec0_body(smem, x, is32, wb0, table, hreg, c, t0, bid, t0 != 0);
  #pragma unroll
  for (int j = 0; j < 2; ++j)
    #pragma unroll
    for (int r = 0; r < 4; ++r)
      cws0[(size_t)(b0 + lg * 4 + r) * HH + hb + 16 * j + ln] = c[j][r];
}

// ---------------------------------------------------------------------------
// 3-stage pipeline launch k: blocks 0-31 rec0(k); 32-63 rec1(k-2); 64+ xg(k-1).
// ---------------------------------------------------------------------------
__global__ __launch_bounds__(512)
void pipe_kernel(const int* __restrict__ x, const int* __restrict__ flagp,
                 const bf16x8* __restrict__ wb0,
                 const unsigned short* __restrict__ table,
                 const unsigned short* __restrict__ xg_in,
                 const bf16x8* __restrict__ wb1,
                 bf16* __restrict__ hreg, float* __restrict__ cws0,
                 float* __restrict__ cws1, int k,
                 const bf16x8* __restrict__ wbi, const float* __restrict__ bi,
                 const float* __restrict__ bh, bf16* __restrict__ xg_out) {
  __shared__ __align__(16) char smem[163840];
  const int bx = blockIdx.x;
  if (bx < 32) {
    if (k < NSEG) rec0_slice(smem, x, *flagp, wb0, table, hreg, cws0, k * TSL, bx);
  } else if (bx < 64) {
    if (k >= 2) rec1_body(smem, xg_in, wb1, hreg, cws1, (k - 2) * TSL, bx - 32);
  } else {
    if (k >= 1 && k <= NSEG)
      xg_body<1>(smem, hreg, wbi, bi, bh, xg_out, (k - 1) * TSL, bx - 64);
  }
}

// ---------------------------------------------------------------------------
// Fallback path kernels (fp32 Wi1 xg).
// ---------------------------------------------------------------------------
__global__ __launch_bounds__(512)
void rec0_full_kernel(const int* __restrict__ x, const int* __restrict__ flagp,
                      const bf16x8* __restrict__ wb,
                      const unsigned short* __restrict__ table,
                      bf16* __restrict__ h1) {
  __shared__ __align__(16) char smem[147456];
  const int is32 = *flagp;
  float c[2][4] = {};
  #pragma unroll 1
  for (int s = 0; s < NSEG; ++s) {
    rec0_body(smem, x, is32, wb, table, h1, c, s * TSL, blockIdx.x, false);
    __syncthreads();
  }
}

__global__ __launch_bounds__(512)
void combo_kernel(const unsigned short* __restrict__ xg_in,
                  const bf16x8* __restrict__ wb, bf16* __restrict__ hreg,
                  float* __restrict__ cws, int t0,
                  const float* __restrict__ Wi, const float* __restrict__ bi,
                  const float* __restrict__ bh, bf16* __restrict__ xg_out) {
  __shared__ __align__(16) char smem[163840];
  if (blockIdx.x < 32)
    rec1_body(smem, xg_in, wb, hreg, cws, t0, blockIdx.x);
  else
    xg_body<0>(smem, hreg, Wi, bi, bh, xg_out, t0 + TSL, blockIdx.x - 32);
}

__global__ __launch_bounds__(512)
void xg_kernel(const bf16* __restrict__ A, const float* __restrict__ W,
               const float* __restrict__ bi, const float* __restrict__ bh,
               bf16* __restrict__ out, int t0) {
  __shared__ __align__(16) char smem[163840];
  xg_body<0>(smem, A, W, bi, bh, out, t0, blockIdx.x);
}

// ---------------------------------------------------------------------------
// proj GEMM (R20 verbatim).
// ---------------------------------------------------------------------------
__global__ __launch_bounds__(512)
void proj_kernel(const bf16* __restrict__ A, const float* __restrict__ W,
                 const float* __restrict__ bias0, float* __restrict__ out) {
  __shared__ bf16x8 alds[4096];
  __shared__ bf16x8 blds[4096];
  const int tid = threadIdx.x, w = tid >> 6, l = tid & 63, lg = l >> 4, ln = l & 15;
  const int wm = w & 1, wn = w >> 1;
  const int R0 = blockIdx.x * 128, N0 = blockIdx.y * 128;
  {
    const int row = tid >> 2, seg = tid & 3;
    const bf16* asrc = A + ((size_t)R0 + row) * HH + seg * 64;
    #pragma unroll
    for (int k = 0; k < 8; ++k) {
      const int g = seg * 8 + k;
      alds[row * 32 + (g ^ (row & 7))] = *(const bf16x8*)(asrc + k * 8);
    }
    const float* bsrc = W + (size_t)(N0 + row) * HH + seg * 64;
    #pragma unroll
    for (int k = 0; k < 8; ++k) {
      const int g = seg * 8 + k;
      blds[row * 32 + (g ^ (row & 7))] = cvt8(bsrc + k * 8);
    }
  }
  __syncthreads();
  f32x4 acc[4][2] = {};
  #pragma unroll
  for (int kc = 0; kc < 8; ++kc) {
    bf16x8 bfr[2];
    #pragma unroll
    for (int nt = 0; nt < 2; ++nt) {
      const int row = wn * 32 + nt * 16 + ln;
      bfr[nt] = blds[row * 32 + ((kc * 4 + lg) ^ (row & 7))];
    }
    #pragma unroll
    for (int mt = 0; mt < 4; ++mt) {
      const int row = wm * 64 + mt * 16 + ln;
      bf16x8 a = alds[row * 32 + ((kc * 4 + lg) ^ (row & 7))];
      #pragma unroll
      for (int nt = 0; nt < 2; ++nt)
        acc[mt][nt] = __builtin_amdgcn_mfma_f32_16x16x32_bf16(a, bfr[nt], acc[mt][nt], 0, 0, 0);
    }
  }
  #pragma unroll
  for (int nt = 0; nt < 2; ++nt) {
    const int n = N0 + wn * 32 + nt * 16 + ln;
    const float bv = bias0[n];
    #pragma unroll
    for (int mt = 0; mt < 4; ++mt)
      #pragma unroll
      for (int r = 0; r < 4; ++r) {
        const size_t row = (size_t)R0 + wm * 64 + mt * 16 + lg * 4 + r;
        out[row * VV + n] = acc[mt][nt][r] + bv;
      }
  }
}

extern "C" void kernel_launch(void* const* d_in, const int* in_sizes, int n_in,
                              void* d_out, int out_size, void* d_ws, size_t ws_size,
                              hipStream_t stream) {
  const int*   x   = (const int*)d_in[0];
  const float* emb = (const float*)d_in[1];
  const float* Wi0 = (const float*)d_in[2];
  const float* bi0 = (const float*)d_in[3];
  const float* Wh0 = (const float*)d_in[4];
  const float* bh0 = (const float*)d_in[5];
  const float* Wi1 = (const float*)d_in[6];
  const float* bi1 = (const float*)d_in[7];
  const float* Wh1 = (const float*)d_in[8];
  const float* bh1 = (const float*)d_in[9];
  const float* Wg  = (const float*)d_in[10];
  const float* bg  = (const float*)d_in[11];

  // ws: [flag 256B][table 256KB][wb0 512KB][wb1 512KB][hreg 128MB]
  //     [cws0 512KB][cws1 512KB][wbi 512KB]   (137.1MB; ws >= 145MB proven R2)
  char* ws = (char*)d_ws;
  int* flag = (int*)ws;
  unsigned short* table = (unsigned short*)(ws + 256);
  bf16x8* wb0 = (bf16x8*)(ws + 256 + 262144);
  bf16x8* wb1 = (bf16x8*)(ws + 256 + 262144 + 524288);
  bf16* hreg = (bf16*)(ws + 256 + 262144 + 524288 + 524288);
  const size_t need_base = 256 + 262144 + 524288 + 524288
                         + (size_t)BB * SS * HH * sizeof(bf16);
  float* cws0 = (float*)(ws + need_base);
  float* cws1 = (float*)(ws + need_base + 524288);
  bf16x8* wbi = (bf16x8*)(ws + need_base + 2 * 524288);
  const size_t need_full = need_base + 3 * 524288;
  if (ws_size < need_base) return;

  bf16* xgbuf0 = (bf16*)d_out;
  bf16* xgbuf1 = (bf16*)((char*)d_out + (size_t)BB * TSL * G4H * sizeof(bf16));

  (void)hipMemsetAsync(flag, 0, sizeof(int), stream);
  detect_kernel<<<dim3(8), dim3(256), 0, stream>>>(x, flag);
  table_kernel<<<dim3(4, 128), dim3(256), 0, stream>>>(emb, Wi0, bi0, bh0, table);
  wprep_kernel<<<dim3(128, 2), dim3(256), 0, stream>>>(Wh0, Wh1, wb0, wb1);

  if (ws_size >= need_full) {
    wiprep_kernel<<<dim3(128), dim3(256), 0, stream>>>(Wi1, wbi);
    for (int k = 0; k <= NSEG + 1; ++k) {
      bf16* xin  = (k & 1) ? xgbuf1 : xgbuf0;   // slice k-2 buffer
      bf16* xout = (k & 1) ? xgbuf0 : xgbuf1;   // slice k-1 buffer
      const bool xgv = (k >= 1 && k <= NSEG);
      const int nblk = 64 + (xgv ? 2048 : 0);
      pipe_kernel<<<dim3(nblk), dim3(512), 0, stream>>>(
          x, flag, wb0, table, (const unsigned short*)xin, wb1,
          hreg, cws0, cws1, k, wbi, bi1, bh1, xout);
    }
  } else {
    float* cwsA = (float*)wb0;  // wb0 dead after rec0_full completes
    rec0_full_kernel<<<dim3(32), dim3(512), 0, stream>>>(x, flag, wb0, table, hreg);
    xg_kernel<<<dim3(2048), dim3(512), 0, stream>>>(hreg, Wi1, bi1, bh1, xgbuf0, 0);
    for (int s = 0; s < NSEG; ++s) {
      const int t0 = s * TSL;
      bf16* xin  = (s & 1) ? xgbuf1 : xgbuf0;
      bf16* xout = (s & 1) ? xgbuf0 : xgbuf1;
      const int nblk = 32 + ((s + 1 < NSEG) ? 2048 : 0);
      combo_kernel<<<dim3(nblk), dim3(512), 0, stream>>>(
          (const unsigned short*)xin, wb1, hreg, cwsA, t0, Wi1, bi1, bh1, xout);
    }
  }
  proj_kernel<<<dim3(BB * SS / 128, VV / 128), dim3(512), 0, stream>>>(
      hreg, Wg, bg, (float*)d_out);
}

// Round 22
// 2573.878 us; speedup vs baseline: 2.7144x; 1.0491x over previous
//
#include <hip/hip_runtime.h>
#include <hip/hip_bf16.h>

#define BB 512
#define SS 512
#define EE 128
#define HH 256
#define VV 128
#define G4H 1024
#define TSL 32              // slice length
#define NSEG (SS / TSL)     // 16

using bf16 = __bf16;
typedef __attribute__((ext_vector_type(8))) __bf16 bf16x8;
typedef __attribute__((ext_vector_type(4))) float f32x4;

__device__ __forceinline__ float rcpf(float x) { return __builtin_amdgcn_rcpf(x); }
__device__ __forceinline__ float exp2f_(float x) { return __builtin_amdgcn_exp2f(x); }
__device__ __forceinline__ float sigf(float x) {
  return rcpf(1.0f + exp2f_(-1.442695041f * x));
}
__device__ __forceinline__ float tanh_(float x) {
  return 2.0f * rcpf(1.0f + exp2f_(-2.885390082f * x)) - 1.0f;
}
__device__ __forceinline__ bf16x8 cvt8(const float* __restrict__ s) {
  bf16x8 f;
  #pragma unroll
  for (int j = 0; j < 8; ++j) f[j] = (bf16)s[j];
  return f;
}
__device__ __forceinline__ float bf2f(unsigned short u) {
  return __uint_as_float(((unsigned)u) << 16);
}

__global__ void detect_kernel(const int* __restrict__ x, int* __restrict__ flag) {
  const int i = blockIdx.x * 256 + threadIdx.x;
  if (x[2 * i + 1] != 0) atomicOr(flag, 1);
}

__global__ __launch_bounds__(256)
void table_kernel(const float* __restrict__ emb, const float* __restrict__ Wi,
                  const float* __restrict__ bi, const float* __restrict__ bh,
                  unsigned short* __restrict__ table) {
  const int g = blockIdx.x * 256 + threadIdx.x;
  const int v = blockIdx.y;
  float s = bi[g] + bh[g];
  const float* er = emb + v * EE;
  const float* wr = Wi + (size_t)g * EE;
  #pragma unroll 4
  for (int e = 0; e < EE; ++e) s += er[e] * wr[e];
  const bf16 b = (bf16)s;
  table[v * G4H + (g & 255) * 4 + (g >> 8)] = *(const unsigned short*)&b;
}

__global__ __launch_bounds__(256)
void wprep_kernel(const float* __restrict__ Wh0, const float* __restrict__ Wh1,
                  bf16x8* __restrict__ wb0, bf16x8* __restrict__ wb1) {
  const int idx = blockIdx.x * 256 + threadIdx.x;
  const int l = idx & 63, kc = (idx >> 6) & 7, s = (idx >> 9) & 7, w = idx >> 12;
  const int lg = l >> 4, ln = l & 15;
  const int n = (s >> 1) * HH + w * 32 + 16 * (s & 1) + ln;
  const int k0 = kc * 32 + lg * 8;
  const float* src = (blockIdx.y ? Wh1 : Wh0) + (size_t)n * HH + k0;
  (blockIdx.y ? wb1 : wb0)[idx] = cvt8(src);
}

// Wi1 (fp32 [1024][256]) -> bf16 granules in xg B-stage layout.
__global__ __launch_bounds__(256)
void wiprep_kernel(const float* __restrict__ Wi1, bf16x8* __restrict__ wbi) {
  const int idx = blockIdx.x * 256 + threadIdx.x;   // 0..32767
  const int g = idx & 31, col = (idx >> 5) & 255, up = idx >> 13;
  const int n = (col & 3) * HH + up * 64 + (col >> 2);
  wbi[idx] = cvt8(Wi1 + (size_t)n * HH + g * 8);
}

// ---------------------------------------------------------------------------
// rec0 slice body (R21 verbatim; TSL-parameterized).
// ---------------------------------------------------------------------------
__device__ __forceinline__
void rec0_body(char* smem, const int* __restrict__ x, int is32,
               const bf16x8* __restrict__ wb,
               const unsigned short* __restrict__ table,
               bf16* __restrict__ h1, float (*cst)[4],
               int t0, int bid, bool load_h) {
  bf16 (*hbuf)[4096] = (bf16(*)[4096])smem;
  bf16x8* wlds = (bf16x8*)(smem + 16384);
  const int tid = threadIdx.x, w = tid >> 6, l = tid & 63, lg = l >> 4, ln = l & 15;
  const int b0 = bid * 16, hb = w * 32;

  bf16x8 Wf[4][8];
  #pragma unroll
  for (int s = 0; s < 4; ++s)
    #pragma unroll
    for (int kc = 0; kc < 8; ++kc)
      Wf[s][kc] = wb[w * 4096 + s * 512 + kc * 64 + l];
  #pragma unroll
  for (int j = 0; j < 2; ++j)
    #pragma unroll
    for (int kc = 0; kc < 8; ++kc)
      wlds[((w * 2 + j) * 8 + kc) * 64 + l] = wb[w * 4096 + (6 + j) * 512 + kc * 64 + l];
  const bf16x8* __restrict__ gsrc0 = wb + w * 4096 + 4 * 512 + l;
  const bf16x8* __restrict__ gsrc1 = wb + w * 4096 + 5 * 512 + l;

  int hoff[4];
  #pragma unroll
  for (int r = 0; r < 4; ++r)
    hoff[r] = ((b0 + lg * 4 + r) * SS) * HH + hb + ln;

  if (t0 == 0) {
    bf16x8 z = {};
    ((bf16x8*)&hbuf[0][0])[tid] = z;
  } else if (load_h) {
    #pragma unroll
    for (int j = 0; j < 2; ++j)
      #pragma unroll
      for (int r = 0; r < 4; ++r) {
        const int m = lg * 4 + r, col = hb + 16 * j + ln;
        const bf16 hv = h1[((size_t)(b0 + m) * SS + (t0 - 1)) * HH + col];
        hbuf[0][(w * 64 + m * 4 + 2 * j + (ln >> 3)) * 8 + (ln & 7)] = hv;
      }
  }
  int idx[4];
  #pragma unroll
  for (int r = 0; r < 4; ++r) {
    const long xi = (long)(b0 + lg * 4 + r) * SS + t0;
    idx[r] = x[is32 ? xi : 2 * xi] & 127;
  }
  __syncthreads();

  #pragma unroll 1
  for (int tt = 0; tt < TSL; ++tt) {
    const int t = t0 + tt, p = tt & 1;
    ushort4 tj[4][2];
    #pragma unroll
    for (int r = 0; r < 4; ++r) {
      const unsigned short* base = table + (size_t)idx[r] * G4H + (hb + ln) * 4;
      tj[r][0] = *(const ushort4*)base;
      tj[r][1] = *(const ushort4*)(base + 64);
    }
    if (tt + 1 < TSL) {
      #pragma unroll
      for (int r = 0; r < 4; ++r) {
        const long xi = (long)(b0 + lg * 4 + r) * SS + (t + 1);
        idx[r] = x[is32 ? xi : 2 * xi] & 127;
      }
    }
    f32x4 acc[4][2] = {};
    #pragma unroll
    for (int kc = 0; kc < 8; ++kc) {
      bf16x8 a = ((const bf16x8*)&hbuf[p][0])[kc * 64 + ln * 4 + lg];
      acc[0][0] = __builtin_amdgcn_mfma_f32_16x16x32_bf16(a, Wf[0][kc], acc[0][0], 0, 0, 0);
      acc[0][1] = __builtin_amdgcn_mfma_f32_16x16x32_bf16(a, Wf[1][kc], acc[0][1], 0, 0, 0);
      acc[1][0] = __builtin_amdgcn_mfma_f32_16x16x32_bf16(a, Wf[2][kc], acc[1][0], 0, 0, 0);
      acc[1][1] = __builtin_amdgcn_mfma_f32_16x16x32_bf16(a, Wf[3][kc], acc[1][1], 0, 0, 0);
      acc[2][0] = __builtin_amdgcn_mfma_f32_16x16x32_bf16(a, gsrc0[kc * 64], acc[2][0], 0, 0, 0);
      acc[2][1] = __builtin_amdgcn_mfma_f32_16x16x32_bf16(a, gsrc1[kc * 64], acc[2][1], 0, 0, 0);
      #pragma unroll
      for (int j = 0; j < 2; ++j) {
        bf16x8 bw = wlds[((w * 2 + j) * 8 + kc) * 64 + l];
        acc[3][j] = __builtin_amdgcn_mfma_f32_16x16x32_bf16(a, bw, acc[3][j], 0, 0, 0);
      }
    }
    #pragma unroll
    for (int j = 0; j < 2; ++j)
      #pragma unroll
      for (int r = 0; r < 4; ++r) {
        const float fg = sigf(acc[0][j][r] + bf2f(tj[r][j].x));
        const float ig = sigf(acc[1][j][r] + bf2f(tj[r][j].y));
        const float gg = tanh_(acc[2][j][r] + bf2f(tj[r][j].z));
        const float og = sigf(acc[3][j][r] + bf2f(tj[r][j].w));
        const float cc = fg * cst[j][r] + ig * gg;
        cst[j][r] = cc;
        const bf16 hv = (bf16)(og * tanh_(cc));
        const int m = lg * 4 + r;
        hbuf[p ^ 1][(w * 64 + m * 4 + 2 * j + (ln >> 3)) * 8 + (ln & 7)] = hv;
        h1[hoff[r] + t * HH + 16 * j] = hv;
      }
    __syncthreads();
  }
}

// ---------------------------------------------------------------------------
// rec1 slice body (R21 verbatim; TSL-parameterized).
// ---------------------------------------------------------------------------
__device__ __forceinline__
void rec1_body(char* smem, const unsigned short* __restrict__ xg,
               const bf16x8* __restrict__ wb, bf16* __restrict__ hreg,
               float* __restrict__ cws, int t0, int bid) {
  bf16 (*hbuf)[4096] = (bf16(*)[4096])smem;
  bf16x8* wlds = (bf16x8*)(smem + 16384);
  const int tid = threadIdx.x, w = tid >> 6, l = tid & 63, lg = l >> 4, ln = l & 15;
  const int b0 = bid * 16, hb = w * 32;

  bf16x8 Wf[4][8];
  #pragma unroll
  for (int s = 0; s < 4; ++s)
    #pragma unroll
    for (int kc = 0; kc < 8; ++kc)
      Wf[s][kc] = wb[w * 4096 + s * 512 + kc * 64 + l];
  #pragma unroll
  for (int j = 0; j < 2; ++j)
    #pragma unroll
    for (int kc = 0; kc < 8; ++kc)
      wlds[((w * 2 + j) * 8 + kc) * 64 + l] = wb[w * 4096 + (6 + j) * 512 + kc * 64 + l];
  const bf16x8* __restrict__ gsrc0 = wb + w * 4096 + 4 * 512 + l;
  const bf16x8* __restrict__ gsrc1 = wb + w * 4096 + 5 * 512 + l;

  int hoff[4];
  size_t xbase[4];
  #pragma unroll
  for (int r = 0; r < 4; ++r) {
    hoff[r] = ((b0 + lg * 4 + r) * SS) * HH + hb + ln;
    xbase[r] = (size_t)(b0 + lg * 4 + r) * TSL * G4H + (hb + ln) * 4;
  }

  float c[2][4];
  if (t0 == 0) {
    #pragma unroll
    for (int j = 0; j < 2; ++j)
      #pragma unroll
      for (int r = 0; r < 4; ++r) c[j][r] = 0.f;
    bf16x8 z = {};
    ((bf16x8*)&hbuf[0][0])[tid] = z;
  } else {
    #pragma unroll
    for (int j = 0; j < 2; ++j)
      #pragma unroll
      for (int r = 0; r < 4; ++r) {
        const int m = lg * 4 + r, col = hb + 16 * j + ln;
        c[j][r] = cws[(size_t)(b0 + m) * HH + col];
        const bf16 hv = hreg[((size_t)(b0 + m) * SS + (t0 - 1)) * HH + col];
        hbuf[0][(w * 64 + m * 4 + 2 * j + (ln >> 3)) * 8 + (ln & 7)] = hv;
      }
  }
  __syncthreads();

  #pragma unroll 1
  for (int tt = 0; tt < TSL; ++tt) {
    const int t = t0 + tt, p = tt & 1;
    ushort4 tj[4][2];
    #pragma unroll
    for (int r = 0; r < 4; ++r) {
      const unsigned short* base = xg + xbase[r] + (size_t)tt * G4H;
      tj[r][0] = *(const ushort4*)base;
      tj[r][1] = *(const ushort4*)(base + 64);
    }
    f32x4 acc[4][2] = {};
    #pragma unroll
    for (int kc = 0; kc < 8; ++kc) {
      bf16x8 a = ((const bf16x8*)&hbuf[p][0])[kc * 64 + ln * 4 + lg];
      acc[0][0] = __builtin_amdgcn_mfma_f32_16x16x32_bf16(a, Wf[0][kc], acc[0][0], 0, 0, 0);
      acc[0][1] = __builtin_amdgcn_mfma_f32_16x16x32_bf16(a, Wf[1][kc], acc[0][1], 0, 0, 0);
      acc[1][0] = __builtin_amdgcn_mfma_f32_16x16x32_bf16(a, Wf[2][kc], acc[1][0], 0, 0, 0);
      acc[1][1] = __builtin_amdgcn_mfma_f32_16x16x32_bf16(a, Wf[3][kc], acc[1][1], 0, 0, 0);
      acc[2][0] = __builtin_amdgcn_mfma_f32_16x16x32_bf16(a, gsrc0[kc * 64], acc[2][0], 0, 0, 0);
      acc[2][1] = __builtin_amdgcn_mfma_f32_16x16x32_bf16(a, gsrc1[kc * 64], acc[2][1], 0, 0, 0);
      #pragma unroll
      for (int j = 0; j < 2; ++j) {
        bf16x8 bw = wlds[((w * 2 + j) * 8 + kc) * 64 + l];
        acc[3][j] = __builtin_amdgcn_mfma_f32_16x16x32_bf16(a, bw, acc[3][j], 0, 0, 0);
      }
    }
    #pragma unroll
    for (int j = 0; j < 2; ++j)
      #pragma unroll
      for (int r = 0; r < 4; ++r) {
        const float fg = sigf(acc[0][j][r] + bf2f(tj[r][j].x));
        const float ig = sigf(acc[1][j][r] + bf2f(tj[r][j].y));
        const float gg = tanh_(acc[2][j][r] + bf2f(tj[r][j].z));
        const float og = sigf(acc[3][j][r] + bf2f(tj[r][j].w));
        const float cc = fg * c[j][r] + ig * gg;
        c[j][r] = cc;
        const bf16 hv = (bf16)(og * tanh_(cc));
        const int m = lg * 4 + r;
        hbuf[p ^ 1][(w * 64 + m * 4 + 2 * j + (ln >> 3)) * 8 + (ln & 7)] = hv;
        hreg[hoff[r] + t * HH + 16 * j] = hv;
      }
    __syncthreads();
  }
  #pragma unroll
  for (int j = 0; j < 2; ++j)
    #pragma unroll
    for (int r = 0; r < 4; ++r)
      cws[(size_t)(b0 + lg * 4 + r) * HH + hb + 16 * j + ln] = c[j][r];
}

// ---------------------------------------------------------------------------
// xg GEMM body: 64 xg-rows x 256 gate-cols. TSL=32: a 64-row tile spans TWO
// batches (batch = R>>5, tt = R&31). WB16 selects bf16-preconverted B.
// ---------------------------------------------------------------------------
template <int WB16>
__device__ __forceinline__
void xg_body(char* smem, const bf16* __restrict__ A, const void* __restrict__ Wb,
             const float* __restrict__ bias0, const float* __restrict__ bias1,
             bf16* __restrict__ out, int t0, int flat) {
  bf16x8* alds = (bf16x8*)smem;                       // 32 KB
  bf16x8* blds = (bf16x8*)(smem + 32768);             // 128 KB
  const int tid = threadIdx.x, w = tid >> 6, l = tid & 63, lg = l >> 4, ln = l & 15;
  const int wm = w & 1, wn = w >> 1;
  const int rt = flat & 255, up = flat >> 8;          // row-tile, u-panel
  const int R0 = rt * 64;
  {
    const int row = tid >> 3, seg = tid & 7;
    const int R = R0 + row;
    const bf16* asrc = A + ((size_t)(R >> 5) * SS + t0 + (R & 31)) * HH + seg * 32;
    #pragma unroll
    for (int k = 0; k < 4; ++k) {
      const int g = seg * 4 + k;
      alds[row * 32 + (g ^ (row & 7))] = *(const bf16x8*)(asrc + k * 8);
    }
    const int col = tid >> 1, half = tid & 1;
    if (WB16) {
      const bf16x8* bsrc = (const bf16x8*)Wb + up * 8192 + col * 32 + half * 16;
      #pragma unroll
      for (int k = 0; k < 16; ++k) {
        const int g = half * 16 + k;
        blds[col * 32 + (g ^ (col & 7))] = bsrc[k];
      }
    } else {
      const int n = (col & 3) * HH + up * 64 + (col >> 2);
      const float* bsrc = (const float*)Wb + (size_t)n * HH + half * 128;
      #pragma unroll
      for (int k = 0; k < 16; ++k) {
        const int g = half * 16 + k;
        blds[col * 32 + (g ^ (col & 7))] = cvt8(bsrc + k * 8);
      }
    }
  }
  __syncthreads();
  f32x4 acc[2][4] = {};
  #pragma unroll
  for (int kc = 0; kc < 8; ++kc) {
    bf16x8 bfr[4];
    #pragma unroll
    for (int nt = 0; nt < 4; ++nt) {
      const int row = wn * 64 + nt * 16 + ln;
      bfr[nt] = blds[row * 32 + ((kc * 4 + lg) ^ (row & 7))];
    }
    #pragma unroll
    for (int mt = 0; mt < 2; ++mt) {
      const int row = wm * 32 + mt * 16 + ln;
      bf16x8 a = alds[row * 32 + ((kc * 4 + lg) ^ (row & 7))];
      #pragma unroll
      for (int nt = 0; nt < 4; ++nt)
        acc[mt][nt] = __builtin_amdgcn_mfma_f32_16x16x32_bf16(a, bfr[nt], acc[mt][nt], 0, 0, 0);
    }
  }
  #pragma unroll
  for (int nt = 0; nt < 4; ++nt) {
    const int local = wn * 64 + nt * 16 + ln;
    const int n = (local & 3) * HH + up * 64 + (local >> 2);
    const float bv = bias0[n] + bias1[n];
    const int gcol = up * 256 + local;
    #pragma unroll
    for (int mt = 0; mt < 2; ++mt)
      #pragma unroll
      for (int r = 0; r < 4; ++r) {
        const size_t row = (size_t)R0 + wm * 32 + mt * 16 + lg * 4 + r;
        out[row * G4H + gcol] = (bf16)(acc[mt][nt][r] + bv);
      }
  }
}

__device__ __forceinline__
void rec0_slice(char* smem, const int* x, int is32, const bf16x8* wb0,
                const unsigned short* table, bf16* hreg, float* cws0,
                int t0, int bid) {
  const int tid = threadIdx.x, w = tid >> 6, l = tid & 63, lg = l >> 4, ln = l & 15;
  const int b0 = bid * 16, hb = w * 32;
  float c[2][4];
  if (t0 == 0) {
    #pragma unroll
    for (int j = 0; j < 2; ++j)
      #pragma unroll
      for (int r = 0; r < 4; ++r) c[j][r] = 0.f;
  } else {
    #pragma unroll
    for (int j = 0; j < 2; ++j)
      #pragma unroll
      for (int r = 0; r < 4; ++r)
        c[j][r] = cws0[(size_t)(b0 + lg * 4 + r) * HH + hb + 16 * j + ln];
  }
  rec0_body(smem, x, is32, wb0, table, hreg, c, t0, bid, t0 != 0);
  #pragma unroll
  for (int j = 0; j < 2; ++j)
    #pragma unroll
    for (int r = 0; r < 4; ++r)
      cws0[(size_t)(b0 + lg * 4 + r) * HH + hb + 16 * j + ln] = c[j][r];
}

// ---------------------------------------------------------------------------
// 3-stage pipeline launch k: blocks 0-31 rec0(k); 32-63 rec1(k-2); 64+ xg(k-1).
// ---------------------------------------------------------------------------
__global__ __launch_bounds__(512)
void pipe_kernel(const int* __restrict__ x, const int* __restrict__ flagp,
                 const bf16x8* __restrict__ wb0,
                 const unsigned short* __restrict__ table,
                 const unsigned short* __restrict__ xg_in,
                 const bf16x8* __restrict__ wb1,
                 bf16* __restrict__ hreg, float* __restrict__ cws0,
                 float* __restrict__ cws1, int k,
                 const bf16x8* __restrict__ wbi, const float* __restrict__ bi,
                 const float* __restrict__ bh, bf16* __restrict__ xg_out) {
  __shared__ __align__(16) char smem[163840];
  const int bx = blockIdx.x;
  if (bx < 32) {
    if (k < NSEG) rec0_slice(smem, x, *flagp, wb0, table, hreg, cws0, k * TSL, bx);
  } else if (bx < 64) {
    if (k >= 2) rec1_body(smem, xg_in, wb1, hreg, cws1, (k - 2) * TSL, bx - 32);
  } else {
    if (k >= 1 && k <= NSEG)
      xg_body<1>(smem, hreg, wbi, bi, bh, xg_out, (k - 1) * TSL, bx - 64);
  }
}

// ---------------------------------------------------------------------------
// Fallback path kernels (fp32 Wi1 xg).
// ---------------------------------------------------------------------------
__global__ __launch_bounds__(512)
void rec0_full_kernel(const int* __restrict__ x, const int* __restrict__ flagp,
                      const bf16x8* __restrict__ wb,
                      const unsigned short* __restrict__ table,
                      bf16* __restrict__ h1) {
  __shared__ __align__(16) char smem[147456];
  const int is32 = *flagp;
  float c[2][4] = {};
  #pragma unroll 1
  for (int s = 0; s < NSEG; ++s) {
    rec0_body(smem, x, is32, wb, table, h1, c, s * TSL, blockIdx.x, false);
    __syncthreads();
  }
}

__global__ __launch_bounds__(512)
void combo_kernel(const unsigned short* __restrict__ xg_in,
                  const bf16x8* __restrict__ wb, bf16* __restrict__ hreg,
                  float* __restrict__ cws, int t0,
                  const float* __restrict__ Wi, const float* __restrict__ bi,
                  const float* __restrict__ bh, bf16* __restrict__ xg_out) {
  __shared__ __align__(16) char smem[163840];
  if (blockIdx.x < 32)
    rec1_body(smem, xg_in, wb, hreg, cws, t0, blockIdx.x);
  else
    xg_body<0>(smem, hreg, Wi, bi, bh, xg_out, t0 + TSL, blockIdx.x - 32);
}

__global__ __launch_bounds__(512)
void xg_kernel(const bf16* __restrict__ A, const float* __restrict__ W,
               const float* __restrict__ bi, const float* __restrict__ bh,
               bf16* __restrict__ out, int t0) {
  __shared__ __align__(16) char smem[163840];
  xg_body<0>(smem, A, W, bi, bh, out, t0, blockIdx.x);
}

// ---------------------------------------------------------------------------
// proj GEMM (R21 verbatim).
// ---------------------------------------------------------------------------
__global__ __launch_bounds__(512)
void proj_kernel(const bf16* __restrict__ A, const float* __restrict__ W,
                 const float* __restrict__ bias0, float* __restrict__ out) {
  __shared__ bf16x8 alds[4096];
  __shared__ bf16x8 blds[4096];
  const int tid = threadIdx.x, w = tid >> 6, l = tid & 63, lg = l >> 4, ln = l & 15;
  const int wm = w & 1, wn = w >> 1;
  const int R0 = blockIdx.x * 128, N0 = blockIdx.y * 128;
  {
    const int row = tid >> 2, seg = tid & 3;
    const bf16* asrc = A + ((size_t)R0 + row) * HH + seg * 64;
    #pragma unroll
    for (int k = 0; k < 8; ++k) {
      const int g = seg * 8 + k;
      alds[row * 32 + (g ^ (row & 7))] = *(const bf16x8*)(asrc + k * 8);
    }
    const float* bsrc = W + (size_t)(N0 + row) * HH + seg * 64;
    #pragma unroll
    for (int k = 0; k < 8; ++k) {
      const int g = seg * 8 + k;
      blds[row * 32 + (g ^ (row & 7))] = cvt8(bsrc + k * 8);
    }
  }
  __syncthreads();
  f32x4 acc[4][2] = {};
  #pragma unroll
  for (int kc = 0; kc < 8; ++kc) {
    bf16x8 bfr[2];
    #pragma unroll
    for (int nt = 0; nt < 2; ++nt) {
      const int row = wn * 32 + nt * 16 + ln;
      bfr[nt] = blds[row * 32 + ((kc * 4 + lg) ^ (row & 7))];
    }
    #pragma unroll
    for (int mt = 0; mt < 4; ++mt) {
      const int row = wm * 64 + mt * 16 + ln;
      bf16x8 a = alds[row * 32 + ((kc * 4 + lg) ^ (row & 7))];
      #pragma unroll
      for (int nt = 0; nt < 2; ++nt)
        acc[mt][nt] = __builtin_amdgcn_mfma_f32_16x16x32_bf16(a, bfr[nt], acc[mt][nt], 0, 0, 0);
    }
  }
  #pragma unroll
  for (int nt = 0; nt < 2; ++nt) {
    const int n = N0 + wn * 32 + nt * 16 + ln;
    const float bv = bias0[n];
    #pragma unroll
    for (int mt = 0; mt < 4; ++mt)
      #pragma unroll
      for (int r = 0; r < 4; ++r) {
        const size_t row = (size_t)R0 + wm * 64 + mt * 16 + lg * 4 + r;
        out[row * VV + n] = acc[mt][nt][r] + bv;
      }
  }
}

extern "C" void kernel_launch(void* const* d_in, const int* in_sizes, int n_in,
                              void* d_out, int out_size, void* d_ws, size_t ws_size,
                              hipStream_t stream) {
  const int*   x   = (const int*)d_in[0];
  const float* emb = (const float*)d_in[1];
  const float* Wi0 = (const float*)d_in[2];
  const float* bi0 = (const float*)d_in[3];
  const float* Wh0 = (const float*)d_in[4];
  const float* bh0 = (const float*)d_in[5];
  const float* Wi1 = (const float*)d_in[6];
  const float* bi1 = (const float*)d_in[7];
  const float* Wh1 = (const float*)d_in[8];
  const float* bh1 = (const float*)d_in[9];
  const float* Wg  = (const float*)d_in[10];
  const float* bg  = (const float*)d_in[11];

  char* ws = (char*)d_ws;
  int* flag = (int*)ws;
  unsigned short* table = (unsigned short*)(ws + 256);
  bf16x8* wb0 = (bf16x8*)(ws + 256 + 262144);
  bf16x8* wb1 = (bf16x8*)(ws + 256 + 262144 + 524288);
  bf16* hreg = (bf16*)(ws + 256 + 262144 + 524288 + 524288);
  const size_t need_base = 256 + 262144 + 524288 + 524288
                         + (size_t)BB * SS * HH * sizeof(bf16);
  float* cws0 = (float*)(ws + need_base);
  float* cws1 = (float*)(ws + need_base + 524288);
  bf16x8* wbi = (bf16x8*)(ws + need_base + 2 * 524288);
  const size_t need_full = need_base + 3 * 524288;
  if (ws_size < need_base) return;

  bf16* xgbuf0 = (bf16*)d_out;
  bf16* xgbuf1 = (bf16*)((char*)d_out + (size_t)BB * TSL * G4H * sizeof(bf16));

  (void)hipMemsetAsync(flag, 0, sizeof(int), stream);
  detect_kernel<<<dim3(8), dim3(256), 0, stream>>>(x, flag);
  table_kernel<<<dim3(4, 128), dim3(256), 0, stream>>>(emb, Wi0, bi0, bh0, table);
  wprep_kernel<<<dim3(128, 2), dim3(256), 0, stream>>>(Wh0, Wh1, wb0, wb1);

  if (ws_size >= need_full) {
    wiprep_kernel<<<dim3(128), dim3(256), 0, stream>>>(Wi1, wbi);
    for (int k = 0; k <= NSEG + 1; ++k) {
      bf16* xin  = (k & 1) ? xgbuf1 : xgbuf0;   // slice k-2 buffer
      bf16* xout = (k & 1) ? xgbuf0 : xgbuf1;   // slice k-1 buffer
      const bool xgv = (k >= 1 && k <= NSEG);
      const int nblk = 64 + (xgv ? 1024 : 0);
      pipe_kernel<<<dim3(nblk), dim3(512), 0, stream>>>(
          x, flag, wb0, table, (const unsigned short*)xin, wb1,
          hreg, cws0, cws1, k, wbi, bi1, bh1, xout);
    }
  } else {
    float* cwsA = (float*)wb0;  // wb0 dead after rec0_full completes
    rec0_full_kernel<<<dim3(32), dim3(512), 0, stream>>>(x, flag, wb0, table, hreg);
    xg_kernel<<<dim3(1024), dim3(512), 0, stream>>>(hreg, Wi1, bi1, bh1, xgbuf0, 0);
    for (int s = 0; s < NSEG; ++s) {
      const int t0 = s * TSL;
      bf16* xin  = (s & 1) ? xgbuf1 : xgbuf0;
      bf16* xout = (s & 1) ? xgbuf0 : xgbuf1;
      const int nblk = 32 + ((s + 1 < NSEG) ? 1024 : 0);
      combo_kernel<<<dim3(nblk), dim3(512), 0, stream>>>(
          (const unsigned short*)xin, wb1, hreg, cwsA, t0, Wi1, bi1, bh1, xout);
    }
  }
  proj_kernel<<<dim3(BB * SS / 128, VV / 128), dim3(512), 0, stream>>>(
      hreg, Wg, bg, (float*)d_out);
}